// Round 7
// baseline (176.951 us; speedup 1.0000x reference)
//
#include <hip/hip_runtime.h>
#include <cmath>

#define B_SZ 2
#define LSEQ 2048
#define DDIM 1024
#define NDIM 16
#define HDIM 128
#define MROWS (B_SZ * LSEQ)    // 4096
#define NBIG (DDIM + 2 * NDIM) // 1056
#define NPAD 1088              // NBIG padded to 64
#define NCAT (DDIM + NBIG)     // 2080: [x_tr | delta | Bm | Cm]
#define NCATP 2112             // NCAT padded to 64

typedef __bf16 bf16x8 __attribute__((ext_vector_type(8)));
typedef __bf16 bf16x4 __attribute__((ext_vector_type(4)));
typedef float f32x4 __attribute__((ext_vector_type(4)));

// async global->LDS, 16B/lane; LDS dest = wave-uniform base + lane*16
__device__ __forceinline__ void glds16(const __bf16* g, __bf16* l) {
    __builtin_amdgcn_global_load_lds(
        (const __attribute__((address_space(1))) unsigned int*)g,
        (__attribute__((address_space(3))) unsigned int*)l, 16, 0, 0);
}

// ---------------------------------------------------------------------------
// Fused preprocessing: weight transpose+cast, bias work, x cast, h0 mask.
// ---------------------------------------------------------------------------
__device__ __forceinline__ void tcast_tile(const float* __restrict__ in,
                                           __bf16* __restrict__ out, int K, int N,
                                           int bx, int by, float (*t)[33]) {
    int tx = threadIdx.x & 31, ty = threadIdx.x >> 5;
    int n0 = bx * 32, k0 = by * 32;
    #pragma unroll
    for (int i = 0; i < 4; ++i) {
        int k = k0 + ty + i * 8, n = n0 + tx;
        t[ty + i * 8][tx] = (k < K && n < N) ? in[(size_t)k * N + n] : 0.f;
    }
    __syncthreads();
    #pragma unroll
    for (int i = 0; i < 4; ++i) {
        int n = n0 + ty + i * 8, k = k0 + tx;
        if (n < N && k < K) out[(size_t)n * K + k] = (__bf16)t[tx][ty + i * 8];
    }
}

__global__ __launch_bounds__(256) void pack_all(
    const float* W1, const float* W2, const float* W3, const float* Wl1,
    const float* Wl2, const float* Wf1, const float* Wf2,
    const float* b1, const float* b2, const float* b3, const float* bf2,
    const float* x, const float* h0,
    __bf16* WbigT, __bf16* WaT, __bf16* Wf1bT, __bf16* Wl2T, __bf16* WcatT,
    __bf16* Wf2c, float* bias_cat, __bf16* x_bf, unsigned* h0mask) {
    __shared__ float t[32][33];
    const int bx = blockIdx.x, by = blockIdx.y, z = blockIdx.z;
    const int tid = threadIdx.x;
    switch (z) {
        case 0: tcast_tile(W1, WbigT, 1024, 1024, bx, by, t); break;
        case 1: if (bx < 4) tcast_tile(Wl1, WaT, 1024, 128, bx, by, t); break;
        case 2: if (bx < 4) tcast_tile(Wf1, WaT + 128 * 1024, 1024, 128, bx, by, t); break;
        case 3: if (bx < 4) tcast_tile(Wf1 + (size_t)1024 * 128, Wf1bT, 1024, 128, bx, by, t); break;
        case 4: if (by < 4) tcast_tile(Wl2, Wl2T, 128, 1024, bx, by, t); break;
        case 5: if (by < 4) tcast_tile(Wf2, WcatT, 128, 1024, bx, by, t); break; // rows 0..1023 of WcatT
        case 6: if (bx < 1) tcast_tile(W2, WbigT + (size_t)1024 * 1024, 1024, 16, bx, by, t); break;
        case 7: if (bx < 1) tcast_tile(W3, WbigT + (size_t)1040 * 1024, 1024, 16, bx, by, t); break;
        case 8: {
            if (by == 0 && bx < 4) { // bias_cat[0:1024] = bf2
                int i = bx * 256 + tid;
                bias_cat[i] = bf2[i];
            }
            if (by == 1 && bx < 32) { // zero WbigT pad rows 1056..1087
                int i = bx * 256 + tid;
                #pragma unroll
                for (int r = 0; r < 4; ++r) {
                    int e = i + r * 8192;
                    if (e < 32 * 1024) WbigT[(size_t)1056 * 1024 + e] = (__bf16)0.f;
                }
            }
            if (by == 2 && bx < 5) { // bias_cat[1024+n] = bf2 @ Wall[:,n] + ball[n]
                int n = bx * 256 + tid;
                if (n < NBIG) {
                    float acc = (n < DDIM) ? b1[n]
                              : (n < DDIM + NDIM) ? b2[n - DDIM] : b3[n - DDIM - NDIM];
                    for (int d = 0; d < DDIM; ++d) {
                        float wv = (n < DDIM) ? W1[(size_t)d * DDIM + n]
                                 : (n < DDIM + NDIM) ? W2[(size_t)d * NDIM + (n - DDIM)]
                                 : W3[(size_t)d * NDIM + (n - DDIM - NDIM)];
                        acc += bf2[d] * wv;
                    }
                    bias_cat[DDIM + n] = acc;
                }
            }
            break;
        }
        case 9: { // x cast fp32->bf16, 4 float4 per thread
            int id = (by * 32 + bx) * 256 + tid;
            #pragma unroll
            for (int j = 0; j < 4; ++j) {
                int e = id + j * 262144;
                float4 v = ((const float4*)x)[e];
                bf16x4 o2 = {(__bf16)v.x, (__bf16)v.y, (__bf16)v.z, (__bf16)v.w};
                ((bf16x4*)x_bf)[e] = o2;
            }
            break;
        }
        case 10: { // h0 nonzero bitmask
            if (bx == 0 && by == 0) {
                __shared__ unsigned sm[32];
                if (tid < 32) sm[tid] = 0u;
                __syncthreads();
                unsigned nib = 0;
                #pragma unroll
                for (int j = 0; j < 4; ++j) {
                    int d = tid * 4 + j;
                    const uint4* hu = (const uint4*)(h0 + d * NDIM);
                    uint4 a0 = hu[0], a1 = hu[1], a2 = hu[2], a3 = hu[3];
                    unsigned nz = a0.x | a0.y | a0.z | a0.w | a1.x | a1.y | a1.z | a1.w |
                                  a2.x | a2.y | a2.z | a2.w | a3.x | a3.y | a3.z | a3.w;
                    if (nz) nib |= (1u << j);
                }
                if (nib) atomicOr(&sm[(tid * 4) >> 5], nib << ((tid * 4) & 31));
                __syncthreads();
                if (tid < 32) h0mask[tid] = sm[tid];
            }
            break;
        }
        case 11: { // plain cast Wf2 -> Wf2c [128][1024] bf16 (row-major, for Gpre Bt)
            int id = (by * 32 + bx) * 256 + tid; // need 8192 threads over 32768 f4 chunks
            if ((by * 32 + bx) < 32) {
                #pragma unroll
                for (int j = 0; j < 4; ++j) {
                    int e = id + j * 8192;
                    float4 v = ((const float4*)Wf2)[e];
                    bf16x4 o2 = {(__bf16)v.x, (__bf16)v.y, (__bf16)v.z, (__bf16)v.w};
                    ((bf16x4*)Wf2c)[e] = o2;
                }
            }
            break;
        }
    }
}

// ---------------------------------------------------------------------------
// bf16 MFMA GEMM, BMxBN tile, BK=64, double-buffered LDS, 2-phase prefetch.
// 4 waves 2x2; wave tile (BM/2)x(BN/2). glds16 staging, linear LDS dest;
// 8-slot XOR swizzle on global source AND ds_read side (involution, rule #21).
// XCD swizzle only when gridDim.x % 8 == 0 (bijectivity).
// ACT: 0 bias, 1 relu(+prev), 2 fast-tanh, 3 raw no-bias,
//      4 split128-relu, 6 cat-epilogue (bias; softplus on cols [1024,2048))
// ---------------------------------------------------------------------------
template <int BM, int BN, int ACT, bool ADD_PREV, bool GUARDN>
__global__ __launch_bounds__(256) void mm(const __bf16* __restrict__ A, int lda,
                                          const __bf16* __restrict__ Bt, int ldb, int Ntot,
                                          const float* __restrict__ bias,
                                          const __bf16* __restrict__ prev, int ldp,
                                          __bf16* __restrict__ C, int ldc, int K, int nbx) {
    constexpr int WM = BM / 2, WN = BN / 2, FM = WM / 16, FN = WN / 16;
    constexpr int ASZ = BM * 64, BSZ = BN * 64;
    __shared__ __bf16 As[2 * ASZ];
    __shared__ __bf16 Bs[2 * BSZ];
    const int tid = threadIdx.x;
    const int lane = tid & 63, w = tid >> 6;
    const int wr = w >> 1, wc = w & 1;
    const int g = lane >> 4, lr = lane & 15;

    const int NB = gridDim.x;
    const int aid = ((NB & 7) == 0)
                        ? (blockIdx.x & 7) * (NB >> 3) + (blockIdx.x >> 3)
                        : blockIdx.x;
    const int bn = (aid % nbx) * BN, bm = (aid / nbx) * BM;

    auto stage = [&](int buf, int k0) {
        #pragma unroll
        for (int i = 0; i < BM / 32; ++i) {
            int D = i * 256 + tid;
            int row = D >> 3, pos = D & 7, c = pos ^ (row & 7);
            glds16(&A[(size_t)(bm + row) * lda + k0 + c * 8],
                   &As[buf * ASZ + (i * 256 + w * 64) * 8]);
        }
        #pragma unroll
        for (int i = 0; i < BN / 32; ++i) {
            int D = i * 256 + tid;
            int row = D >> 3, pos = D & 7, c = pos ^ (row & 7);
            glds16(&Bt[(size_t)(bn + row) * ldb + k0 + c * 8],
                   &Bs[buf * BSZ + (i * 256 + w * 64) * 8]);
        }
    };

    f32x4 acc[FM][FN] = {};
    const int x7 = lr & 7;
    const int ca[2] = {(g ^ x7) * 8, ((4 + g) ^ x7) * 8};
    const int arow0 = wr * WM + lr;
    const int brow0 = wc * WN + lr;

    const int nt = K >> 6;
    stage(0, 0);
    __syncthreads();
    for (int t = 0; t < nt; ++t) {
        if (t + 1 < nt) stage((t + 1) & 1, (t + 1) << 6);
        const __bf16* Ab = &As[(t & 1) * ASZ];
        const __bf16* Bb = &Bs[(t & 1) * BSZ];
        bf16x8 af[FM][2], bfr[FN][2];
        #pragma unroll
        for (int m = 0; m < FM; ++m)
            #pragma unroll
            for (int h = 0; h < 2; ++h)
                af[m][h] = *(const bf16x8*)&Ab[(arow0 + m * 16) * 64 + ca[h]];
        #pragma unroll
        for (int n = 0; n < FN; ++n)
            #pragma unroll
            for (int h = 0; h < 2; ++h)
                bfr[n][h] = *(const bf16x8*)&Bb[(brow0 + n * 16) * 64 + ca[h]];
        #pragma unroll
        for (int h = 0; h < 2; ++h)
            #pragma unroll
            for (int m = 0; m < FM; ++m)
                #pragma unroll
                for (int n = 0; n < FN; ++n)
                    acc[m][n] = __builtin_amdgcn_mfma_f32_16x16x32_bf16(
                        af[m][h], bfr[n][h], acc[m][n], 0, 0, 0);
        __syncthreads();
    }

    // epilogue: C/D layout col=lane&15, row=(lane>>4)*4+reg
    #pragma unroll
    for (int m = 0; m < FM; ++m) {
        #pragma unroll
        for (int n = 0; n < FN; ++n) {
            #pragma unroll
            for (int r = 0; r < 4; ++r) {
                int grow = bm + wr * WM + m * 16 + g * 4 + r;
                int gcol = bn + wc * WN + n * 16 + lr;
                if (!GUARDN || gcol < Ntot) {
                    float v = acc[m][n][r];
                    if (ACT == 0) {
                        v += bias[gcol];
                    } else if (ACT == 1) {
                        v += bias[gcol];
                        if (ADD_PREV) v += (float)prev[(size_t)grow * ldp + gcol];
                        v = fmaxf(v, 0.f);
                    } else if (ACT == 2) { // fast tanh: 1 - 2/(1+e^2v)
                        v += bias[gcol];
                        float e = __expf(2.f * v);
                        v = 1.f - 2.f * __builtin_amdgcn_rcpf(e + 1.f);
                    } else if (ACT == 3) {
                        // raw, no bias (Gpre)
                    } else if (ACT == 4) {
                        if (gcol < HDIM) v = fmaxf(v + bias[gcol], 0.f);
                    } else if (ACT == 6) {
                        v += bias[gcol];
                        if (gcol >= DDIM && gcol < 2 * DDIM) { // delta: softplus
                            float e = __expf(-fabsf(v));
                            v = fmaxf(v, 0.f) + __logf(1.f + e);
                        }
                    }
                    C[(size_t)grow * ldc + gcol] = (__bf16)v;
                }
            }
        }
    }
}

// ---------------------------------------------------------------------------
// Final fusion. xdb row = [x_tr(1024) | delta(1024) | Bm(16) | Cm(16)], ld NCATP.
// ---------------------------------------------------------------------------
__global__ __launch_bounds__(256) void final_k(const __bf16* __restrict__ xdb,
                                               const float* __restrict__ A,
                                               const float* __restrict__ h0,
                                               const unsigned* __restrict__ h0mask,
                                               float* __restrict__ out,
                                               float* __restrict__ last_h) {
    const int row = blockIdx.x;
    const int tid = threadIdx.x;
    const __bf16* rp = xdb + (size_t)row * NCATP;
    __shared__ float sC[NDIM], sB[NDIM];
    if (tid < NDIM) sB[tid] = (float)rp[2 * DDIM + tid];
    else if (tid >= 32 && tid < 32 + NDIM)
        sC[tid - 32] = (float)rp[2 * DDIM + NDIM + (tid - 32)];
    __syncthreads();
    float cb = 0.f;
    #pragma unroll
    for (int n = 0; n < NDIM; ++n) cb += sC[n] * sB[n];

    const int l = row & (LSEQ - 1);
    const int b = row >> 11;
    const bool is_last = (l == LSEQ - 1);

    const int d0 = tid * 4;
    bf16x4 xv = *(const bf16x4*)&rp[d0];
    bf16x4 dv = *(const bf16x4*)&rp[DDIM + d0];
    const unsigned nib = (h0mask[d0 >> 5] >> (d0 & 31)) & 0xFu;
    float4 o;
    float* op = &o.x;
    #pragma unroll
    for (int j = 0; j < 4; ++j) {
        const int d = d0 + j;
        const float xd = (float)xv[j] * (float)dv[j];
        float s = 0.f;
        if (!((nib >> j) & 1u)) {
            if (is_last) {
                #pragma unroll
                for (int n = 0; n < NDIM; ++n)
                    last_h[((size_t)b * DDIM + d) * NDIM + n] = xd * sB[n];
            }
        } else {
            const float de = (float)dv[j];
            const float* hf = h0 + d * NDIM;
            #pragma unroll
            for (int n = 0; n < NDIM; ++n) {
                float z = de * A[d * NDIM + n];
                float c = (z > 0.f) ? z : __expf(z) - 1.f;
                float da = __expf(-c);
                float h0v = hf[n];
                s += sC[n] * da * h0v;
                if (is_last)
                    last_h[((size_t)b * DDIM + d) * NDIM + n] = da * h0v + xd * sB[n];
            }
        }
        op[j] = xd * cb + s;
    }
    *(float4*)&out[(size_t)row * DDIM + d0] = o;
}

extern "C" void kernel_launch(void* const* d_in, const int* in_sizes, int n_in,
                              void* d_out, int out_size, void* d_ws, size_t ws_size,
                              hipStream_t stream) {
    const float* x   = (const float*)d_in[0];
    const float* W1  = (const float*)d_in[1];
    const float* b1  = (const float*)d_in[2];
    const float* W2  = (const float*)d_in[3];
    const float* b2  = (const float*)d_in[4];
    const float* W3  = (const float*)d_in[5];
    const float* b3  = (const float*)d_in[6];
    const float* Wl1 = (const float*)d_in[7];
    const float* bl1 = (const float*)d_in[8];
    const float* Wl2 = (const float*)d_in[9];
    const float* bl2 = (const float*)d_in[10];
    const float* Wf1 = (const float*)d_in[11];
    const float* bf1 = (const float*)d_in[12];
    const float* Wf2 = (const float*)d_in[13];
    const float* bf2 = (const float*)d_in[14];
    const float* h0  = (const float*)d_in[15];
    const float* Amat= (const float*)d_in[16];

    float* out    = (float*)d_out;
    float* last_h = (float*)d_out + (size_t)MROWS * DDIM;

    __bf16* wsb = (__bf16*)d_ws;
    size_t o = 0;
    auto alloc = [&](size_t n) { __bf16* p = wsb + o; o += n; return p; };
    __bf16* x_bf   = alloc((size_t)MROWS * DDIM);
    __bf16* WaT    = alloc(256 * 1024);             // [Wl1 | Wf1_top]^T
    __bf16* Wf1bT  = alloc(128 * 1024);
    __bf16* Wl2T   = alloc(1024 * 128);
    __bf16* WbigT  = alloc((size_t)NPAD * 1024);    // [W1 | W2 | W3 | pad]^T
    __bf16* WcatT  = alloc((size_t)NCATP * 128);    // [Wf2 | Wcomb | pad]^T
    __bf16* Wf2c   = alloc(128 * 1024);             // Wf2 bf16 row-major
    __bf16* tmp12  = alloc((size_t)MROWS * 256);    // [relu(x@Wl1+bl1) | x@Wf1_top]
    __bf16* lifted = alloc((size_t)MROWS * DDIM);
    __bf16* tmp2   = alloc((size_t)MROWS * HDIM);
    __bf16* xdb    = alloc((size_t)MROWS * NCATP);  // [x_tr | delta | Bm | Cm]
    float*  bias_cat = (float*)(wsb + o); o += 2 * NCATP;
    unsigned* h0mask = (unsigned*)(wsb + o);

    pack_all<<<dim3(32, 32, 12), 256, 0, stream>>>(W1, W2, W3, Wl1, Wl2, Wf1, Wf2,
                                                   b1, b2, b3, bf2, x, h0,
                                                   WbigT, WaT, Wf1bT, Wl2T, WcatT,
                                                   Wf2c, bias_cat, x_bf, h0mask);

    // Gpre: WcatT[1024:2112] = (Wall^T @ Wf2^T)  M=1088 N=128 K=1024, 34 blk
    mm<64, 64, 3, false, false><<<dim3(2 * 17), 256, 0, stream>>>(
        WbigT, 1024, Wf2c, 1024, 128, nullptr, nullptr, 0,
        WcatT + (size_t)1024 * 128, 128, 1024, 2);
    // G1: tmp12 = [relu(x@Wl1+bl1) | x@Wf1_top]     M=4096 N=256 K=1024, 256 blk
    mm<64, 64, 4, false, false><<<dim3(4 * 64), 256, 0, stream>>>(
        x_bf, DDIM, WaT, 1024, 256, bl1, nullptr, 0, tmp12, 256, 1024, 4);
    // G2: lifted = tanh(tmp12[:,:128] @ Wl2 + bl2)  M=4096 N=1024 K=128, 512 blk
    mm<64, 128, 2, false, false><<<dim3(8 * 64), 256, 0, stream>>>(
        tmp12, 256, Wl2T, 128, 1024, bl2, nullptr, 0, lifted, DDIM, 128, 8);
    // G3: tmp2 = relu(lifted@Wf1_bot + bf1 + tmp12[:,128:]) M=4096 N=128 K=1024, 256 blk
    mm<32, 64, 1, true, false><<<dim3(2 * 128), 256, 0, stream>>>(
        lifted, DDIM, Wf1bT, 1024, 128, bf1, tmp12 + 128, 256, tmp2, HDIM, 1024, 2);
    // G45: xdb = tmp2 @ [Wf2|Wcomb] + bias_cat (softplus on delta cols)
    //      M=4096 N=2080(pad 2112) K=128, 2112 blk
    mm<64, 64, 6, false, true><<<dim3(33 * 64), 256, 0, stream>>>(
        tmp2, HDIM, WcatT, 128, NCAT, bias_cat, nullptr, 0, xdb, NCATP, 128, 33);

    final_k<<<dim3(MROWS), 256, 0, stream>>>(xdb, Amat, h0, h0mask, out, last_h);
}

// Round 8
// 87.638 us; speedup vs baseline: 2.0191x; 2.0191x over previous
//
#include <hip/hip_runtime.h>
#include <cmath>

#define B_SZ 2
#define LSEQ 2048
#define DDIM 1024
#define NDIM 16
#define HDIM 128
#define MROWS (B_SZ * LSEQ)    // 4096
#define NBIG (DDIM + 2 * NDIM) // 1056
#define NPAD 1088              // NBIG padded to 64
#define NCAT (DDIM + NBIG)     // 2080: [x_tr | delta | Bm | Cm]
#define NCATP 2112             // NCAT padded to 64

typedef __bf16 bf16x8 __attribute__((ext_vector_type(8)));
typedef __bf16 bf16x4 __attribute__((ext_vector_type(4)));
typedef float f32x4 __attribute__((ext_vector_type(4)));

// async global->LDS, 16B/lane; LDS dest = wave-uniform base + lane*16
__device__ __forceinline__ void glds16(const __bf16* g, __bf16* l) {
    __builtin_amdgcn_global_load_lds(
        (const __attribute__((address_space(1))) unsigned int*)g,
        (__attribute__((address_space(3))) unsigned int*)l, 16, 0, 0);
}

// ---------------------------------------------------------------------------
// Fused preprocessing: weight transpose+cast, x cast, h0 mask.
// ---------------------------------------------------------------------------
__device__ __forceinline__ void tcast_tile(const float* __restrict__ in,
                                           __bf16* __restrict__ out, int K, int N,
                                           int bx, int by, float (*t)[33]) {
    int tx = threadIdx.x & 31, ty = threadIdx.x >> 5;
    int n0 = bx * 32, k0 = by * 32;
    #pragma unroll
    for (int i = 0; i < 4; ++i) {
        int k = k0 + ty + i * 8, n = n0 + tx;
        t[ty + i * 8][tx] = (k < K && n < N) ? in[(size_t)k * N + n] : 0.f;
    }
    __syncthreads();
    #pragma unroll
    for (int i = 0; i < 4; ++i) {
        int n = n0 + ty + i * 8, k = k0 + tx;
        if (n < N && k < K) out[(size_t)n * K + k] = (__bf16)t[tx][ty + i * 8];
    }
}

__global__ __launch_bounds__(256) void pack_all(
    const float* W1, const float* W2, const float* W3, const float* Wl1,
    const float* Wl2, const float* Wf1, const float* Wf2,
    const float* bf2, const float* x, const float* h0,
    __bf16* WbigT, __bf16* WaT, __bf16* Wf1bT, __bf16* Wl2T, __bf16* WcatT,
    __bf16* Wf2c, float* bias_cat, __bf16* x_bf, unsigned* h0mask) {
    __shared__ float t[32][33];
    const int bx = blockIdx.x, by = blockIdx.y, z = blockIdx.z;
    const int tid = threadIdx.x;
    switch (z) {
        case 0: tcast_tile(W1, WbigT, 1024, 1024, bx, by, t); break;
        case 1: if (bx < 4) tcast_tile(Wl1, WaT, 1024, 128, bx, by, t); break;
        case 2: if (bx < 4) tcast_tile(Wf1, WaT + 128 * 1024, 1024, 128, bx, by, t); break;
        case 3: if (bx < 4) tcast_tile(Wf1 + (size_t)1024 * 128, Wf1bT, 1024, 128, bx, by, t); break;
        case 4: if (by < 4) tcast_tile(Wl2, Wl2T, 128, 1024, bx, by, t); break;
        case 5: if (by < 4) tcast_tile(Wf2, WcatT, 128, 1024, bx, by, t); break; // WcatT rows 0..1023
        case 6: if (bx < 1) tcast_tile(W2, WbigT + (size_t)1024 * 1024, 1024, 16, bx, by, t); break;
        case 7: if (bx < 1) tcast_tile(W3, WbigT + (size_t)1040 * 1024, 1024, 16, bx, by, t); break;
        case 8: {
            if (by == 0 && bx < 4) { // bias_cat[0:1024] = bf2
                int i = bx * 256 + tid;
                bias_cat[i] = bf2[i];
            }
            if (by == 1 && bx < 32) { // zero WbigT pad rows 1056..1087
                int i = bx * 256 + tid;
                #pragma unroll
                for (int r = 0; r < 4; ++r) {
                    int e = i + r * 8192;
                    if (e < 32 * 1024) WbigT[(size_t)1056 * 1024 + e] = (__bf16)0.f;
                }
            }
            break;
        }
        case 9: { // x cast fp32->bf16, 4 float4 per thread
            int id = (by * 32 + bx) * 256 + tid;
            #pragma unroll
            for (int j = 0; j < 4; ++j) {
                int e = id + j * 262144;
                float4 v = ((const float4*)x)[e];
                bf16x4 o2 = {(__bf16)v.x, (__bf16)v.y, (__bf16)v.z, (__bf16)v.w};
                ((bf16x4*)x_bf)[e] = o2;
            }
            break;
        }
        case 10: { // h0 nonzero bitmask
            if (bx == 0 && by == 0) {
                __shared__ unsigned sm[32];
                if (tid < 32) sm[tid] = 0u;
                __syncthreads();
                unsigned nib = 0;
                #pragma unroll
                for (int j = 0; j < 4; ++j) {
                    int d = tid * 4 + j;
                    const uint4* hu = (const uint4*)(h0 + d * NDIM);
                    uint4 a0 = hu[0], a1 = hu[1], a2 = hu[2], a3 = hu[3];
                    unsigned nz = a0.x | a0.y | a0.z | a0.w | a1.x | a1.y | a1.z | a1.w |
                                  a2.x | a2.y | a2.z | a2.w | a3.x | a3.y | a3.z | a3.w;
                    if (nz) nib |= (1u << j);
                }
                if (nib) atomicOr(&sm[(tid * 4) >> 5], nib << ((tid * 4) & 31));
                __syncthreads();
                if (tid < 32) h0mask[tid] = sm[tid];
            }
            break;
        }
        case 11: { // plain cast Wf2 -> Wf2c [128][1024] bf16 row-major (Gpre Bt)
            if ((by * 32 + bx) < 32) {
                int id = (by * 32 + bx) * 256 + tid;
                #pragma unroll
                for (int j = 0; j < 4; ++j) {
                    int e = id + j * 8192;
                    float4 v = ((const float4*)Wf2)[e];
                    bf16x4 o2 = {(__bf16)v.x, (__bf16)v.y, (__bf16)v.z, (__bf16)v.w};
                    ((bf16x4*)Wf2c)[e] = o2;
                }
            }
            break;
        }
    }
}

// ---------------------------------------------------------------------------
// bias_cat[1024+n] = ball[n] + sum_d bf2[d] * Wall[d][n], via WbigT rows
// (contiguous, coalesced). One wave per n; 64-lane shuffle reduce.
// ---------------------------------------------------------------------------
__global__ __launch_bounds__(256) void bias_comb_k(const __bf16* __restrict__ WbigT,
                                                   const float* __restrict__ bf2,
                                                   const float* __restrict__ b1,
                                                   const float* __restrict__ b2,
                                                   const float* __restrict__ b3,
                                                   float* __restrict__ bias_cat) {
    const int n = blockIdx.x * 4 + (threadIdx.x >> 6);
    const int lane = threadIdx.x & 63;
    const __bf16* wr = WbigT + (size_t)n * 1024 + lane * 16;
    float s = 0.f;
    #pragma unroll
    for (int i = 0; i < 2; ++i) {
        bf16x8 wv = *(const bf16x8*)&wr[i * 8];
        float4 f0 = *(const float4*)&bf2[lane * 16 + i * 8];
        float4 f1 = *(const float4*)&bf2[lane * 16 + i * 8 + 4];
        s += (float)wv[0] * f0.x + (float)wv[1] * f0.y + (float)wv[2] * f0.z +
             (float)wv[3] * f0.w + (float)wv[4] * f1.x + (float)wv[5] * f1.y +
             (float)wv[6] * f1.z + (float)wv[7] * f1.w;
    }
    #pragma unroll
    for (int off = 32; off; off >>= 1) s += __shfl_down(s, off);
    if (lane == 0) {
        float base = (n < DDIM) ? b1[n]
                   : (n < DDIM + NDIM) ? b2[n - DDIM] : b3[n - DDIM - NDIM];
        bias_cat[DDIM + n] = base + s;
    }
}

// ---------------------------------------------------------------------------
// bf16 MFMA GEMM, BMxBN tile, BK=64, double-buffered LDS, 2-phase prefetch.
// 4 waves 2x2; glds16 staging, linear LDS dest; 8-slot XOR swizzle both sides.
// XCD swizzle only when gridDim.x % 8 == 0 (bijectivity).
// ACT: 0 bias, 1 relu(+prev), 2 fast-tanh, 3 raw no-bias,
//      4 split128-relu, 6 cat-epilogue (bias; softplus on cols [1024,2048))
// ---------------------------------------------------------------------------
template <int BM, int BN, int ACT, bool ADD_PREV, bool GUARDN>
__global__ __launch_bounds__(256) void mm(const __bf16* __restrict__ A, int lda,
                                          const __bf16* __restrict__ Bt, int ldb, int Ntot,
                                          const float* __restrict__ bias,
                                          const __bf16* __restrict__ prev, int ldp,
                                          __bf16* __restrict__ C, int ldc, int K, int nbx) {
    constexpr int WM = BM / 2, WN = BN / 2, FM = WM / 16, FN = WN / 16;
    constexpr int ASZ = BM * 64, BSZ = BN * 64;
    __shared__ __bf16 As[2 * ASZ];
    __shared__ __bf16 Bs[2 * BSZ];
    const int tid = threadIdx.x;
    const int lane = tid & 63, w = tid >> 6;
    const int wr = w >> 1, wc = w & 1;
    const int g = lane >> 4, lr = lane & 15;

    const int NB = gridDim.x;
    const int aid = ((NB & 7) == 0)
                        ? (blockIdx.x & 7) * (NB >> 3) + (blockIdx.x >> 3)
                        : blockIdx.x;
    const int bn = (aid % nbx) * BN, bm = (aid / nbx) * BM;

    auto stage = [&](int buf, int k0) {
        #pragma unroll
        for (int i = 0; i < BM / 32; ++i) {
            int D = i * 256 + tid;
            int row = D >> 3, pos = D & 7, c = pos ^ (row & 7);
            glds16(&A[(size_t)(bm + row) * lda + k0 + c * 8],
                   &As[buf * ASZ + (i * 256 + w * 64) * 8]);
        }
        #pragma unroll
        for (int i = 0; i < BN / 32; ++i) {
            int D = i * 256 + tid;
            int row = D >> 3, pos = D & 7, c = pos ^ (row & 7);
            glds16(&Bt[(size_t)(bn + row) * ldb + k0 + c * 8],
                   &Bs[buf * BSZ + (i * 256 + w * 64) * 8]);
        }
    };

    f32x4 acc[FM][FN] = {};
    const int x7 = lr & 7;
    const int ca[2] = {(g ^ x7) * 8, ((4 + g) ^ x7) * 8};
    const int arow0 = wr * WM + lr;
    const int brow0 = wc * WN + lr;

    const int nt = K >> 6;
    stage(0, 0);
    __syncthreads();
    for (int t = 0; t < nt; ++t) {
        if (t + 1 < nt) stage((t + 1) & 1, (t + 1) << 6);
        const __bf16* Ab = &As[(t & 1) * ASZ];
        const __bf16* Bb = &Bs[(t & 1) * BSZ];
        bf16x8 af[FM][2], bfr[FN][2];
        #pragma unroll
        for (int m = 0; m < FM; ++m)
            #pragma unroll
            for (int h = 0; h < 2; ++h)
                af[m][h] = *(const bf16x8*)&Ab[(arow0 + m * 16) * 64 + ca[h]];
        #pragma unroll
        for (int n = 0; n < FN; ++n)
            #pragma unroll
            for (int h = 0; h < 2; ++h)
                bfr[n][h] = *(const bf16x8*)&Bb[(brow0 + n * 16) * 64 + ca[h]];
        #pragma unroll
        for (int h = 0; h < 2; ++h)
            #pragma unroll
            for (int m = 0; m < FM; ++m)
                #pragma unroll
                for (int n = 0; n < FN; ++n)
                    acc[m][n] = __builtin_amdgcn_mfma_f32_16x16x32_bf16(
                        af[m][h], bfr[n][h], acc[m][n], 0, 0, 0);
        __syncthreads();
    }

    // epilogue: C/D layout col=lane&15, row=(lane>>4)*4+reg
    #pragma unroll
    for (int m = 0; m < FM; ++m) {
        #pragma unroll
        for (int n = 0; n < FN; ++n) {
            #pragma unroll
            for (int r = 0; r < 4; ++r) {
                int grow = bm + wr * WM + m * 16 + g * 4 + r;
                int gcol = bn + wc * WN + n * 16 + lr;
                if (!GUARDN || gcol < Ntot) {
                    float v = acc[m][n][r];
                    if (ACT == 0) {
                        v += bias[gcol];
                    } else if (ACT == 1) {
                        v += bias[gcol];
                        if (ADD_PREV) v += (float)prev[(size_t)grow * ldp + gcol];
                        v = fmaxf(v, 0.f);
                    } else if (ACT == 2) { // fast tanh: 1 - 2/(1+e^2v)
                        v += bias[gcol];
                        float e = __expf(2.f * v);
                        v = 1.f - 2.f * __builtin_amdgcn_rcpf(e + 1.f);
                    } else if (ACT == 3) {
                        // raw, no bias (Gpre)
                    } else if (ACT == 4) {
                        if (gcol < HDIM) v = fmaxf(v + bias[gcol], 0.f);
                    } else if (ACT == 6) {
                        v += bias[gcol];
                        if (gcol >= DDIM && gcol < 2 * DDIM) { // delta: softplus
                            float e = __expf(-fabsf(v));
                            v = fmaxf(v, 0.f) + __logf(1.f + e);
                        }
                    }
                    C[(size_t)grow * ldc + gcol] = (__bf16)v;
                }
            }
        }
    }
}

// ---------------------------------------------------------------------------
// Final fusion. xdb row = [x_tr(1024) | delta(1024) | Bm(16) | Cm(16)], ld NCATP.
// ---------------------------------------------------------------------------
__global__ __launch_bounds__(256) void final_k(const __bf16* __restrict__ xdb,
                                               const float* __restrict__ A,
                                               const float* __restrict__ h0,
                                               const unsigned* __restrict__ h0mask,
                                               float* __restrict__ out,
                                               float* __restrict__ last_h) {
    const int row = blockIdx.x;
    const int tid = threadIdx.x;
    const __bf16* rp = xdb + (size_t)row * NCATP;
    __shared__ float sC[NDIM], sB[NDIM];
    if (tid < NDIM) sB[tid] = (float)rp[2 * DDIM + tid];
    else if (tid >= 32 && tid < 32 + NDIM)
        sC[tid - 32] = (float)rp[2 * DDIM + NDIM + (tid - 32)];
    __syncthreads();
    float cb = 0.f;
    #pragma unroll
    for (int n = 0; n < NDIM; ++n) cb += sC[n] * sB[n];

    const int l = row & (LSEQ - 1);
    const int b = row >> 11;
    const bool is_last = (l == LSEQ - 1);

    const int d0 = tid * 4;
    bf16x4 xv = *(const bf16x4*)&rp[d0];
    bf16x4 dv = *(const bf16x4*)&rp[DDIM + d0];
    const unsigned nib = (h0mask[d0 >> 5] >> (d0 & 31)) & 0xFu;
    float4 o;
    float* op = &o.x;
    #pragma unroll
    for (int j = 0; j < 4; ++j) {
        const int d = d0 + j;
        const float xd = (float)xv[j] * (float)dv[j];
        float s = 0.f;
        if (!((nib >> j) & 1u)) {
            if (is_last) {
                #pragma unroll
                for (int n = 0; n < NDIM; ++n)
                    last_h[((size_t)b * DDIM + d) * NDIM + n] = xd * sB[n];
            }
        } else {
            const float de = (float)dv[j];
            const float* hf = h0 + d * NDIM;
            #pragma unroll
            for (int n = 0; n < NDIM; ++n) {
                float z = de * A[d * NDIM + n];
                float c = (z > 0.f) ? z : __expf(z) - 1.f;
                float da = __expf(-c);
                float h0v = hf[n];
                s += sC[n] * da * h0v;
                if (is_last)
                    last_h[((size_t)b * DDIM + d) * NDIM + n] = da * h0v + xd * sB[n];
            }
        }
        op[j] = xd * cb + s;
    }
    *(float4*)&out[(size_t)row * DDIM + d0] = o;
}

extern "C" void kernel_launch(void* const* d_in, const int* in_sizes, int n_in,
                              void* d_out, int out_size, void* d_ws, size_t ws_size,
                              hipStream_t stream) {
    const float* x   = (const float*)d_in[0];
    const float* W1  = (const float*)d_in[1];
    const float* b1  = (const float*)d_in[2];
    const float* W2  = (const float*)d_in[3];
    const float* b2  = (const float*)d_in[4];
    const float* W3  = (const float*)d_in[5];
    const float* b3  = (const float*)d_in[6];
    const float* Wl1 = (const float*)d_in[7];
    const float* bl1 = (const float*)d_in[8];
    const float* Wl2 = (const float*)d_in[9];
    const float* bl2 = (const float*)d_in[10];
    const float* Wf1 = (const float*)d_in[11];
    const float* bf1 = (const float*)d_in[12];
    const float* Wf2 = (const float*)d_in[13];
    const float* bf2 = (const float*)d_in[14];
    const float* h0  = (const float*)d_in[15];
    const float* Amat= (const float*)d_in[16];

    float* out    = (float*)d_out;
    float* last_h = (float*)d_out + (size_t)MROWS * DDIM;

    __bf16* wsb = (__bf16*)d_ws;
    size_t o = 0;
    auto alloc = [&](size_t n) { __bf16* p = wsb + o; o += n; return p; };
    __bf16* x_bf   = alloc((size_t)MROWS * DDIM);
    __bf16* WaT    = alloc(256 * 1024);             // [Wl1 | Wf1_top]^T
    __bf16* Wf1bT  = alloc(128 * 1024);
    __bf16* Wl2T   = alloc(1024 * 128);
    __bf16* WbigT  = alloc((size_t)NPAD * 1024);    // [W1 | W2 | W3 | pad]^T
    __bf16* WcatT  = alloc((size_t)NCATP * 128);    // [Wf2 | Wcomb | pad]^T
    __bf16* Wf2c   = alloc(128 * 1024);             // Wf2 bf16 row-major
    __bf16* tmp12  = alloc((size_t)MROWS * 256);    // [relu(x@Wl1+bl1) | x@Wf1_top]
    __bf16* lifted = alloc((size_t)MROWS * DDIM);
    __bf16* tmp2   = alloc((size_t)MROWS * HDIM);
    __bf16* xdb    = alloc((size_t)MROWS * NCATP);  // [x_tr | delta | Bm | Cm]
    float*  bias_cat = (float*)(wsb + o); o += 2 * NCATP;
    unsigned* h0mask = (unsigned*)(wsb + o);

    pack_all<<<dim3(32, 32, 12), 256, 0, stream>>>(W1, W2, W3, Wl1, Wl2, Wf1, Wf2,
                                                   bf2, x, h0,
                                                   WbigT, WaT, Wf1bT, Wl2T, WcatT,
                                                   Wf2c, bias_cat, x_bf, h0mask);
    // bias_cat[1024:2080] from WbigT rows (coalesced) — needs pack_all done
    bias_comb_k<<<dim3(NBIG / 4), 256, 0, stream>>>(WbigT, bf2, b1, b2, b3, bias_cat);

    // Gpre: WcatT[1024:2112] = Wall^T @ Wf2^T   M=1088 N=128 K=1024, 34 blk
    mm<64, 64, 3, false, false><<<dim3(2 * 17), 256, 0, stream>>>(
        WbigT, 1024, Wf2c, 1024, 128, nullptr, nullptr, 0,
        WcatT + (size_t)1024 * 128, 128, 1024, 2);
    // G1: tmp12 = [relu(x@Wl1+bl1) | x@Wf1_top]     M=4096 N=256 K=1024, 256 blk
    mm<64, 64, 4, false, false><<<dim3(4 * 64), 256, 0, stream>>>(
        x_bf, DDIM, WaT, 1024, 256, bl1, nullptr, 0, tmp12, 256, 1024, 4);
    // G2: lifted = tanh(tmp12[:,:128] @ Wl2 + bl2)  M=4096 N=1024 K=128, 512 blk
    mm<64, 128, 2, false, false><<<dim3(8 * 64), 256, 0, stream>>>(
        tmp12, 256, Wl2T, 128, 1024, bl2, nullptr, 0, lifted, DDIM, 128, 8);
    // G3: tmp2 = relu(lifted@Wf1_bot + bf1 + tmp12[:,128:]) M=4096 N=128 K=1024, 256 blk
    mm<32, 64, 1, true, false><<<dim3(2 * 128), 256, 0, stream>>>(
        lifted, DDIM, Wf1bT, 1024, 128, bf1, tmp12 + 128, 256, tmp2, HDIM, 1024, 2);
    // G45: xdb = tmp2 @ [Wf2|Wcomb] + bias_cat (softplus on delta cols)
    //      M=4096 N=2080(pad 2112) K=128, 2112 blk
    mm<64, 64, 6, false, true><<<dim3(33 * 64), 256, 0, stream>>>(
        tmp2, HDIM, WcatT, 128, NCAT, bias_cat, nullptr, 0, xdb, NCATP, 128, 33);

    final_k<<<dim3(MROWS), 256, 0, stream>>>(xdb, Amat, h0, h0mask, out, last_h);
}

// Round 9
// 72.638 us; speedup vs baseline: 2.4360x; 1.2065x over previous
//
#include <hip/hip_runtime.h>
#include <cmath>

#define B_SZ 2
#define LSEQ 2048
#define DDIM 1024
#define NDIM 16
#define HDIM 128
#define MROWS (B_SZ * LSEQ)    // 4096
#define NBIG (DDIM + 2 * NDIM) // 1056
#define NPAD 1088              // NBIG padded to 64
#define NCAT (DDIM + NBIG)     // 2080: [x_tr | delta | Bm | Cm]
#define NCATP 2112             // NCAT padded to 64

typedef __bf16 bf16x8 __attribute__((ext_vector_type(8)));
typedef __bf16 bf16x4 __attribute__((ext_vector_type(4)));
typedef float f32x4 __attribute__((ext_vector_type(4)));

// async global->LDS, 16B/lane; LDS dest = wave-uniform base + lane*16
__device__ __forceinline__ void glds16(const __bf16* g, __bf16* l) {
    __builtin_amdgcn_global_load_lds(
        (const __attribute__((address_space(1))) unsigned int*)g,
        (__attribute__((address_space(3))) unsigned int*)l, 16, 0, 0);
}

// ---------------------------------------------------------------------------
// Preprocessing: weight transpose+cast, h0 mask, Wf2 row-major cast.
// ---------------------------------------------------------------------------
__device__ __forceinline__ void tcast_tile(const float* __restrict__ in,
                                           __bf16* __restrict__ out, int K, int N,
                                           int bx, int by, float (*t)[33]) {
    int tx = threadIdx.x & 31, ty = threadIdx.x >> 5;
    int n0 = bx * 32, k0 = by * 32;
    #pragma unroll
    for (int i = 0; i < 4; ++i) {
        int k = k0 + ty + i * 8, n = n0 + tx;
        t[ty + i * 8][tx] = (k < K && n < N) ? in[(size_t)k * N + n] : 0.f;
    }
    __syncthreads();
    #pragma unroll
    for (int i = 0; i < 4; ++i) {
        int n = n0 + ty + i * 8, k = k0 + tx;
        if (n < N && k < K) out[(size_t)n * K + k] = (__bf16)t[tx][ty + i * 8];
    }
}

__global__ __launch_bounds__(256) void pack_all(
    const float* W1, const float* W2, const float* W3, const float* Wl1,
    const float* Wl2, const float* Wf1, const float* Wf2,
    const float* bf2, const float* h0,
    __bf16* WbigT, __bf16* WaT, __bf16* Wf1bT, __bf16* Wl2T, __bf16* WcatT,
    __bf16* Wf2c, float* bias_cat, unsigned* h0mask) {
    __shared__ float t[32][33];
    const int bx = blockIdx.x, by = blockIdx.y, z = blockIdx.z;
    const int tid = threadIdx.x;
    switch (z) {
        case 0: tcast_tile(W1, WbigT, 1024, 1024, bx, by, t); break;
        case 1: if (bx < 4) tcast_tile(Wl1, WaT, 1024, 128, bx, by, t); break;
        case 2: if (bx < 4) tcast_tile(Wf1, WaT + 128 * 1024, 1024, 128, bx, by, t); break;
        case 3: if (bx < 4) tcast_tile(Wf1 + (size_t)1024 * 128, Wf1bT, 1024, 128, bx, by, t); break;
        case 4: if (by < 4) tcast_tile(Wl2, Wl2T, 128, 1024, bx, by, t); break;
        case 5: if (by < 4) tcast_tile(Wf2, WcatT, 128, 1024, bx, by, t); break; // WcatT rows 0..1023
        case 6: if (bx < 1) tcast_tile(W2, WbigT + (size_t)1024 * 1024, 1024, 16, bx, by, t); break;
        case 7: if (bx < 1) tcast_tile(W3, WbigT + (size_t)1040 * 1024, 1024, 16, bx, by, t); break;
        case 8: {
            if (by == 0 && bx < 4) { // bias_cat[0:1024] = bf2
                int i = bx * 256 + tid;
                bias_cat[i] = bf2[i];
            }
            if (by == 1 && bx < 32) { // zero WbigT pad rows 1056..1087
                int i = bx * 256 + tid;
                #pragma unroll
                for (int r = 0; r < 4; ++r) {
                    int e = i + r * 8192;
                    if (e < 32 * 1024) WbigT[(size_t)1056 * 1024 + e] = (__bf16)0.f;
                }
            }
            break;
        }
        case 9: { // cast Wf2 -> Wf2c [128][1024] bf16 row-major (Gpre Bt operand)
            if ((by * 32 + bx) < 32) {
                int id = (by * 32 + bx) * 256 + tid;
                #pragma unroll
                for (int j = 0; j < 4; ++j) {
                    int e = id + j * 8192;
                    float4 v = ((const float4*)Wf2)[e];
                    bf16x4 o2 = {(__bf16)v.x, (__bf16)v.y, (__bf16)v.z, (__bf16)v.w};
                    ((bf16x4*)Wf2c)[e] = o2;
                }
            }
            break;
        }
        case 10: { // h0 nonzero bitmask: bit d set iff h0[d,:] has a nonzero
            if (bx == 0 && by == 0) {
                __shared__ unsigned sm[32];
                if (tid < 32) sm[tid] = 0u;
                __syncthreads();
                unsigned nib = 0;
                #pragma unroll
                for (int j = 0; j < 4; ++j) {
                    int d = tid * 4 + j;
                    const uint4* hu = (const uint4*)(h0 + d * NDIM);
                    uint4 a0 = hu[0], a1 = hu[1], a2 = hu[2], a3 = hu[3];
                    unsigned nz = a0.x | a0.y | a0.z | a0.w | a1.x | a1.y | a1.z | a1.w |
                                  a2.x | a2.y | a2.z | a2.w | a3.x | a3.y | a3.z | a3.w;
                    if (nz) nib |= (1u << j);
                }
                if (nib) atomicOr(&sm[(tid * 4) >> 5], nib << ((tid * 4) & 31));
                __syncthreads();
                if (tid < 32) h0mask[tid] = sm[tid];
            }
            break;
        }
    }
}

// ---------------------------------------------------------------------------
// Core BMxBN / BK=64 double-buffered MFMA GEMM (device-side).
// A staged via glds16 (bf16) or reg-staged fp32->bf16 (AF32).
// 8-slot XOR swizzle: LDS(row,pos) holds global chunk pos^(row&7); reads
// apply the same XOR (involution, rule #21).
// ACT: 0 bias, 1 relu(+prev), 2 fast-tanh, 3 raw, 4 split128-relu,
//      6 cat-epilogue (bias; softplus on cols [1024,2048))
// ---------------------------------------------------------------------------
template <int BM, int BN, int ACT, bool ADD_PREV, bool GUARDN, bool AF32>
__device__ __forceinline__ void gemm_core(
    const void* Av, int lda, const __bf16* __restrict__ Bt, int ldb, int Ntot,
    const float* __restrict__ bias, const __bf16* __restrict__ prev, int ldp,
    __bf16* __restrict__ C, int ldc, int K, int bm, int bn,
    __bf16* As, __bf16* Bs) {
    constexpr int WM = BM / 2, WN = BN / 2, FM = WM / 16, FN = WN / 16;
    constexpr int ASZ = BM * 64, BSZ = BN * 64;
    const int tid = threadIdx.x;
    const int lane = tid & 63, w = tid >> 6;
    const int wr = w >> 1, wc = w & 1;
    const int g = lane >> 4, lr = lane & 15;
    const __bf16* A16 = (const __bf16*)Av;
    const float* A32 = (const float*)Av;

    auto stage = [&](int buf, int k0) {
        #pragma unroll
        for (int i = 0; i < BM / 32; ++i) {
            int D = i * 256 + tid;
            int row = D >> 3, pos = D & 7, c = pos ^ (row & 7);
            if constexpr (AF32) {
                const float* s = &A32[(size_t)(bm + row) * lda + k0 + c * 8];
                float4 v0 = *(const float4*)s;
                float4 v1 = *(const float4*)(s + 4);
                bf16x8 pk = {(__bf16)v0.x, (__bf16)v0.y, (__bf16)v0.z, (__bf16)v0.w,
                             (__bf16)v1.x, (__bf16)v1.y, (__bf16)v1.z, (__bf16)v1.w};
                *(bf16x8*)&As[buf * ASZ + row * 64 + pos * 8] = pk;
            } else {
                glds16(&A16[(size_t)(bm + row) * lda + k0 + c * 8],
                       &As[buf * ASZ + (i * 256 + w * 64) * 8]);
            }
        }
        #pragma unroll
        for (int i = 0; i < BN / 32; ++i) {
            int D = i * 256 + tid;
            int row = D >> 3, pos = D & 7, c = pos ^ (row & 7);
            glds16(&Bt[(size_t)(bn + row) * ldb + k0 + c * 8],
                   &Bs[buf * BSZ + (i * 256 + w * 64) * 8]);
        }
    };

    f32x4 acc[FM][FN] = {};
    const int x7 = lr & 7;
    const int ca[2] = {(g ^ x7) * 8, ((4 + g) ^ x7) * 8};
    const int arow0 = wr * WM + lr;
    const int brow0 = wc * WN + lr;

    const int nt = K >> 6;
    stage(0, 0);
    __syncthreads();
    for (int t = 0; t < nt; ++t) {
        if (t + 1 < nt) stage((t + 1) & 1, (t + 1) << 6);
        const __bf16* Ab = &As[(t & 1) * ASZ];
        const __bf16* Bb = &Bs[(t & 1) * BSZ];
        bf16x8 af[FM][2], bfr[FN][2];
        #pragma unroll
        for (int m = 0; m < FM; ++m)
            #pragma unroll
            for (int h = 0; h < 2; ++h)
                af[m][h] = *(const bf16x8*)&Ab[(arow0 + m * 16) * 64 + ca[h]];
        #pragma unroll
        for (int n = 0; n < FN; ++n)
            #pragma unroll
            for (int h = 0; h < 2; ++h)
                bfr[n][h] = *(const bf16x8*)&Bb[(brow0 + n * 16) * 64 + ca[h]];
        #pragma unroll
        for (int h = 0; h < 2; ++h)
            #pragma unroll
            for (int m = 0; m < FM; ++m)
                #pragma unroll
                for (int n = 0; n < FN; ++n)
                    acc[m][n] = __builtin_amdgcn_mfma_f32_16x16x32_bf16(
                        af[m][h], bfr[n][h], acc[m][n], 0, 0, 0);
        __syncthreads();
    }

    // epilogue: C/D layout col=lane&15, row=(lane>>4)*4+reg
    #pragma unroll
    for (int m = 0; m < FM; ++m) {
        #pragma unroll
        for (int n = 0; n < FN; ++n) {
            #pragma unroll
            for (int r = 0; r < 4; ++r) {
                int grow = bm + wr * WM + m * 16 + g * 4 + r;
                int gcol = bn + wc * WN + n * 16 + lr;
                if (!GUARDN || gcol < Ntot) {
                    float v = acc[m][n][r];
                    if (ACT == 0) {
                        v += bias[gcol];
                    } else if (ACT == 1) {
                        v += bias[gcol];
                        if (ADD_PREV) v += (float)prev[(size_t)grow * ldp + gcol];
                        v = fmaxf(v, 0.f);
                    } else if (ACT == 2) { // fast tanh: 1 - 2/(1+e^2v)
                        v += bias[gcol];
                        float e = __expf(2.f * v);
                        v = 1.f - 2.f * __builtin_amdgcn_rcpf(e + 1.f);
                    } else if (ACT == 3) {
                        // raw, no bias (Gpre)
                    } else if (ACT == 4) {
                        if (gcol < HDIM) v = fmaxf(v + bias[gcol], 0.f);
                    } else if (ACT == 6) {
                        v += bias[gcol];
                        if (gcol >= DDIM && gcol < 2 * DDIM) { // delta: softplus
                            float e = __expf(-fabsf(v));
                            v = fmaxf(v, 0.f) + __logf(1.f + e);
                        }
                    }
                    C[(size_t)grow * ldc + gcol] = (__bf16)v;
                }
            }
        }
    }
}

// thin global wrapper (1-D grid, bijective XCD swizzle when NB%8==0)
template <int BM, int BN, int ACT, bool ADD_PREV, bool GUARDN>
__global__ __launch_bounds__(256) void mm(const __bf16* __restrict__ A, int lda,
                                          const __bf16* __restrict__ Bt, int ldb, int Ntot,
                                          const float* __restrict__ bias,
                                          const __bf16* __restrict__ prev, int ldp,
                                          __bf16* __restrict__ C, int ldc, int K, int nbx) {
    __shared__ __bf16 As[2 * BM * 64];
    __shared__ __bf16 Bs[2 * BN * 64];
    const int NB = gridDim.x;
    const int aid = ((NB & 7) == 0)
                        ? (blockIdx.x & 7) * (NB >> 3) + (blockIdx.x >> 3)
                        : blockIdx.x;
    const int bn = (aid % nbx) * BN, bm = (aid / nbx) * BM;
    gemm_core<BM, BN, ACT, ADD_PREV, GUARDN, false>(
        A, lda, Bt, ldb, Ntot, bias, prev, ldp, C, ldc, K, bm, bn, As, Bs);
}

// ---------------------------------------------------------------------------
// Merged stage-2 launch: blocks [0,512) G1 (x fp32 reg-staged);
// [512,546) Gpre (Wcomb = Wall^T @ Wf2^T); [546,810) bias fold.
// All three depend only on pack_all.
// ---------------------------------------------------------------------------
__global__ __launch_bounds__(256) void stage2_k(
    const float* __restrict__ x, const __bf16* __restrict__ WaT,
    const __bf16* __restrict__ WbigT, const __bf16* __restrict__ Wf2c,
    const float* __restrict__ bf2, const float* __restrict__ b1,
    const float* __restrict__ b2, const float* __restrict__ b3,
    const float* __restrict__ bl1,
    __bf16* __restrict__ tmp12, __bf16* __restrict__ WcatT,
    float* __restrict__ bias_cat) {
    __shared__ __bf16 As[2 * 64 * 64];
    __shared__ __bf16 Bs[2 * 64 * 64];
    const int b = blockIdx.x;
    if (b < 512) {
        // G1: tmp12 = [relu(x@Wl1+bl1) | x@Wf1_top]  M=4096 N=256 K=1024
        // BM=32 BN=64, nbx=4; bijective swizzle within 512
        const int aid = (b & 7) * 64 + (b >> 3);
        const int bn = (aid & 3) * 64, bm = (aid >> 2) * 32;
        gemm_core<32, 64, 4, false, false, true>(
            x, DDIM, WaT, 1024, 256, bl1, nullptr, 0, tmp12, 256, 1024, bm, bn, As, Bs);
    } else if (b < 546) {
        // Gpre: WcatT[1024:2112] = Wall^T @ Wf2^T  M=1088 N=128 K=1024
        const int aid = b - 512;
        const int bn = (aid & 1) * 64, bm = (aid >> 1) * 64;
        gemm_core<64, 64, 3, false, false, false>(
            WbigT, 1024, Wf2c, 1024, 128, nullptr, nullptr, 0,
            WcatT + (size_t)1024 * 128, 128, 1024, bm, bn, As, Bs);
    } else {
        // bias fold: bias_cat[1024+n] = ball[n] + sum_d bf2[d]*Wall[d][n]
        const int n = (b - 546) * 4 + (threadIdx.x >> 6);
        const int lane = threadIdx.x & 63;
        const __bf16* wr = WbigT + (size_t)n * 1024 + lane * 16;
        float s = 0.f;
        #pragma unroll
        for (int i = 0; i < 2; ++i) {
            bf16x8 wv = *(const bf16x8*)&wr[i * 8];
            float4 f0 = *(const float4*)&bf2[lane * 16 + i * 8];
            float4 f1 = *(const float4*)&bf2[lane * 16 + i * 8 + 4];
            s += (float)wv[0] * f0.x + (float)wv[1] * f0.y + (float)wv[2] * f0.z +
                 (float)wv[3] * f0.w + (float)wv[4] * f1.x + (float)wv[5] * f1.y +
                 (float)wv[6] * f1.z + (float)wv[7] * f1.w;
        }
        #pragma unroll
        for (int off = 32; off; off >>= 1) s += __shfl_down(s, off);
        if (lane == 0) {
            float base = (n < DDIM) ? b1[n]
                       : (n < DDIM + NDIM) ? b2[n - DDIM] : b3[n - DDIM - NDIM];
            bias_cat[DDIM + n] = base + s;
        }
    }
}

// ---------------------------------------------------------------------------
// Final fusion. xdb row = [x_tr(1024) | delta(1024) | Bm(16) | Cm(16)], ld NCATP.
// ---------------------------------------------------------------------------
__global__ __launch_bounds__(256) void final_k(const __bf16* __restrict__ xdb,
                                               const float* __restrict__ A,
                                               const float* __restrict__ h0,
                                               const unsigned* __restrict__ h0mask,
                                               float* __restrict__ out,
                                               float* __restrict__ last_h) {
    const int row = blockIdx.x;
    const int tid = threadIdx.x;
    const __bf16* rp = xdb + (size_t)row * NCATP;
    __shared__ float sC[NDIM], sB[NDIM];
    if (tid < NDIM) sB[tid] = (float)rp[2 * DDIM + tid];
    else if (tid >= 32 && tid < 32 + NDIM)
        sC[tid - 32] = (float)rp[2 * DDIM + NDIM + (tid - 32)];
    __syncthreads();
    float cb = 0.f;
    #pragma unroll
    for (int n = 0; n < NDIM; ++n) cb += sC[n] * sB[n];

    const int l = row & (LSEQ - 1);
    const int b = row >> 11;
    const bool is_last = (l == LSEQ - 1);

    const int d0 = tid * 4;
    bf16x4 xv = *(const bf16x4*)&rp[d0];
    bf16x4 dv = *(const bf16x4*)&rp[DDIM + d0];
    const unsigned nib = (h0mask[d0 >> 5] >> (d0 & 31)) & 0xFu;
    float4 o;
    float* op = &o.x;
    #pragma unroll
    for (int j = 0; j < 4; ++j) {
        const int d = d0 + j;
        const float xd = (float)xv[j] * (float)dv[j];
        float s = 0.f;
        if (!((nib >> j) & 1u)) {
            if (is_last) {
                #pragma unroll
                for (int n = 0; n < NDIM; ++n)
                    last_h[((size_t)b * DDIM + d) * NDIM + n] = xd * sB[n];
            }
        } else {
            const float de = (float)dv[j];
            const float* hf = h0 + d * NDIM;
            #pragma unroll
            for (int n = 0; n < NDIM; ++n) {
                float z = de * A[d * NDIM + n];
                float c = (z > 0.f) ? z : __expf(z) - 1.f;
                float da = __expf(-c);
                float h0v = hf[n];
                s += sC[n] * da * h0v;
                if (is_last)
                    last_h[((size_t)b * DDIM + d) * NDIM + n] = da * h0v + xd * sB[n];
            }
        }
        op[j] = xd * cb + s;
    }
    *(float4*)&out[(size_t)row * DDIM + d0] = o;
}

extern "C" void kernel_launch(void* const* d_in, const int* in_sizes, int n_in,
                              void* d_out, int out_size, void* d_ws, size_t ws_size,
                              hipStream_t stream) {
    const float* x   = (const float*)d_in[0];
    const float* W1  = (const float*)d_in[1];
    const float* b1  = (const float*)d_in[2];
    const float* W2  = (const float*)d_in[3];
    const float* b2  = (const float*)d_in[4];
    const float* W3  = (const float*)d_in[5];
    const float* b3  = (const float*)d_in[6];
    const float* Wl1 = (const float*)d_in[7];
    const float* bl1 = (const float*)d_in[8];
    const float* Wl2 = (const float*)d_in[9];
    const float* bl2 = (const float*)d_in[10];
    const float* Wf1 = (const float*)d_in[11];
    const float* bf1 = (const float*)d_in[12];
    const float* Wf2 = (const float*)d_in[13];
    const float* bf2 = (const float*)d_in[14];
    const float* h0  = (const float*)d_in[15];
    const float* Amat= (const float*)d_in[16];

    float* out    = (float*)d_out;
    float* last_h = (float*)d_out + (size_t)MROWS * DDIM;

    __bf16* wsb = (__bf16*)d_ws;
    size_t o = 0;
    auto alloc = [&](size_t n) { __bf16* p = wsb + o; o += n; return p; };
    __bf16* WaT    = alloc(256 * 1024);             // [Wl1 | Wf1_top]^T
    __bf16* Wf1bT  = alloc(128 * 1024);
    __bf16* Wl2T   = alloc(1024 * 128);
    __bf16* WbigT  = alloc((size_t)NPAD * 1024);    // [W1 | W2 | W3 | pad]^T
    __bf16* WcatT  = alloc((size_t)NCATP * 128);    // [Wf2 | Wcomb | pad]^T
    __bf16* Wf2c   = alloc(128 * 1024);             // Wf2 bf16 row-major
    __bf16* tmp12  = alloc((size_t)MROWS * 256);    // [relu(x@Wl1+bl1) | x@Wf1_top]
    __bf16* lifted = alloc((size_t)MROWS * DDIM);
    __bf16* tmp2   = alloc((size_t)MROWS * HDIM);
    __bf16* xdb    = alloc((size_t)MROWS * NCATP);  // [x_tr | delta | Bm | Cm]
    float*  bias_cat = (float*)(wsb + o); o += 2 * NCATP;
    unsigned* h0mask = (unsigned*)(wsb + o);

    // 1. pack (weights only; no x cast anymore)
    pack_all<<<dim3(32, 32, 11), 256, 0, stream>>>(W1, W2, W3, Wl1, Wl2, Wf1, Wf2,
                                                   bf2, h0,
                                                   WbigT, WaT, Wf1bT, Wl2T, WcatT,
                                                   Wf2c, bias_cat, h0mask);
    // 2. merged: G1 (512 blk) + Gpre (34 blk) + bias fold (264 blk)
    stage2_k<<<dim3(810), 256, 0, stream>>>(x, WaT, WbigT, Wf2c, bf2, b1, b2, b3,
                                            bl1, tmp12, WcatT, bias_cat);
    // 3. G2: lifted = tanh(tmp12[:,:128] @ Wl2 + bl2)  M=4096 N=1024 K=128, 512 blk
    mm<64, 128, 2, false, false><<<dim3(8 * 64), 256, 0, stream>>>(
        tmp12, 256, Wl2T, 128, 1024, bl2, nullptr, 0, lifted, DDIM, 128, 8);
    // 4. G3: tmp2 = relu(lifted@Wf1_bot + bf1 + tmp12[:,128:]) M=4096 N=128 K=1024, 512 blk
    mm<32, 32, 1, true, false><<<dim3(4 * 128), 256, 0, stream>>>(
        lifted, DDIM, Wf1bT, 1024, 128, bf1, tmp12 + 128, 256, tmp2, HDIM, 1024, 4);
    // 5. G45: xdb = tmp2 @ [Wf2|Wcomb] + bias_cat (softplus on delta cols)
    //    M=4096 N=2080(pad 2112) K=128, 2112 blk
    mm<64, 64, 6, false, true><<<dim3(33 * 64), 256, 0, stream>>>(
        tmp2, HDIM, WcatT, 128, NCAT, bias_cat, nullptr, 0, xdb, NCATP, 128, 33);
    // 6. final
    final_k<<<dim3(MROWS), 256, 0, stream>>>(xdb, Amat, h0, h0mask, out, last_h);
}

// Round 10
// 63.443 us; speedup vs baseline: 2.7891x; 1.1449x over previous
//
#include <hip/hip_runtime.h>
#include <cmath>

#define B_SZ 2
#define LSEQ 2048
#define DDIM 1024
#define NDIM 16
#define HDIM 128
#define MROWS (B_SZ * LSEQ)    // 4096
#define NBIG (DDIM + 2 * NDIM) // 1056
#define NPAD 1088              // NBIG padded to 64
#define NPAIR 2048             // pair-layout cols: 128 groups x [xt16|de16]

typedef __bf16 bf16x8 __attribute__((ext_vector_type(8)));
typedef __bf16 bf16x4 __attribute__((ext_vector_type(4)));
typedef float f32x4 __attribute__((ext_vector_type(4)));

// async global->LDS, 16B/lane; LDS dest = wave-uniform base + lane*16
__device__ __forceinline__ void glds16(const __bf16* g, __bf16* l) {
    __builtin_amdgcn_global_load_lds(
        (const __attribute__((address_space(1))) unsigned int*)g,
        (__attribute__((address_space(3))) unsigned int*)l, 16, 0, 0);
}

// pair-layout row slots
__device__ __forceinline__ int slot_xt(int d) { return (d >> 4) * 32 + (d & 15); }
__device__ __forceinline__ int slot_de(int d) { return (d >> 4) * 32 + 16 + (d & 15); }

// ---------------------------------------------------------------------------
// Preprocessing: weight transpose+cast, h0 mask, Wf2 row-major cast.
// ---------------------------------------------------------------------------
__device__ __forceinline__ void tcast_tile(const float* __restrict__ in,
                                           __bf16* __restrict__ out, int K, int N,
                                           int bx, int by, float (*t)[33]) {
    int tx = threadIdx.x & 31, ty = threadIdx.x >> 5;
    int n0 = bx * 32, k0 = by * 32;
    #pragma unroll
    for (int i = 0; i < 4; ++i) {
        int k = k0 + ty + i * 8, n = n0 + tx;
        t[ty + i * 8][tx] = (k < K && n < N) ? in[(size_t)k * N + n] : 0.f;
    }
    __syncthreads();
    #pragma unroll
    for (int i = 0; i < 4; ++i) {
        int n = n0 + ty + i * 8, k = k0 + tx;
        if (n < N && k < K) out[(size_t)n * K + k] = (__bf16)t[tx][ty + i * 8];
    }
}

// Wf2 [128][1024] -> WpairT xt slots (row slot_xt(n), ld 128)
__device__ __forceinline__ void tcast_pair_tile(const float* __restrict__ in,
                                                __bf16* __restrict__ out,
                                                int bx, int by, float (*t)[33]) {
    int tx = threadIdx.x & 31, ty = threadIdx.x >> 5;
    int n0 = bx * 32, k0 = by * 32;
    #pragma unroll
    for (int i = 0; i < 4; ++i) {
        int k = k0 + ty + i * 8, n = n0 + tx;
        t[ty + i * 8][tx] = in[(size_t)k * 1024 + n];
    }
    __syncthreads();
    #pragma unroll
    for (int i = 0; i < 4; ++i) {
        int n = n0 + ty + i * 8, k = k0 + tx;
        out[(size_t)slot_xt(n) * 128 + k] = (__bf16)t[tx][ty + i * 8];
    }
}

__global__ __launch_bounds__(256) void pack_all(
    const float* W1, const float* W2, const float* W3, const float* Wl1,
    const float* Wl2, const float* Wf1, const float* Wf2,
    const float* bf2, const float* h0,
    __bf16* WbigT, __bf16* WaT, __bf16* Wf1bT, __bf16* Wl2T, __bf16* WpairT,
    __bf16* Wf2c, float* bias_pair, unsigned* h0mask) {
    __shared__ float t[32][33];
    const int bx = blockIdx.x, by = blockIdx.y, z = blockIdx.z;
    const int tid = threadIdx.x;
    switch (z) {
        case 0: tcast_tile(W1, WbigT, 1024, 1024, bx, by, t); break;
        case 1: if (bx < 4) tcast_tile(Wl1, WaT, 1024, 128, bx, by, t); break;
        case 2: if (bx < 4) tcast_tile(Wf1, WaT + 128 * 1024, 1024, 128, bx, by, t); break;
        case 3: if (bx < 4) tcast_tile(Wf1 + (size_t)1024 * 128, Wf1bT, 1024, 128, bx, by, t); break;
        case 4: if (by < 4) tcast_tile(Wl2, Wl2T, 128, 1024, bx, by, t); break;
        case 5: if (by < 4) tcast_pair_tile(Wf2, WpairT, bx, by, t); break; // xt slots
        case 6: if (bx < 1) tcast_tile(W2, WbigT + (size_t)1024 * 1024, 1024, 16, bx, by, t); break;
        case 7: if (bx < 1) tcast_tile(W3, WbigT + (size_t)1040 * 1024, 1024, 16, bx, by, t); break;
        case 8: {
            if (by == 0 && bx < 4) { // xt bias = bf2, scattered to pair slots
                int i = bx * 256 + tid;
                bias_pair[slot_xt(i)] = bf2[i];
            }
            if (by == 1 && bx < 32) { // zero WbigT pad rows 1056..1087
                int i = bx * 256 + tid;
                #pragma unroll
                for (int r = 0; r < 4; ++r) {
                    int e = i + r * 8192;
                    if (e < 32 * 1024) WbigT[(size_t)1056 * 1024 + e] = (__bf16)0.f;
                }
            }
            break;
        }
        case 9: { // cast Wf2 -> Wf2c [128][1024] bf16 row-major (Gpre Bt operand)
            if ((by * 32 + bx) < 32) {
                int id = (by * 32 + bx) * 256 + tid;
                #pragma unroll
                for (int j = 0; j < 4; ++j) {
                    int e = id + j * 8192;
                    float4 v = ((const float4*)Wf2)[e];
                    bf16x4 o2 = {(__bf16)v.x, (__bf16)v.y, (__bf16)v.z, (__bf16)v.w};
                    ((bf16x4*)Wf2c)[e] = o2;
                }
            }
            break;
        }
        case 10: { // h0 nonzero bitmask: bit d set iff h0[d,:] has a nonzero
            if (bx == 0 && by == 0) {
                __shared__ unsigned sm[32];
                if (tid < 32) sm[tid] = 0u;
                __syncthreads();
                unsigned nib = 0;
                #pragma unroll
                for (int j = 0; j < 4; ++j) {
                    int d = tid * 4 + j;
                    const uint4* hu = (const uint4*)(h0 + d * NDIM);
                    uint4 a0 = hu[0], a1 = hu[1], a2 = hu[2], a3 = hu[3];
                    unsigned nz = a0.x | a0.y | a0.z | a0.w | a1.x | a1.y | a1.z | a1.w |
                                  a2.x | a2.y | a2.z | a2.w | a3.x | a3.y | a3.z | a3.w;
                    if (nz) nib |= (1u << j);
                }
                if (nib) atomicOr(&sm[(tid * 4) >> 5], nib << ((tid * 4) & 31));
                __syncthreads();
                if (tid < 32) h0mask[tid] = sm[tid];
            }
            break;
        }
    }
}

// ---------------------------------------------------------------------------
// Core BMxBN / BK=64 double-buffered MFMA GEMM.
// ACT: 1 relu(+prev), 2 fast-tanh, 4 split128-relu,
//      7 pair-scatter raw write (Gpre): row n<1024 -> slot_de(n); else 2048+(n-1024)
// ---------------------------------------------------------------------------
template <int BM, int BN, int ACT, bool ADD_PREV, bool GUARDN, bool AF32>
__device__ __forceinline__ void gemm_core(
    const void* Av, int lda, const __bf16* __restrict__ Bt, int ldb, int Ntot,
    const float* __restrict__ bias, const __bf16* __restrict__ prev, int ldp,
    __bf16* __restrict__ C, int ldc, int K, int bm, int bn,
    __bf16* As, __bf16* Bs) {
    constexpr int WM = BM / 2, WN = BN / 2, FM = WM / 16, FN = WN / 16;
    constexpr int ASZ = BM * 64, BSZ = BN * 64;
    const int tid = threadIdx.x;
    const int lane = tid & 63, w = tid >> 6;
    const int wr = w >> 1, wc = w & 1;
    const int g = lane >> 4, lr = lane & 15;
    const __bf16* A16 = (const __bf16*)Av;
    const float* A32 = (const float*)Av;

    auto stage = [&](int buf, int k0) {
        #pragma unroll
        for (int i = 0; i < BM / 32; ++i) {
            int D = i * 256 + tid;
            int row = D >> 3, pos = D & 7, c = pos ^ (row & 7);
            if constexpr (AF32) {
                const float* s = &A32[(size_t)(bm + row) * lda + k0 + c * 8];
                float4 v0 = *(const float4*)s;
                float4 v1 = *(const float4*)(s + 4);
                bf16x8 pk = {(__bf16)v0.x, (__bf16)v0.y, (__bf16)v0.z, (__bf16)v0.w,
                             (__bf16)v1.x, (__bf16)v1.y, (__bf16)v1.z, (__bf16)v1.w};
                *(bf16x8*)&As[buf * ASZ + row * 64 + pos * 8] = pk;
            } else {
                glds16(&A16[(size_t)(bm + row) * lda + k0 + c * 8],
                       &As[buf * ASZ + (i * 256 + w * 64) * 8]);
            }
        }
        #pragma unroll
        for (int i = 0; i < BN / 32; ++i) {
            int D = i * 256 + tid;
            int row = D >> 3, pos = D & 7, c = pos ^ (row & 7);
            glds16(&Bt[(size_t)(bn + row) * ldb + k0 + c * 8],
                   &Bs[buf * BSZ + (i * 256 + w * 64) * 8]);
        }
    };

    f32x4 acc[FM][FN] = {};
    const int x7 = lr & 7;
    const int ca[2] = {(g ^ x7) * 8, ((4 + g) ^ x7) * 8};
    const int arow0 = wr * WM + lr;
    const int brow0 = wc * WN + lr;

    const int nt = K >> 6;
    stage(0, 0);
    __syncthreads();
    for (int t = 0; t < nt; ++t) {
        if (t + 1 < nt) stage((t + 1) & 1, (t + 1) << 6);
        const __bf16* Ab = &As[(t & 1) * ASZ];
        const __bf16* Bb = &Bs[(t & 1) * BSZ];
        bf16x8 af[FM][2], bfr[FN][2];
        #pragma unroll
        for (int m = 0; m < FM; ++m)
            #pragma unroll
            for (int h = 0; h < 2; ++h)
                af[m][h] = *(const bf16x8*)&Ab[(arow0 + m * 16) * 64 + ca[h]];
        #pragma unroll
        for (int n = 0; n < FN; ++n)
            #pragma unroll
            for (int h = 0; h < 2; ++h)
                bfr[n][h] = *(const bf16x8*)&Bb[(brow0 + n * 16) * 64 + ca[h]];
        #pragma unroll
        for (int h = 0; h < 2; ++h)
            #pragma unroll
            for (int m = 0; m < FM; ++m)
                #pragma unroll
                for (int n = 0; n < FN; ++n)
                    acc[m][n] = __builtin_amdgcn_mfma_f32_16x16x32_bf16(
                        af[m][h], bfr[n][h], acc[m][n], 0, 0, 0);
        __syncthreads();
    }

    // epilogue: C/D layout col=lane&15, row=(lane>>4)*4+reg
    #pragma unroll
    for (int m = 0; m < FM; ++m) {
        #pragma unroll
        for (int n = 0; n < FN; ++n) {
            #pragma unroll
            for (int r = 0; r < 4; ++r) {
                int grow = bm + wr * WM + m * 16 + g * 4 + r;
                int gcol = bn + wc * WN + n * 16 + lr;
                if (!GUARDN || gcol < Ntot) {
                    float v = acc[m][n][r];
                    int orow = grow;
                    if (ACT == 1) {
                        v += bias[gcol];
                        if (ADD_PREV) v += (float)prev[(size_t)grow * ldp + gcol];
                        v = fmaxf(v, 0.f);
                    } else if (ACT == 2) { // fast tanh: 1 - 2/(1+e^2v)
                        v += bias[gcol];
                        float e = __expf(2.f * v);
                        v = 1.f - 2.f * __builtin_amdgcn_rcpf(e + 1.f);
                    } else if (ACT == 4) {
                        if (gcol < HDIM) v = fmaxf(v + bias[gcol], 0.f);
                    } else if (ACT == 7) { // Gpre pair-scatter, raw
                        orow = (grow < 1024) ? slot_de(grow) : 2048 + (grow - 1024);
                    }
                    C[(size_t)orow * ldc + gcol] = (__bf16)v;
                }
            }
        }
    }
}

// thin global wrapper (1-D grid, bijective XCD swizzle when NB%8==0)
template <int BM, int BN, int ACT, bool ADD_PREV, bool GUARDN>
__global__ __launch_bounds__(256) void mm(const __bf16* __restrict__ A, int lda,
                                          const __bf16* __restrict__ Bt, int ldb, int Ntot,
                                          const float* __restrict__ bias,
                                          const __bf16* __restrict__ prev, int ldp,
                                          __bf16* __restrict__ C, int ldc, int K, int nbx) {
    __shared__ __bf16 As[2 * BM * 64];
    __shared__ __bf16 Bs[2 * BN * 64];
    const int NB = gridDim.x;
    const int aid = ((NB & 7) == 0)
                        ? (blockIdx.x & 7) * (NB >> 3) + (blockIdx.x >> 3)
                        : blockIdx.x;
    const int bn = (aid % nbx) * BN, bm = (aid / nbx) * BM;
    gemm_core<BM, BN, ACT, ADD_PREV, GUARDN, false>(
        A, lda, Bt, ldb, Ntot, bias, prev, ldp, C, ldc, K, bm, bn, As, Bs);
}

// ---------------------------------------------------------------------------
// Merged stage-2: [0,512) G1 (x fp32 reg-staged); [512,546) Gpre->WpairT;
// [546,810) bias fold -> bias_pair (delta + BC slots).
// ---------------------------------------------------------------------------
__global__ __launch_bounds__(256) void stage2_k(
    const float* __restrict__ x, const __bf16* __restrict__ WaT,
    const __bf16* __restrict__ WbigT, const __bf16* __restrict__ Wf2c,
    const float* __restrict__ bf2, const float* __restrict__ b1,
    const float* __restrict__ b2, const float* __restrict__ b3,
    const float* __restrict__ bl1,
    __bf16* __restrict__ tmp12, __bf16* __restrict__ WpairT,
    float* __restrict__ bias_pair) {
    __shared__ __bf16 As[2 * 64 * 64];
    __shared__ __bf16 Bs[2 * 64 * 64];
    const int b = blockIdx.x;
    if (b < 512) {
        // G1: tmp12 = [relu(x@Wl1+bl1) | x@Wf1_top]  M=4096 N=256 K=1024
        const int aid = (b & 7) * 64 + (b >> 3);
        const int bn = (aid & 3) * 64, bm = (aid >> 2) * 32;
        gemm_core<32, 64, 4, false, false, true>(
            x, DDIM, WaT, 1024, 256, bl1, nullptr, 0, tmp12, 256, 1024, bm, bn, As, Bs);
    } else if (b < 546) {
        // Gpre: Wcomb cols scattered into WpairT delta/BC slots  M=1088 N=128 K=1024
        const int aid = b - 512;
        const int bn = (aid & 1) * 64, bm = (aid >> 1) * 64;
        gemm_core<64, 64, 7, false, false, false>(
            WbigT, 1024, Wf2c, 1024, 128, nullptr, nullptr, 0,
            WpairT, 128, 1024, bm, bn, As, Bs);
    } else {
        // bias fold: fold(n) = ball[n] + sum_d bf2[d]*Wall[d][n] -> pair/BC slots
        const int n = (b - 546) * 4 + (threadIdx.x >> 6);
        const int lane = threadIdx.x & 63;
        const __bf16* wr = WbigT + (size_t)n * 1024 + lane * 16;
        float s = 0.f;
        #pragma unroll
        for (int i = 0; i < 2; ++i) {
            bf16x8 wv = *(const bf16x8*)&wr[i * 8];
            float4 f0 = *(const float4*)&bf2[lane * 16 + i * 8];
            float4 f1 = *(const float4*)&bf2[lane * 16 + i * 8 + 4];
            s += (float)wv[0] * f0.x + (float)wv[1] * f0.y + (float)wv[2] * f0.z +
                 (float)wv[3] * f0.w + (float)wv[4] * f1.x + (float)wv[5] * f1.y +
                 (float)wv[6] * f1.z + (float)wv[7] * f1.w;
        }
        #pragma unroll
        for (int off = 32; off; off >>= 1) s += __shfl_down(s, off);
        if (lane == 0) {
            float base = (n < DDIM) ? b1[n]
                       : (n < DDIM + NDIM) ? b2[n - DDIM] : b3[n - DDIM - NDIM];
            int sl = (n < DDIM) ? slot_de(n) : 2048 + (n - DDIM);
            bias_pair[sl] = base + s;
        }
    }
}

// ---------------------------------------------------------------------------
// bc_k: Bm/Cm/cb per row from tmp2 (f32 accumulate). 256 blocks x 16 rows.
// ---------------------------------------------------------------------------
__global__ __launch_bounds__(256) void bc_k(const __bf16* __restrict__ tmp2,
                                            const __bf16* __restrict__ WbcT,
                                            const float* __restrict__ bias_bc,
                                            __bf16* __restrict__ Bmv,
                                            __bf16* __restrict__ Cmv,
                                            float* __restrict__ cbv) {
    __shared__ __bf16 t2[16][128];
    const int blk = blockIdx.x, tid = threadIdx.x;
    const int rr = tid >> 4, cc = tid & 15;
    *(bf16x8*)&t2[rr][cc * 8] =
        *(const bf16x8*)&tmp2[(size_t)(blk * 16 + rr) * 128 + cc * 8];
    __syncthreads();
    float sB = bias_bc[cc], sC = bias_bc[16 + cc];
    #pragma unroll
    for (int i = 0; i < 16; ++i) {
        bf16x8 tv = *(const bf16x8*)&t2[rr][i * 8];
        bf16x8 wb = *(const bf16x8*)&WbcT[(size_t)cc * 128 + i * 8];
        bf16x8 wc2 = *(const bf16x8*)&WbcT[(size_t)(16 + cc) * 128 + i * 8];
        #pragma unroll
        for (int j = 0; j < 8; ++j) {
            float tvf = (float)tv[j];
            sB += tvf * (float)wb[j];
            sC += tvf * (float)wc2[j];
        }
    }
    const int row = blk * 16 + rr;
    Bmv[row * NDIM + cc] = (__bf16)sB;
    Cmv[row * NDIM + cc] = (__bf16)sC;
    float p = sB * sC;
    #pragma unroll
    for (int m2 = 1; m2 < 16; m2 <<= 1) p += __shfl_xor(p, m2);
    if (cc == 0) cbv[row] = p;
}

// ---------------------------------------------------------------------------
// mm_pairs: [xt|de] pair GEMM, fused final epilogue. M=4096 N=2048 K=128.
// BM=BN=64, nbx=32, 2048 blocks. Thread holds xt in acc[m][0], delta in
// acc[m][1] for the same d -> out/last_h written directly; no xdb buffer.
// ---------------------------------------------------------------------------
__global__ __launch_bounds__(256) void mm_pairs(
    const __bf16* __restrict__ tmp2, const __bf16* __restrict__ WpairT,
    const float* __restrict__ bias_pair, const float* __restrict__ cbv,
    const __bf16* __restrict__ Bmv, const __bf16* __restrict__ Cmv,
    const float* __restrict__ Amat, const float* __restrict__ h0,
    const unsigned* __restrict__ h0mask,
    float* __restrict__ out, float* __restrict__ last_h) {
    __shared__ __bf16 As[2 * 4096];
    __shared__ __bf16 Bs[2 * 4096];
    const int NB = gridDim.x; // 2048
    const int aid = (blockIdx.x & 7) * (NB >> 3) + (blockIdx.x >> 3);
    const int bn = (aid & 31) * 64, bm = (aid >> 5) * 64;
    const int tid = threadIdx.x;
    const int lane = tid & 63, w = tid >> 6;
    const int wr = w >> 1, wc = w & 1;
    const int g = lane >> 4, lr = lane & 15;

    auto stage = [&](int buf, int k0) {
        #pragma unroll
        for (int i = 0; i < 2; ++i) {
            int D = i * 256 + tid;
            int row = D >> 3, pos = D & 7, c = pos ^ (row & 7);
            glds16(&tmp2[(size_t)(bm + row) * 128 + k0 + c * 8],
                   &As[buf * 4096 + (i * 256 + w * 64) * 8]);
            glds16(&WpairT[(size_t)(bn + row) * 128 + k0 + c * 8],
                   &Bs[buf * 4096 + (i * 256 + w * 64) * 8]);
        }
    };

    f32x4 acc[2][2] = {};
    const int x7 = lr & 7;
    const int ca[2] = {(g ^ x7) * 8, ((4 + g) ^ x7) * 8};
    const int arow0 = wr * 32 + lr, brow0 = wc * 32 + lr;
    stage(0, 0);
    __syncthreads();
    #pragma unroll
    for (int t = 0; t < 2; ++t) {
        if (t == 0) stage(1, 64);
        const __bf16* Ab = &As[t * 4096];
        const __bf16* Bb = &Bs[t * 4096];
        bf16x8 af[2][2], bfr[2][2];
        #pragma unroll
        for (int m = 0; m < 2; ++m)
            #pragma unroll
            for (int h = 0; h < 2; ++h) {
                af[m][h] = *(const bf16x8*)&Ab[(arow0 + m * 16) * 64 + ca[h]];
                bfr[m][h] = *(const bf16x8*)&Bb[(brow0 + m * 16) * 64 + ca[h]];
            }
        #pragma unroll
        for (int h = 0; h < 2; ++h)
            #pragma unroll
            for (int m = 0; m < 2; ++m)
                #pragma unroll
                for (int n = 0; n < 2; ++n)
                    acc[m][n] = __builtin_amdgcn_mfma_f32_16x16x32_bf16(
                        af[m][h], bfr[n][h], acc[m][n], 0, 0, 0);
        __syncthreads();
    }

    // epilogue: d = group*16 + lr; xt = acc[m][0], de = acc[m][1]
    const int d = ((bn + wc * 32) >> 1) + lr;
    const float bx_ = bias_pair[bn + wc * 32 + lr];
    const float bd_ = bias_pair[bn + wc * 32 + 16 + lr];
    const bool msk = (h0mask[d >> 5] >> (d & 31)) & 1u;
    #pragma unroll
    for (int m = 0; m < 2; ++m) {
        #pragma unroll
        for (int r = 0; r < 4; ++r) {
            const int row = bm + wr * 32 + m * 16 + g * 4 + r;
            const float xt = acc[m][0][r] + bx_;
            const float dr = acc[m][1][r] + bd_;
            const float e = __expf(-fabsf(dr));
            const float de = fmaxf(dr, 0.f) + __logf(1.f + e);
            const float xd = xt * de;
            float res = xd * cbv[row];
            const bool is_last = (row & (LSEQ - 1)) == (LSEQ - 1);
            if (msk) {
                float s = 0.f;
                #pragma unroll
                for (int n = 0; n < NDIM; ++n) {
                    float z = de * Amat[d * NDIM + n];
                    float c2 = (z > 0.f) ? z : __expf(z) - 1.f;
                    float da = __expf(-c2);
                    float h0v = h0[d * NDIM + n];
                    s += (float)Cmv[row * NDIM + n] * da * h0v;
                    if (is_last)
                        last_h[(((size_t)(row >> 11)) * DDIM + d) * NDIM + n] =
                            da * h0v + xd * (float)Bmv[row * NDIM + n];
                }
                res += s;
            } else if (is_last) {
                #pragma unroll
                for (int n = 0; n < NDIM; ++n)
                    last_h[(((size_t)(row >> 11)) * DDIM + d) * NDIM + n] =
                        xd * (float)Bmv[row * NDIM + n];
            }
            out[(size_t)row * DDIM + d] = res;
        }
    }
}

extern "C" void kernel_launch(void* const* d_in, const int* in_sizes, int n_in,
                              void* d_out, int out_size, void* d_ws, size_t ws_size,
                              hipStream_t stream) {
    const float* x   = (const float*)d_in[0];
    const float* W1  = (const float*)d_in[1];
    const float* b1  = (const float*)d_in[2];
    const float* W2  = (const float*)d_in[3];
    const float* b2  = (const float*)d_in[4];
    const float* W3  = (const float*)d_in[5];
    const float* b3  = (const float*)d_in[6];
    const float* Wl1 = (const float*)d_in[7];
    const float* bl1 = (const float*)d_in[8];
    const float* Wl2 = (const float*)d_in[9];
    const float* bl2 = (const float*)d_in[10];
    const float* Wf1 = (const float*)d_in[11];
    const float* bf1 = (const float*)d_in[12];
    const float* Wf2 = (const float*)d_in[13];
    const float* bf2 = (const float*)d_in[14];
    const float* h0  = (const float*)d_in[15];
    const float* Amat= (const float*)d_in[16];

    float* out    = (float*)d_out;
    float* last_h = (float*)d_out + (size_t)MROWS * DDIM;

    __bf16* wsb = (__bf16*)d_ws;
    size_t o = 0;
    auto alloc = [&](size_t n) { __bf16* p = wsb + o; o += n; return p; };
    __bf16* WaT    = alloc(256 * 1024);             // [Wl1 | Wf1_top]^T
    __bf16* Wf1bT  = alloc(128 * 1024);
    __bf16* Wl2T   = alloc(1024 * 128);
    __bf16* WbigT  = alloc((size_t)NPAD * 1024);    // [W1 | W2 | W3 | pad]^T
    __bf16* WpairT = alloc(2112 * 128);             // pairs 0..2047, BC 2048..2079
    __bf16* Wf2c   = alloc(128 * 1024);             // Wf2 bf16 row-major
    __bf16* tmp12  = alloc((size_t)MROWS * 256);    // [relu(x@Wl1+bl1) | x@Wf1_top]
    __bf16* lifted = alloc((size_t)MROWS * DDIM);
    __bf16* tmp2   = alloc((size_t)MROWS * HDIM);
    __bf16* Bmv    = alloc((size_t)MROWS * NDIM);
    __bf16* Cmv    = alloc((size_t)MROWS * NDIM);
    float*  bias_pair = (float*)(wsb + o); o += 2 * 2112;
    float*  cbv    = (float*)(wsb + o); o += 2 * MROWS;
    unsigned* h0mask = (unsigned*)(wsb + o);

    // 1. pack
    pack_all<<<dim3(32, 32, 11), 256, 0, stream>>>(W1, W2, W3, Wl1, Wl2, Wf1, Wf2,
                                                   bf2, h0,
                                                   WbigT, WaT, Wf1bT, Wl2T, WpairT,
                                                   Wf2c, bias_pair, h0mask);
    // 2. merged: G1 (512) + Gpre (34) + bias fold (264)
    stage2_k<<<dim3(810), 256, 0, stream>>>(x, WaT, WbigT, Wf2c, bf2, b1, b2, b3,
                                            bl1, tmp12, WpairT, bias_pair);
    // 3. G2: lifted = tanh(tmp12[:,:128] @ Wl2 + bl2)  M=4096 N=1024 K=128, 512 blk
    mm<64, 128, 2, false, false><<<dim3(8 * 64), 256, 0, stream>>>(
        tmp12, 256, Wl2T, 128, 1024, bl2, nullptr, 0, lifted, DDIM, 128, 8);
    // 4. G3: tmp2 = relu(lifted@Wf1_bot + bf1 + tmp12[:,128:]) M=4096 N=128 K=1024, 512 blk
    mm<32, 32, 1, true, false><<<dim3(4 * 128), 256, 0, stream>>>(
        lifted, DDIM, Wf1bT, 1024, 128, bf1, tmp12 + 128, 256, tmp2, HDIM, 1024, 4);
    // 5. bc_k: Bm/Cm/cb per row (f32)
    bc_k<<<dim3(MROWS / 16), 256, 0, stream>>>(tmp2, WpairT + 2048 * 128,
                                               bias_pair + 2048, Bmv, Cmv, cbv);
    // 6. mm_pairs: fused [x_tr|delta] GEMM + final epilogue -> out, last_h
    mm_pairs<<<dim3(32 * 64), 256, 0, stream>>>(tmp2, WpairT, bias_pair, cbv,
                                                Bmv, Cmv, Amat, h0, h0mask,
                                                out, last_h);
}

// Round 11
// 59.096 us; speedup vs baseline: 2.9943x; 1.0736x over previous
//
#include <hip/hip_runtime.h>
#include <cmath>

#define B_SZ 2
#define LSEQ 2048
#define DDIM 1024
#define NDIM 16
#define HDIM 128
#define MROWS (B_SZ * LSEQ)    // 4096
#define NBIG (DDIM + 2 * NDIM) // 1056
#define NPAD 1088              // NBIG padded to 64

typedef __bf16 bf16x8 __attribute__((ext_vector_type(8)));
typedef __bf16 bf16x4 __attribute__((ext_vector_type(4)));
typedef float f32x4 __attribute__((ext_vector_type(4)));

// async global->LDS, 16B/lane; LDS dest = wave-uniform base + lane*16
__device__ __forceinline__ void glds16(const __bf16* g, __bf16* l) {
    __builtin_amdgcn_global_load_lds(
        (const __attribute__((address_space(1))) unsigned int*)g,
        (__attribute__((address_space(3))) unsigned int*)l, 16, 0, 0);
}

// pair-layout row slots
__device__ __forceinline__ int slot_xt(int d) { return (d >> 4) * 32 + (d & 15); }
__device__ __forceinline__ int slot_de(int d) { return (d >> 4) * 32 + 16 + (d & 15); }

// ---------------------------------------------------------------------------
// Preprocessing (flat 1-D grid, 1797 blocks; no idle dispatch waste).
// ---------------------------------------------------------------------------
__device__ __forceinline__ void tcast_tile(const float* __restrict__ in,
                                           __bf16* __restrict__ out, int K, int N,
                                           int bx, int by, float (*t)[33]) {
    int tx = threadIdx.x & 31, ty = threadIdx.x >> 5;
    int n0 = bx * 32, k0 = by * 32;
    #pragma unroll
    for (int i = 0; i < 4; ++i) {
        int k = k0 + ty + i * 8, n = n0 + tx;
        t[ty + i * 8][tx] = (k < K && n < N) ? in[(size_t)k * N + n] : 0.f;
    }
    __syncthreads();
    #pragma unroll
    for (int i = 0; i < 4; ++i) {
        int n = n0 + ty + i * 8, k = k0 + tx;
        if (n < N && k < K) out[(size_t)n * K + k] = (__bf16)t[tx][ty + i * 8];
    }
}

// Wf2 [128][1024] -> WpairT xt slots (row slot_xt(n), ld 128)
__device__ __forceinline__ void tcast_pair_tile(const float* __restrict__ in,
                                                __bf16* __restrict__ out,
                                                int bx, int by, float (*t)[33]) {
    int tx = threadIdx.x & 31, ty = threadIdx.x >> 5;
    int n0 = bx * 32, k0 = by * 32;
    #pragma unroll
    for (int i = 0; i < 4; ++i) {
        int k = k0 + ty + i * 8, n = n0 + tx;
        t[ty + i * 8][tx] = in[(size_t)k * 1024 + n];
    }
    __syncthreads();
    #pragma unroll
    for (int i = 0; i < 4; ++i) {
        int n = n0 + ty + i * 8, k = k0 + tx;
        out[(size_t)slot_xt(n) * 128 + k] = (__bf16)t[tx][ty + i * 8];
    }
}

__global__ __launch_bounds__(256) void pack_all(
    const float* W1, const float* W2, const float* W3, const float* Wl1,
    const float* Wl2, const float* Wf1, const float* Wf2,
    const float* bf2, const float* h0,
    __bf16* WbigT, __bf16* WaT, __bf16* Wf1bT, __bf16* Wl2T, __bf16* WpairT,
    __bf16* Wf2c, float* bias_pair, unsigned* h0mask) {
    __shared__ float t[32][33];
    const int b = blockIdx.x;
    const int tid = threadIdx.x;
    if (b < 1024) {                       // W1 -> WbigT
        tcast_tile(W1, WbigT, 1024, 1024, b & 31, b >> 5, t);
    } else if (b < 1152) {                // Wl1 -> WaT
        int i = b - 1024; tcast_tile(Wl1, WaT, 1024, 128, i & 3, i >> 2, t);
    } else if (b < 1280) {                // Wf1 top -> WaT[128k..]
        int i = b - 1152; tcast_tile(Wf1, WaT + 128 * 1024, 1024, 128, i & 3, i >> 2, t);
    } else if (b < 1408) {                // Wf1 bottom -> Wf1bT
        int i = b - 1280;
        tcast_tile(Wf1 + (size_t)1024 * 128, Wf1bT, 1024, 128, i & 3, i >> 2, t);
    } else if (b < 1536) {                // Wl2 -> Wl2T
        int i = b - 1408; tcast_tile(Wl2, Wl2T, 128, 1024, i & 31, i >> 5, t);
    } else if (b < 1664) {                // Wf2 -> WpairT xt slots
        int i = b - 1536; tcast_pair_tile(Wf2, WpairT, i & 31, i >> 5, t);
    } else if (b < 1696) {                // W2 -> WbigT[1024..]
        int i = b - 1664; tcast_tile(W2, WbigT + (size_t)1024 * 1024, 1024, 16, 0, i, t);
    } else if (b < 1728) {                // W3 -> WbigT[1040..]
        int i = b - 1696; tcast_tile(W3, WbigT + (size_t)1040 * 1024, 1024, 16, 0, i, t);
    } else if (b < 1732) {                // xt bias scatter
        int i = (b - 1728) * 256 + tid;
        bias_pair[slot_xt(i)] = bf2[i];
    } else if (b < 1764) {                // zero WbigT pad rows
        int i = (b - 1732) * 256 + tid;
        #pragma unroll
        for (int r = 0; r < 4; ++r) {
            int e = i + r * 8192;
            if (e < 32 * 1024) WbigT[(size_t)1056 * 1024 + e] = (__bf16)0.f;
        }
    } else if (b < 1796) {                // Wf2 -> Wf2c row-major bf16
        int id = (b - 1764) * 256 + tid;
        #pragma unroll
        for (int j = 0; j < 4; ++j) {
            int e = id + j * 8192;
            float4 v = ((const float4*)Wf2)[e];
            bf16x4 o2 = {(__bf16)v.x, (__bf16)v.y, (__bf16)v.z, (__bf16)v.w};
            ((bf16x4*)Wf2c)[e] = o2;
        }
    } else {                              // h0 nonzero bitmask
        __shared__ unsigned sm[32];
        if (tid < 32) sm[tid] = 0u;
        __syncthreads();
        unsigned nib = 0;
        #pragma unroll
        for (int j = 0; j < 4; ++j) {
            int d = tid * 4 + j;
            const uint4* hu = (const uint4*)(h0 + d * NDIM);
            uint4 a0 = hu[0], a1 = hu[1], a2 = hu[2], a3 = hu[3];
            unsigned nz = a0.x | a0.y | a0.z | a0.w | a1.x | a1.y | a1.z | a1.w |
                          a2.x | a2.y | a2.z | a2.w | a3.x | a3.y | a3.z | a3.w;
            if (nz) nib |= (1u << j);
        }
        if (nib) atomicOr(&sm[(tid * 4) >> 5], nib << ((tid * 4) & 31));
        __syncthreads();
        if (tid < 32) h0mask[tid] = sm[tid];
    }
}

// ---------------------------------------------------------------------------
// Core BMxBN / BK=64 double-buffered MFMA GEMM.
// ACT: 1 relu(+prev), 2 fast-tanh, 4 split128-relu,
//      7 pair-scatter raw write (Gpre)
// ---------------------------------------------------------------------------
template <int BM, int BN, int ACT, bool ADD_PREV, bool GUARDN, bool AF32>
__device__ __forceinline__ void gemm_core(
    const void* Av, int lda, const __bf16* __restrict__ Bt, int ldb, int Ntot,
    const float* __restrict__ bias, const __bf16* __restrict__ prev, int ldp,
    __bf16* __restrict__ C, int ldc, int K, int bm, int bn,
    __bf16* As, __bf16* Bs) {
    constexpr int WM = BM / 2, WN = BN / 2, FM = WM / 16, FN = WN / 16;
    constexpr int ASZ = BM * 64, BSZ = BN * 64;
    const int tid = threadIdx.x;
    const int lane = tid & 63, w = tid >> 6;
    const int wr = w >> 1, wc = w & 1;
    const int g = lane >> 4, lr = lane & 15;
    const __bf16* A16 = (const __bf16*)Av;
    const float* A32 = (const float*)Av;

    auto stage = [&](int buf, int k0) {
        #pragma unroll
        for (int i = 0; i < BM / 32; ++i) {
            int D = i * 256 + tid;
            int row = D >> 3, pos = D & 7, c = pos ^ (row & 7);
            if constexpr (AF32) {
                const float* s = &A32[(size_t)(bm + row) * lda + k0 + c * 8];
                float4 v0 = *(const float4*)s;
                float4 v1 = *(const float4*)(s + 4);
                bf16x8 pk = {(__bf16)v0.x, (__bf16)v0.y, (__bf16)v0.z, (__bf16)v0.w,
                             (__bf16)v1.x, (__bf16)v1.y, (__bf16)v1.z, (__bf16)v1.w};
                *(bf16x8*)&As[buf * ASZ + row * 64 + pos * 8] = pk;
            } else {
                glds16(&A16[(size_t)(bm + row) * lda + k0 + c * 8],
                       &As[buf * ASZ + (i * 256 + w * 64) * 8]);
            }
        }
        #pragma unroll
        for (int i = 0; i < BN / 32; ++i) {
            int D = i * 256 + tid;
            int row = D >> 3, pos = D & 7, c = pos ^ (row & 7);
            glds16(&Bt[(size_t)(bn + row) * ldb + k0 + c * 8],
                   &Bs[buf * BSZ + (i * 256 + w * 64) * 8]);
        }
    };

    f32x4 acc[FM][FN] = {};
    const int x7 = lr & 7;
    const int ca[2] = {(g ^ x7) * 8, ((4 + g) ^ x7) * 8};
    const int arow0 = wr * WM + lr;
    const int brow0 = wc * WN + lr;

    const int nt = K >> 6;
    stage(0, 0);
    __syncthreads();
    for (int t = 0; t < nt; ++t) {
        if (t + 1 < nt) stage((t + 1) & 1, (t + 1) << 6);
        const __bf16* Ab = &As[(t & 1) * ASZ];
        const __bf16* Bb = &Bs[(t & 1) * BSZ];
        bf16x8 af[FM][2], bfr[FN][2];
        #pragma unroll
        for (int m = 0; m < FM; ++m)
            #pragma unroll
            for (int h = 0; h < 2; ++h)
                af[m][h] = *(const bf16x8*)&Ab[(arow0 + m * 16) * 64 + ca[h]];
        #pragma unroll
        for (int n = 0; n < FN; ++n)
            #pragma unroll
            for (int h = 0; h < 2; ++h)
                bfr[n][h] = *(const bf16x8*)&Bb[(brow0 + n * 16) * 64 + ca[h]];
        #pragma unroll
        for (int h = 0; h < 2; ++h)
            #pragma unroll
            for (int m = 0; m < FM; ++m)
                #pragma unroll
                for (int n = 0; n < FN; ++n)
                    acc[m][n] = __builtin_amdgcn_mfma_f32_16x16x32_bf16(
                        af[m][h], bfr[n][h], acc[m][n], 0, 0, 0);
        __syncthreads();
    }

    // epilogue: C/D layout col=lane&15, row=(lane>>4)*4+reg
    #pragma unroll
    for (int m = 0; m < FM; ++m) {
        #pragma unroll
        for (int n = 0; n < FN; ++n) {
            #pragma unroll
            for (int r = 0; r < 4; ++r) {
                int grow = bm + wr * WM + m * 16 + g * 4 + r;
                int gcol = bn + wc * WN + n * 16 + lr;
                if (!GUARDN || gcol < Ntot) {
                    float v = acc[m][n][r];
                    int orow = grow;
                    if (ACT == 1) {
                        v += bias[gcol];
                        if (ADD_PREV) v += (float)prev[(size_t)grow * ldp + gcol];
                        v = fmaxf(v, 0.f);
                    } else if (ACT == 2) { // fast tanh: 1 - 2/(1+e^2v)
                        v += bias[gcol];
                        float e = __expf(2.f * v);
                        v = 1.f - 2.f * __builtin_amdgcn_rcpf(e + 1.f);
                    } else if (ACT == 4) {
                        if (gcol < HDIM) v = fmaxf(v + bias[gcol], 0.f);
                    } else if (ACT == 7) { // Gpre pair-scatter, raw
                        orow = (grow < 1024) ? slot_de(grow) : 2048 + (grow - 1024);
                    }
                    C[(size_t)orow * ldc + gcol] = (__bf16)v;
                }
            }
        }
    }
}

// thin global wrapper (1-D grid, bijective XCD swizzle when NB%8==0)
template <int BM, int BN, int ACT, bool ADD_PREV, bool GUARDN>
__global__ __launch_bounds__(256) void mm(const __bf16* __restrict__ A, int lda,
                                          const __bf16* __restrict__ Bt, int ldb, int Ntot,
                                          const float* __restrict__ bias,
                                          const __bf16* __restrict__ prev, int ldp,
                                          __bf16* __restrict__ C, int ldc, int K, int nbx) {
    __shared__ __bf16 As[2 * BM * 64];
    __shared__ __bf16 Bs[2 * BN * 64];
    const int NB = gridDim.x;
    const int aid = ((NB & 7) == 0)
                        ? (blockIdx.x & 7) * (NB >> 3) + (blockIdx.x >> 3)
                        : blockIdx.x;
    const int bn = (aid % nbx) * BN, bm = (aid / nbx) * BM;
    gemm_core<BM, BN, ACT, ADD_PREV, GUARDN, false>(
        A, lda, Bt, ldb, Ntot, bias, prev, ldp, C, ldc, K, bm, bn, As, Bs);
}

// ---------------------------------------------------------------------------
// Merged stage-2: [0,512) G1 (x fp32 reg-staged); [512,546) Gpre->WpairT;
// [546,810) bias fold -> bias_pair (delta + BC slots).
// ---------------------------------------------------------------------------
__global__ __launch_bounds__(256) void stage2_k(
    const float* __restrict__ x, const __bf16* __restrict__ WaT,
    const __bf16* __restrict__ WbigT, const __bf16* __restrict__ Wf2c,
    const float* __restrict__ bf2, const float* __restrict__ b1,
    const float* __restrict__ b2, const float* __restrict__ b3,
    const float* __restrict__ bl1,
    __bf16* __restrict__ tmp12, __bf16* __restrict__ WpairT,
    float* __restrict__ bias_pair) {
    __shared__ __bf16 As[2 * 64 * 64];
    __shared__ __bf16 Bs[2 * 64 * 64];
    const int b = blockIdx.x;
    if (b < 512) {
        // G1: tmp12 = [relu(x@Wl1+bl1) | x@Wf1_top]  M=4096 N=256 K=1024
        const int aid = (b & 7) * 64 + (b >> 3);
        const int bn = (aid & 3) * 64, bm = (aid >> 2) * 32;
        gemm_core<32, 64, 4, false, false, true>(
            x, DDIM, WaT, 1024, 256, bl1, nullptr, 0, tmp12, 256, 1024, bm, bn, As, Bs);
    } else if (b < 546) {
        // Gpre: Wcomb cols scattered into WpairT delta/BC slots  M=1088 N=128 K=1024
        const int aid = b - 512;
        const int bn = (aid & 1) * 64, bm = (aid >> 1) * 64;
        gemm_core<64, 64, 7, false, false, false>(
            WbigT, 1024, Wf2c, 1024, 128, nullptr, nullptr, 0,
            WpairT, 128, 1024, bm, bn, As, Bs);
    } else {
        // bias fold: fold(n) = ball[n] + sum_d bf2[d]*Wall[d][n] -> pair/BC slots
        const int n = (b - 546) * 4 + (threadIdx.x >> 6);
        const int lane = threadIdx.x & 63;
        const __bf16* wr = WbigT + (size_t)n * 1024 + lane * 16;
        float s = 0.f;
        #pragma unroll
        for (int i = 0; i < 2; ++i) {
            bf16x8 wv = *(const bf16x8*)&wr[i * 8];
            float4 f0 = *(const float4*)&bf2[lane * 16 + i * 8];
            float4 f1 = *(const float4*)&bf2[lane * 16 + i * 8 + 4];
            s += (float)wv[0] * f0.x + (float)wv[1] * f0.y + (float)wv[2] * f0.z +
                 (float)wv[3] * f0.w + (float)wv[4] * f1.x + (float)wv[5] * f1.y +
                 (float)wv[6] * f1.z + (float)wv[7] * f1.w;
        }
        #pragma unroll
        for (int off = 32; off; off >>= 1) s += __shfl_down(s, off);
        if (lane == 0) {
            float base = (n < DDIM) ? b1[n]
                       : (n < DDIM + NDIM) ? b2[n - DDIM] : b3[n - DDIM - NDIM];
            int sl = (n < DDIM) ? slot_de(n) : 2048 + (n - DDIM);
            bias_pair[sl] = base + s;
        }
    }
}

// ---------------------------------------------------------------------------
// bc_k: Bm/Cm/cb per row from tmp2 (f32 accumulate). 256 blocks x 16 rows.
// ---------------------------------------------------------------------------
__global__ __launch_bounds__(256) void bc_k(const __bf16* __restrict__ tmp2,
                                            const __bf16* __restrict__ WbcT,
                                            const float* __restrict__ bias_bc,
                                            __bf16* __restrict__ Bmv,
                                            __bf16* __restrict__ Cmv,
                                            float* __restrict__ cbv) {
    __shared__ __bf16 t2[16][128];
    const int blk = blockIdx.x, tid = threadIdx.x;
    const int rr = tid >> 4, cc = tid & 15;
    *(bf16x8*)&t2[rr][cc * 8] =
        *(const bf16x8*)&tmp2[(size_t)(blk * 16 + rr) * 128 + cc * 8];
    __syncthreads();
    float sB = bias_bc[cc], sC = bias_bc[16 + cc];
    #pragma unroll
    for (int i = 0; i < 16; ++i) {
        bf16x8 tv = *(const bf16x8*)&t2[rr][i * 8];
        bf16x8 wb = *(const bf16x8*)&WbcT[(size_t)cc * 128 + i * 8];
        bf16x8 wc2 = *(const bf16x8*)&WbcT[(size_t)(16 + cc) * 128 + i * 8];
        #pragma unroll
        for (int j = 0; j < 8; ++j) {
            float tvf = (float)tv[j];
            sB += tvf * (float)wb[j];
            sC += tvf * (float)wc2[j];
        }
    }
    const int row = blk * 16 + rr;
    Bmv[row * NDIM + cc] = (__bf16)sB;
    Cmv[row * NDIM + cc] = (__bf16)sC;
    float p = sB * sC;
    #pragma unroll
    for (int m2 = 1; m2 < 16; m2 <<= 1) p += __shfl_xor(p, m2);
    if (cc == 0) cbv[row] = p;
}

// ---------------------------------------------------------------------------
// mm_pairs: [xt|de] pair GEMM + fused final epilogue. M=4096 N=2048 K=128.
// BM=128 BN=64 (FM=4): 32 MFMA/wave/k-iter, 1024 blocks, LDS 48 KB.
// ---------------------------------------------------------------------------
__global__ __launch_bounds__(256) void mm_pairs(
    const __bf16* __restrict__ tmp2, const __bf16* __restrict__ WpairT,
    const float* __restrict__ bias_pair, const float* __restrict__ cbv,
    const __bf16* __restrict__ Bmv, const __bf16* __restrict__ Cmv,
    const float* __restrict__ Amat, const float* __restrict__ h0,
    const unsigned* __restrict__ h0mask,
    float* __restrict__ out, float* __restrict__ last_h) {
    constexpr int ASZ = 128 * 64, BSZ = 64 * 64;
    __shared__ __bf16 As[2 * ASZ];
    __shared__ __bf16 Bs[2 * BSZ];
    const int NB = gridDim.x; // 1024
    const int aid = (blockIdx.x & 7) * (NB >> 3) + (blockIdx.x >> 3);
    const int bn = (aid & 31) * 64, bm = (aid >> 5) * 128;
    const int tid = threadIdx.x;
    const int lane = tid & 63, w = tid >> 6;
    const int wr = w >> 1, wc = w & 1;
    const int g = lane >> 4, lr = lane & 15;

    auto stage = [&](int buf, int k0) {
        #pragma unroll
        for (int i = 0; i < 4; ++i) {
            int D = i * 256 + tid;
            int row = D >> 3, pos = D & 7, c = pos ^ (row & 7);
            glds16(&tmp2[(size_t)(bm + row) * 128 + k0 + c * 8],
                   &As[buf * ASZ + (i * 256 + w * 64) * 8]);
        }
        #pragma unroll
        for (int i = 0; i < 2; ++i) {
            int D = i * 256 + tid;
            int row = D >> 3, pos = D & 7, c = pos ^ (row & 7);
            glds16(&WpairT[(size_t)(bn + row) * 128 + k0 + c * 8],
                   &Bs[buf * BSZ + (i * 256 + w * 64) * 8]);
        }
    };

    f32x4 acc[4][2] = {};
    const int x7 = lr & 7;
    const int ca[2] = {(g ^ x7) * 8, ((4 + g) ^ x7) * 8};
    const int arow0 = wr * 64 + lr, brow0 = wc * 32 + lr;
    stage(0, 0);
    __syncthreads();
    #pragma unroll
    for (int t = 0; t < 2; ++t) {
        if (t == 0) stage(1, 64);
        const __bf16* Ab = &As[t * ASZ];
        const __bf16* Bb = &Bs[t * BSZ];
        bf16x8 af[4][2], bfr[2][2];
        #pragma unroll
        for (int m = 0; m < 4; ++m)
            #pragma unroll
            for (int h = 0; h < 2; ++h)
                af[m][h] = *(const bf16x8*)&Ab[(arow0 + m * 16) * 64 + ca[h]];
        #pragma unroll
        for (int n = 0; n < 2; ++n)
            #pragma unroll
            for (int h = 0; h < 2; ++h)
                bfr[n][h] = *(const bf16x8*)&Bb[(brow0 + n * 16) * 64 + ca[h]];
        #pragma unroll
        for (int h = 0; h < 2; ++h)
            #pragma unroll
            for (int m = 0; m < 4; ++m)
                #pragma unroll
                for (int n = 0; n < 2; ++n)
                    acc[m][n] = __builtin_amdgcn_mfma_f32_16x16x32_bf16(
                        af[m][h], bfr[n][h], acc[m][n], 0, 0, 0);
        __syncthreads();
    }

    // epilogue: d = group*16 + lr; xt = acc[m][0], de = acc[m][1]
    const int d = ((bn + wc * 32) >> 1) + lr;
    const float bx_ = bias_pair[bn + wc * 32 + lr];
    const float bd_ = bias_pair[bn + wc * 32 + 16 + lr];
    const bool msk = (h0mask[d >> 5] >> (d & 31)) & 1u;
    #pragma unroll
    for (int m = 0; m < 4; ++m) {
        #pragma unroll
        for (int r = 0; r < 4; ++r) {
            const int row = bm + wr * 64 + m * 16 + g * 4 + r;
            const float xt = acc[m][0][r] + bx_;
            const float dr = acc[m][1][r] + bd_;
            const float e = __expf(-fabsf(dr));
            const float de = fmaxf(dr, 0.f) + __logf(1.f + e);
            const float xd = xt * de;
            float res = xd * cbv[row];
            const bool is_last = (row & (LSEQ - 1)) == (LSEQ - 1);
            if (msk) {
                float s = 0.f;
                #pragma unroll
                for (int n = 0; n < NDIM; ++n) {
                    float z = de * Amat[d * NDIM + n];
                    float c2 = (z > 0.f) ? z : __expf(z) - 1.f;
                    float da = __expf(-c2);
                    float h0v = h0[d * NDIM + n];
                    s += (float)Cmv[row * NDIM + n] * da * h0v;
                    if (is_last)
                        last_h[(((size_t)(row >> 11)) * DDIM + d) * NDIM + n] =
                            da * h0v + xd * (float)Bmv[row * NDIM + n];
                }
                res += s;
            } else if (is_last) {
                #pragma unroll
                for (int n = 0; n < NDIM; ++n)
                    last_h[(((size_t)(row >> 11)) * DDIM + d) * NDIM + n] =
                        xd * (float)Bmv[row * NDIM + n];
            }
            out[(size_t)row * DDIM + d] = res;
        }
    }
}

extern "C" void kernel_launch(void* const* d_in, const int* in_sizes, int n_in,
                              void* d_out, int out_size, void* d_ws, size_t ws_size,
                              hipStream_t stream) {
    const float* x   = (const float*)d_in[0];
    const float* W1  = (const float*)d_in[1];
    const float* b1  = (const float*)d_in[2];
    const float* W2  = (const float*)d_in[3];
    const float* b2  = (const float*)d_in[4];
    const float* W3  = (const float*)d_in[5];
    const float* b3  = (const float*)d_in[6];
    const float* Wl1 = (const float*)d_in[7];
    const float* bl1 = (const float*)d_in[8];
    const float* Wl2 = (const float*)d_in[9];
    const float* bl2 = (const float*)d_in[10];
    const float* Wf1 = (const float*)d_in[11];
    const float* bf1 = (const float*)d_in[12];
    const float* Wf2 = (const float*)d_in[13];
    const float* bf2 = (const float*)d_in[14];
    const float* h0  = (const float*)d_in[15];
    const float* Amat= (const float*)d_in[16];

    float* out    = (float*)d_out;
    float* last_h = (float*)d_out + (size_t)MROWS * DDIM;

    __bf16* wsb = (__bf16*)d_ws;
    size_t o = 0;
    auto alloc = [&](size_t n) { __bf16* p = wsb + o; o += n; return p; };
    __bf16* WaT    = alloc(256 * 1024);             // [Wl1 | Wf1_top]^T
    __bf16* Wf1bT  = alloc(128 * 1024);
    __bf16* Wl2T   = alloc(1024 * 128);
    __bf16* WbigT  = alloc((size_t)NPAD * 1024);    // [W1 | W2 | W3 | pad]^T
    __bf16* WpairT = alloc(2112 * 128);             // pairs 0..2047, BC 2048..2079
    __bf16* Wf2c   = alloc(128 * 1024);             // Wf2 bf16 row-major
    __bf16* tmp12  = alloc((size_t)MROWS * 256);    // [relu(x@Wl1+bl1) | x@Wf1_top]
    __bf16* lifted = alloc((size_t)MROWS * DDIM);
    __bf16* tmp2   = alloc((size_t)MROWS * HDIM);
    __bf16* Bmv    = alloc((size_t)MROWS * NDIM);
    __bf16* Cmv    = alloc((size_t)MROWS * NDIM);
    float*  bias_pair = (float*)(wsb + o); o += 2 * 2112;
    float*  cbv    = (float*)(wsb + o); o += 2 * MROWS;
    unsigned* h0mask = (unsigned*)(wsb + o);

    // 1. pack (flat 1797 blocks)
    pack_all<<<dim3(1797), 256, 0, stream>>>(W1, W2, W3, Wl1, Wl2, Wf1, Wf2,
                                             bf2, h0,
                                             WbigT, WaT, Wf1bT, Wl2T, WpairT,
                                             Wf2c, bias_pair, h0mask);
    // 2. merged: G1 (512) + Gpre (34) + bias fold (264)
    stage2_k<<<dim3(810), 256, 0, stream>>>(x, WaT, WbigT, Wf2c, bf2, b1, b2, b3,
                                            bl1, tmp12, WpairT, bias_pair);
    // 3. G2: lifted = tanh(tmp12[:,:128] @ Wl2 + bl2)  M=4096 N=1024 K=128, 1024 blk
    mm<64, 64, 2, false, false><<<dim3(16 * 64), 256, 0, stream>>>(
        tmp12, 256, Wl2T, 128, 1024, bl2, nullptr, 0, lifted, DDIM, 128, 16);
    // 4. G3: tmp2 = relu(lifted@Wf1_bot + bf1 + tmp12[:,128:]) M=4096 N=128 K=1024, 512 blk
    mm<32, 32, 1, true, false><<<dim3(4 * 128), 256, 0, stream>>>(
        lifted, DDIM, Wf1bT, 1024, 128, bf1, tmp12 + 128, 256, tmp2, HDIM, 1024, 4);
    // 5. bc_k: Bm/Cm/cb per row (f32)
    bc_k<<<dim3(MROWS / 16), 256, 0, stream>>>(tmp2, WpairT + 2048 * 128,
                                               bias_pair + 2048, Bmv, Cmv, cbv);
    // 6. mm_pairs: fused [x_tr|delta] GEMM + final epilogue -> out, last_h
    mm_pairs<<<dim3(32 * 32), 256, 0, stream>>>(tmp2, WpairT, bias_pair, cbv,
                                                Bmv, Cmv, Amat, h0, h0mask,
                                                out, last_h);
}

// Round 12
// 56.409 us; speedup vs baseline: 3.1369x; 1.0476x over previous
//
#include <hip/hip_runtime.h>
#include <cmath>

#define B_SZ 2
#define LSEQ 2048
#define DDIM 1024
#define NDIM 16
#define HDIM 128
#define MROWS (B_SZ * LSEQ)    // 4096
#define NBIG (DDIM + 2 * NDIM) // 1056
#define NPAD 1088              // NBIG padded to 64

typedef __bf16 bf16x8 __attribute__((ext_vector_type(8)));
typedef __bf16 bf16x4 __attribute__((ext_vector_type(4)));
typedef float f32x4 __attribute__((ext_vector_type(4)));

// async global->LDS, 16B/lane; LDS dest = wave-uniform base + lane*16
__device__ __forceinline__ void glds16(const __bf16* g, __bf16* l) {
    __builtin_amdgcn_global_load_lds(
        (const __attribute__((address_space(1))) unsigned int*)g,
        (__attribute__((address_space(3))) unsigned int*)l, 16, 0, 0);
}

// pair-layout row slots
__device__ __forceinline__ int slot_xt(int d) { return (d >> 4) * 32 + (d & 15); }
__device__ __forceinline__ int slot_de(int d) { return (d >> 4) * 32 + 16 + (d & 15); }

// ---------------------------------------------------------------------------
// Preprocessing (flat 1-D grid, 1797 blocks).
// ---------------------------------------------------------------------------
__device__ __forceinline__ void tcast_tile(const float* __restrict__ in,
                                           __bf16* __restrict__ out, int K, int N,
                                           int bx, int by, float (*t)[33]) {
    int tx = threadIdx.x & 31, ty = threadIdx.x >> 5;
    int n0 = bx * 32, k0 = by * 32;
    #pragma unroll
    for (int i = 0; i < 4; ++i) {
        int k = k0 + ty + i * 8, n = n0 + tx;
        t[ty + i * 8][tx] = (k < K && n < N) ? in[(size_t)k * N + n] : 0.f;
    }
    __syncthreads();
    #pragma unroll
    for (int i = 0; i < 4; ++i) {
        int n = n0 + ty + i * 8, k = k0 + tx;
        if (n < N && k < K) out[(size_t)n * K + k] = (__bf16)t[tx][ty + i * 8];
    }
}

// Wf2 [128][1024] -> WpairT xt slots (row slot_xt(n), ld 128)
__device__ __forceinline__ void tcast_pair_tile(const float* __restrict__ in,
                                                __bf16* __restrict__ out,
                                                int bx, int by, float (*t)[33]) {
    int tx = threadIdx.x & 31, ty = threadIdx.x >> 5;
    int n0 = bx * 32, k0 = by * 32;
    #pragma unroll
    for (int i = 0; i < 4; ++i) {
        int k = k0 + ty + i * 8, n = n0 + tx;
        t[ty + i * 8][tx] = in[(size_t)k * 1024 + n];
    }
    __syncthreads();
    #pragma unroll
    for (int i = 0; i < 4; ++i) {
        int n = n0 + ty + i * 8, k = k0 + tx;
        out[(size_t)slot_xt(n) * 128 + k] = (__bf16)t[tx][ty + i * 8];
    }
}

__global__ __launch_bounds__(256) void pack_all(
    const float* W1, const float* W2, const float* W3, const float* Wl1,
    const float* Wl2, const float* Wf1, const float* Wf2,
    const float* bf2, const float* h0,
    __bf16* WbigT, __bf16* WaT, __bf16* Wf1bT, __bf16* Wl2T, __bf16* WpairT,
    __bf16* Wf2c, float* bias_pair, unsigned* h0mask) {
    __shared__ float t[32][33];
    const int b = blockIdx.x;
    const int tid = threadIdx.x;
    if (b < 1024) {                       // W1 -> WbigT
        tcast_tile(W1, WbigT, 1024, 1024, b & 31, b >> 5, t);
    } else if (b < 1152) {                // Wl1 -> WaT
        int i = b - 1024; tcast_tile(Wl1, WaT, 1024, 128, i & 3, i >> 2, t);
    } else if (b < 1280) {                // Wf1 top -> WaT[128k..]
        int i = b - 1152; tcast_tile(Wf1, WaT + 128 * 1024, 1024, 128, i & 3, i >> 2, t);
    } else if (b < 1408) {                // Wf1 bottom -> Wf1bT
        int i = b - 1280;
        tcast_tile(Wf1 + (size_t)1024 * 128, Wf1bT, 1024, 128, i & 3, i >> 2, t);
    } else if (b < 1536) {                // Wl2 -> Wl2T
        int i = b - 1408; tcast_tile(Wl2, Wl2T, 128, 1024, i & 31, i >> 5, t);
    } else if (b < 1664) {                // Wf2 -> WpairT xt slots
        int i = b - 1536; tcast_pair_tile(Wf2, WpairT, i & 31, i >> 5, t);
    } else if (b < 1696) {                // W2 -> WbigT[1024..]
        int i = b - 1664; tcast_tile(W2, WbigT + (size_t)1024 * 1024, 1024, 16, 0, i, t);
    } else if (b < 1728) {                // W3 -> WbigT[1040..]
        int i = b - 1696; tcast_tile(W3, WbigT + (size_t)1040 * 1024, 1024, 16, 0, i, t);
    } else if (b < 1732) {                // xt bias scatter
        int i = (b - 1728) * 256 + tid;
        bias_pair[slot_xt(i)] = bf2[i];
    } else if (b < 1764) {                // zero WbigT pad rows
        int i = (b - 1732) * 256 + tid;
        #pragma unroll
        for (int r = 0; r < 4; ++r) {
            int e = i + r * 8192;
            if (e < 32 * 1024) WbigT[(size_t)1056 * 1024 + e] = (__bf16)0.f;
        }
    } else if (b < 1796) {                // Wf2 -> Wf2c row-major bf16
        int id = (b - 1764) * 256 + tid;
        #pragma unroll
        for (int j = 0; j < 4; ++j) {
            int e = id + j * 8192;
            float4 v = ((const float4*)Wf2)[e];
            bf16x4 o2 = {(__bf16)v.x, (__bf16)v.y, (__bf16)v.z, (__bf16)v.w};
            ((bf16x4*)Wf2c)[e] = o2;
        }
    } else {                              // h0 nonzero bitmask
        __shared__ unsigned sm[32];
        if (tid < 32) sm[tid] = 0u;
        __syncthreads();
        unsigned nib = 0;
        #pragma unroll
        for (int j = 0; j < 4; ++j) {
            int d = tid * 4 + j;
            const uint4* hu = (const uint4*)(h0 + d * NDIM);
            uint4 a0 = hu[0], a1 = hu[1], a2 = hu[2], a3 = hu[3];
            unsigned nz = a0.x | a0.y | a0.z | a0.w | a1.x | a1.y | a1.z | a1.w |
                          a2.x | a2.y | a2.z | a2.w | a3.x | a3.y | a3.z | a3.w;
            if (nz) nib |= (1u << j);
        }
        if (nib) atomicOr(&sm[(tid * 4) >> 5], nib << ((tid * 4) & 31));
        __syncthreads();
        if (tid < 32) h0mask[tid] = sm[tid];
    }
}

// ---------------------------------------------------------------------------
// Core BMxBN / BK=64 double-buffered MFMA GEMM.
// ACT: 1 relu(+prev), 2 fast-tanh, 4 split128-relu, 7 pair-scatter raw (Gpre)
// ---------------------------------------------------------------------------
template <int BM, int BN, int ACT, bool ADD_PREV, bool GUARDN, bool AF32>
__device__ __forceinline__ void gemm_core(
    const void* Av, int lda, const __bf16* __restrict__ Bt, int ldb, int Ntot,
    const float* __restrict__ bias, const __bf16* __restrict__ prev, int ldp,
    __bf16* __restrict__ C, int ldc, int K, int bm, int bn,
    __bf16* As, __bf16* Bs) {
    constexpr int WM = BM / 2, WN = BN / 2, FM = WM / 16, FN = WN / 16;
    constexpr int ASZ = BM * 64, BSZ = BN * 64;
    const int tid = threadIdx.x;
    const int lane = tid & 63, w = tid >> 6;
    const int wr = w >> 1, wc = w & 1;
    const int g = lane >> 4, lr = lane & 15;
    const __bf16* A16 = (const __bf16*)Av;
    const float* A32 = (const float*)Av;

    auto stage = [&](int buf, int k0) {
        #pragma unroll
        for (int i = 0; i < BM / 32; ++i) {
            int D = i * 256 + tid;
            int row = D >> 3, pos = D & 7, c = pos ^ (row & 7);
            if constexpr (AF32) {
                const float* s = &A32[(size_t)(bm + row) * lda + k0 + c * 8];
                float4 v0 = *(const float4*)s;
                float4 v1 = *(const float4*)(s + 4);
                bf16x8 pk = {(__bf16)v0.x, (__bf16)v0.y, (__bf16)v0.z, (__bf16)v0.w,
                             (__bf16)v1.x, (__bf16)v1.y, (__bf16)v1.z, (__bf16)v1.w};
                *(bf16x8*)&As[buf * ASZ + row * 64 + pos * 8] = pk;
            } else {
                glds16(&A16[(size_t)(bm + row) * lda + k0 + c * 8],
                       &As[buf * ASZ + (i * 256 + w * 64) * 8]);
            }
        }
        #pragma unroll
        for (int i = 0; i < BN / 32; ++i) {
            int D = i * 256 + tid;
            int row = D >> 3, pos = D & 7, c = pos ^ (row & 7);
            glds16(&Bt[(size_t)(bn + row) * ldb + k0 + c * 8],
                   &Bs[buf * BSZ + (i * 256 + w * 64) * 8]);
        }
    };

    f32x4 acc[FM][FN] = {};
    const int x7 = lr & 7;
    const int ca[2] = {(g ^ x7) * 8, ((4 + g) ^ x7) * 8};
    const int arow0 = wr * WM + lr;
    const int brow0 = wc * WN + lr;

    const int nt = K >> 6;
    stage(0, 0);
    __syncthreads();
    for (int t = 0; t < nt; ++t) {
        if (t + 1 < nt) stage((t + 1) & 1, (t + 1) << 6);
        const __bf16* Ab = &As[(t & 1) * ASZ];
        const __bf16* Bb = &Bs[(t & 1) * BSZ];
        bf16x8 af[FM][2], bfr[FN][2];
        #pragma unroll
        for (int m = 0; m < FM; ++m)
            #pragma unroll
            for (int h = 0; h < 2; ++h)
                af[m][h] = *(const bf16x8*)&Ab[(arow0 + m * 16) * 64 + ca[h]];
        #pragma unroll
        for (int n = 0; n < FN; ++n)
            #pragma unroll
            for (int h = 0; h < 2; ++h)
                bfr[n][h] = *(const bf16x8*)&Bb[(brow0 + n * 16) * 64 + ca[h]];
        #pragma unroll
        for (int h = 0; h < 2; ++h)
            #pragma unroll
            for (int m = 0; m < FM; ++m)
                #pragma unroll
                for (int n = 0; n < FN; ++n)
                    acc[m][n] = __builtin_amdgcn_mfma_f32_16x16x32_bf16(
                        af[m][h], bfr[n][h], acc[m][n], 0, 0, 0);
        __syncthreads();
    }

    // epilogue: C/D layout col=lane&15, row=(lane>>4)*4+reg
    #pragma unroll
    for (int m = 0; m < FM; ++m) {
        #pragma unroll
        for (int n = 0; n < FN; ++n) {
            #pragma unroll
            for (int r = 0; r < 4; ++r) {
                int grow = bm + wr * WM + m * 16 + g * 4 + r;
                int gcol = bn + wc * WN + n * 16 + lr;
                if (!GUARDN || gcol < Ntot) {
                    float v = acc[m][n][r];
                    int orow = grow;
                    if (ACT == 1) {
                        v += bias[gcol];
                        if (ADD_PREV) v += (float)prev[(size_t)grow * ldp + gcol];
                        v = fmaxf(v, 0.f);
                    } else if (ACT == 2) { // fast tanh: 1 - 2/(1+e^2v)
                        v += bias[gcol];
                        float e = __expf(2.f * v);
                        v = 1.f - 2.f * __builtin_amdgcn_rcpf(e + 1.f);
                    } else if (ACT == 4) {
                        if (gcol < HDIM) v = fmaxf(v + bias[gcol], 0.f);
                    } else if (ACT == 7) { // Gpre pair-scatter, raw
                        orow = (grow < 1024) ? slot_de(grow) : 2048 + (grow - 1024);
                    }
                    C[(size_t)orow * ldc + gcol] = (__bf16)v;
                }
            }
        }
    }
}

// thin global wrapper (1-D grid, bijective XCD swizzle when NB%8==0)
template <int BM, int BN, int ACT, bool ADD_PREV, bool GUARDN>
__global__ __launch_bounds__(256) void mm(const __bf16* __restrict__ A, int lda,
                                          const __bf16* __restrict__ Bt, int ldb, int Ntot,
                                          const float* __restrict__ bias,
                                          const __bf16* __restrict__ prev, int ldp,
                                          __bf16* __restrict__ C, int ldc, int K, int nbx) {
    __shared__ __bf16 As[2 * BM * 64];
    __shared__ __bf16 Bs[2 * BN * 64];
    const int NB = gridDim.x;
    const int aid = ((NB & 7) == 0)
                        ? (blockIdx.x & 7) * (NB >> 3) + (blockIdx.x >> 3)
                        : blockIdx.x;
    const int bn = (aid % nbx) * BN, bm = (aid / nbx) * BM;
    gemm_core<BM, BN, ACT, ADD_PREV, GUARDN, false>(
        A, lda, Bt, ldb, Ntot, bias, prev, ldp, C, ldc, K, bm, bn, As, Bs);
}

// ---------------------------------------------------------------------------
// Merged stage-2: [0,512) G1 (x fp32 reg-staged); [512,546) Gpre->WpairT;
// [546,810) bias fold -> bias_pair (delta + BC slots).
// ---------------------------------------------------------------------------
__global__ __launch_bounds__(256) void stage2_k(
    const float* __restrict__ x, const __bf16* __restrict__ WaT,
    const __bf16* __restrict__ WbigT, const __bf16* __restrict__ Wf2c,
    const float* __restrict__ bf2, const float* __restrict__ b1,
    const float* __restrict__ b2, const float* __restrict__ b3,
    const float* __restrict__ bl1,
    __bf16* __restrict__ tmp12, __bf16* __restrict__ WpairT,
    float* __restrict__ bias_pair) {
    __shared__ __bf16 As[2 * 64 * 64];
    __shared__ __bf16 Bs[2 * 64 * 64];
    const int b = blockIdx.x;
    if (b < 512) {
        // G1: tmp12 = [relu(x@Wl1+bl1) | x@Wf1_top]  M=4096 N=256 K=1024
        const int aid = (b & 7) * 64 + (b >> 3);
        const int bn = (aid & 3) * 64, bm = (aid >> 2) * 32;
        gemm_core<32, 64, 4, false, false, true>(
            x, DDIM, WaT, 1024, 256, bl1, nullptr, 0, tmp12, 256, 1024, bm, bn, As, Bs);
    } else if (b < 546) {
        // Gpre: Wcomb cols scattered into WpairT delta/BC slots  M=1088 N=128 K=1024
        const int aid = b - 512;
        const int bn = (aid & 1) * 64, bm = (aid >> 1) * 64;
        gemm_core<64, 64, 7, false, false, false>(
            WbigT, 1024, Wf2c, 1024, 128, nullptr, nullptr, 0,
            WpairT, 128, 1024, bm, bn, As, Bs);
    } else {
        // bias fold: fold(n) = ball[n] + sum_d bf2[d]*Wall[d][n] -> pair/BC slots
        const int n = (b - 546) * 4 + (threadIdx.x >> 6);
        const int lane = threadIdx.x & 63;
        const __bf16* wr = WbigT + (size_t)n * 1024 + lane * 16;
        float s = 0.f;
        #pragma unroll
        for (int i = 0; i < 2; ++i) {
            bf16x8 wv = *(const bf16x8*)&wr[i * 8];
            float4 f0 = *(const float4*)&bf2[lane * 16 + i * 8];
            float4 f1 = *(const float4*)&bf2[lane * 16 + i * 8 + 4];
            s += (float)wv[0] * f0.x + (float)wv[1] * f0.y + (float)wv[2] * f0.z +
                 (float)wv[3] * f0.w + (float)wv[4] * f1.x + (float)wv[5] * f1.y +
                 (float)wv[6] * f1.z + (float)wv[7] * f1.w;
        }
        #pragma unroll
        for (int off = 32; off; off >>= 1) s += __shfl_down(s, off);
        if (lane == 0) {
            float base = (n < DDIM) ? b1[n]
                       : (n < DDIM + NDIM) ? b2[n - DDIM] : b3[n - DDIM - NDIM];
            int sl = (n < DDIM) ? slot_de(n) : 2048 + (n - DDIM);
            bias_pair[sl] = base + s;
        }
    }
}

// ---------------------------------------------------------------------------
// mm_pairs: [xt|de] pair GEMM + in-kernel BC (Bm/Cm/cb) + final epilogue.
// M=4096 N=2048 K=128. BM=128 BN=64, 1024 blocks, LDS 48 KB.
// After main loop: As holds both tmp2 K-tiles -> reuse for BC MFMA against
// the Bbc tile (WpairT rows 2048..2079) staged into dead Bs buf0.
// Bm/Cm/cb parked in dead Bs buf1 / As for the epilogue.
// ---------------------------------------------------------------------------
__global__ __launch_bounds__(256) void mm_pairs(
    const __bf16* __restrict__ tmp2, const __bf16* __restrict__ WpairT,
    const float* __restrict__ bias_pair,
    const float* __restrict__ Amat, const float* __restrict__ h0,
    const unsigned* __restrict__ h0mask,
    float* __restrict__ out, float* __restrict__ last_h) {
    constexpr int ASZ = 128 * 64, BSZ = 64 * 64;
    __shared__ __bf16 As[2 * ASZ];
    __shared__ __bf16 Bs[2 * BSZ];
    const int NB = gridDim.x; // 1024
    const int aid = (blockIdx.x & 7) * (NB >> 3) + (blockIdx.x >> 3);
    const int bn = (aid & 31) * 64, bm = (aid >> 5) * 128;
    const int tid = threadIdx.x;
    const int lane = tid & 63, w = tid >> 6;
    const int wr = w >> 1, wc = w & 1;
    const int g = lane >> 4, lr = lane & 15;

    auto stage = [&](int buf, int k0) {
        #pragma unroll
        for (int i = 0; i < 4; ++i) {
            int D = i * 256 + tid;
            int row = D >> 3, pos = D & 7, c = pos ^ (row & 7);
            glds16(&tmp2[(size_t)(bm + row) * 128 + k0 + c * 8],
                   &As[buf * ASZ + (i * 256 + w * 64) * 8]);
        }
        #pragma unroll
        for (int i = 0; i < 2; ++i) {
            int D = i * 256 + tid;
            int row = D >> 3, pos = D & 7, c = pos ^ (row & 7);
            glds16(&WpairT[(size_t)(bn + row) * 128 + k0 + c * 8],
                   &Bs[buf * BSZ + (i * 256 + w * 64) * 8]);
        }
    };

    f32x4 acc[4][2] = {};
    const int x7 = lr & 7;
    const int ca[2] = {(g ^ x7) * 8, ((4 + g) ^ x7) * 8};
    const int arow0 = wr * 64 + lr, brow0 = wc * 32 + lr;
    stage(0, 0);
    __syncthreads();
    #pragma unroll
    for (int t = 0; t < 2; ++t) {
        if (t == 0) stage(1, 64);
        const __bf16* Ab = &As[t * ASZ];
        const __bf16* Bb = &Bs[t * BSZ];
        bf16x8 af[4][2], bfr[2][2];
        #pragma unroll
        for (int m = 0; m < 4; ++m)
            #pragma unroll
            for (int h = 0; h < 2; ++h)
                af[m][h] = *(const bf16x8*)&Ab[(arow0 + m * 16) * 64 + ca[h]];
        #pragma unroll
        for (int n = 0; n < 2; ++n)
            #pragma unroll
            for (int h = 0; h < 2; ++h)
                bfr[n][h] = *(const bf16x8*)&Bb[(brow0 + n * 16) * 64 + ca[h]];
        #pragma unroll
        for (int h = 0; h < 2; ++h)
            #pragma unroll
            for (int m = 0; m < 4; ++m)
                #pragma unroll
                for (int n = 0; n < 2; ++n)
                    acc[m][n] = __builtin_amdgcn_mfma_f32_16x16x32_bf16(
                        af[m][h], bfr[n][h], acc[m][n], 0, 0, 0);
        __syncthreads();
    }

    // --- in-kernel BC: stage Bbc (WpairT rows 2048..2079) into Bs buf0 ---
    {
        int row = tid >> 3, pos = tid & 7, c = pos ^ (row & 7);
        #pragma unroll
        for (int t2 = 0; t2 < 2; ++t2)
            glds16(&WpairT[(size_t)(2048 + row) * 128 + t2 * 64 + c * 8],
                   &Bs[t2 * 2048 + w * 512]);
    }
    __syncthreads();
    // BC MFMA: wave w computes rows [w*32, w*32+32) x [Bm(16)|Cm(16)]
    f32x4 accB[2] = {}, accC[2] = {};
    #pragma unroll
    for (int t2 = 0; t2 < 2; ++t2) {
        const __bf16* Ab = &As[t2 * ASZ];
        #pragma unroll
        for (int h = 0; h < 2; ++h) {
            bf16x8 bB = *(const bf16x8*)&Bs[t2 * 2048 + lr * 64 + ca[h]];
            bf16x8 bC = *(const bf16x8*)&Bs[t2 * 2048 + (16 + lr) * 64 + ca[h]];
            #pragma unroll
            for (int m2 = 0; m2 < 2; ++m2) {
                bf16x8 a2 = *(const bf16x8*)&Ab[(w * 32 + m2 * 16 + lr) * 64 + ca[h]];
                accB[m2] = __builtin_amdgcn_mfma_f32_16x16x32_bf16(a2, bB, accB[m2], 0, 0, 0);
                accC[m2] = __builtin_amdgcn_mfma_f32_16x16x32_bf16(a2, bC, accC[m2], 0, 0, 0);
            }
        }
    }
    __syncthreads(); // all BC reads done before reusing Bs/As space
    float* sCB = (float*)As;      // 128 floats (As dead after BC)
    __bf16* sBC = &Bs[BSZ];       // [128][32]: Bm cols 0..15, Cm cols 16..31
    const float bB_ = bias_pair[2048 + lr], bC_ = bias_pair[2064 + lr];
    #pragma unroll
    for (int m2 = 0; m2 < 2; ++m2) {
        #pragma unroll
        for (int r = 0; r < 4; ++r) {
            int lrow = w * 32 + m2 * 16 + g * 4 + r;
            float vB = accB[m2][r] + bB_;
            float vC = accC[m2][r] + bC_;
            sBC[lrow * 32 + lr] = (__bf16)vB;
            sBC[lrow * 32 + 16 + lr] = (__bf16)vC;
            float p = vB * vC;
            #pragma unroll
            for (int m3 = 1; m3 < 16; m3 <<= 1) p += __shfl_xor(p, m3);
            if (lr == 0) sCB[lrow] = p;
        }
    }
    __syncthreads();

    // --- epilogue: d = group*16 + lr; xt = acc[m][0], de = acc[m][1] ---
    const int d = ((bn + wc * 32) >> 1) + lr;
    const float bx_ = bias_pair[bn + wc * 32 + lr];
    const float bd_ = bias_pair[bn + wc * 32 + 16 + lr];
    const bool msk = (h0mask[d >> 5] >> (d & 31)) & 1u;
    #pragma unroll
    for (int m = 0; m < 4; ++m) {
        #pragma unroll
        for (int r = 0; r < 4; ++r) {
            const int lrow = wr * 64 + m * 16 + g * 4 + r;
            const int row = bm + lrow;
            const float xt = acc[m][0][r] + bx_;
            const float dr = acc[m][1][r] + bd_;
            const float e = __expf(-fabsf(dr));
            const float de = fmaxf(dr, 0.f) + __logf(1.f + e);
            const float xd = xt * de;
            float res = xd * sCB[lrow];
            const bool is_last = (row & (LSEQ - 1)) == (LSEQ - 1);
            if (msk) {
                float s = 0.f;
                #pragma unroll
                for (int n = 0; n < NDIM; ++n) {
                    float z = de * Amat[d * NDIM + n];
                    float c2 = (z > 0.f) ? z : __expf(z) - 1.f;
                    float da = __expf(-c2);
                    float h0v = h0[d * NDIM + n];
                    s += (float)sBC[lrow * 32 + 16 + n] * da * h0v;
                    if (is_last)
                        last_h[(((size_t)(row >> 11)) * DDIM + d) * NDIM + n] =
                            da * h0v + xd * (float)sBC[lrow * 32 + n];
                }
                res += s;
            } else if (is_last) {
                #pragma unroll
                for (int n = 0; n < NDIM; ++n)
                    last_h[(((size_t)(row >> 11)) * DDIM + d) * NDIM + n] =
                        xd * (float)sBC[lrow * 32 + n];
            }
            out[(size_t)row * DDIM + d] = res;
        }
    }
}

extern "C" void kernel_launch(void* const* d_in, const int* in_sizes, int n_in,
                              void* d_out, int out_size, void* d_ws, size_t ws_size,
                              hipStream_t stream) {
    const float* x   = (const float*)d_in[0];
    const float* W1  = (const float*)d_in[1];
    const float* b1  = (const float*)d_in[2];
    const float* W2  = (const float*)d_in[3];
    const float* b2  = (const float*)d_in[4];
    const float* W3  = (const float*)d_in[5];
    const float* b3  = (const float*)d_in[6];
    const float* Wl1 = (const float*)d_in[7];
    const float* bl1 = (const float*)d_in[8];
    const float* Wl2 = (const float*)d_in[9];
    const float* bl2 = (const float*)d_in[10];
    const float* Wf1 = (const float*)d_in[11];
    const float* bf1 = (const float*)d_in[12];
    const float* Wf2 = (const float*)d_in[13];
    const float* bf2 = (const float*)d_in[14];
    const float* h0  = (const float*)d_in[15];
    const float* Amat= (const float*)d_in[16];

    float* out    = (float*)d_out;
    float* last_h = (float*)d_out + (size_t)MROWS * DDIM;

    __bf16* wsb = (__bf16*)d_ws;
    size_t o = 0;
    auto alloc = [&](size_t n) { __bf16* p = wsb + o; o += n; return p; };
    __bf16* WaT    = alloc(256 * 1024);             // [Wl1 | Wf1_top]^T
    __bf16* Wf1bT  = alloc(128 * 1024);
    __bf16* Wl2T   = alloc(1024 * 128);
    __bf16* WbigT  = alloc((size_t)NPAD * 1024);    // [W1 | W2 | W3 | pad]^T
    __bf16* WpairT = alloc(2112 * 128);             // pairs 0..2047, BC 2048..2079
    __bf16* Wf2c   = alloc(128 * 1024);             // Wf2 bf16 row-major
    __bf16* tmp12  = alloc((size_t)MROWS * 256);    // [relu(x@Wl1+bl1) | x@Wf1_top]
    __bf16* lifted = alloc((size_t)MROWS * DDIM);
    __bf16* tmp2   = alloc((size_t)MROWS * HDIM);
    float*  bias_pair = (float*)(wsb + o); o += 2 * 2112;
    unsigned* h0mask = (unsigned*)(wsb + o);

    // 1. pack (flat 1797 blocks)
    pack_all<<<dim3(1797), 256, 0, stream>>>(W1, W2, W3, Wl1, Wl2, Wf1, Wf2,
                                             bf2, h0,
                                             WbigT, WaT, Wf1bT, Wl2T, WpairT,
                                             Wf2c, bias_pair, h0mask);
    // 2. merged: G1 (512) + Gpre (34) + bias fold (264)
    stage2_k<<<dim3(810), 256, 0, stream>>>(x, WaT, WbigT, Wf2c, bf2, b1, b2, b3,
                                            bl1, tmp12, WpairT, bias_pair);
    // 3. G2: lifted = tanh(tmp12[:,:128] @ Wl2 + bl2)  M=4096 N=1024 K=128, 1024 blk
    mm<64, 64, 2, false, false><<<dim3(16 * 64), 256, 0, stream>>>(
        tmp12, 256, Wl2T, 128, 1024, bl2, nullptr, 0, lifted, DDIM, 128, 16);
    // 4. G3: tmp2 = relu(lifted@Wf1_bot + bf1 + tmp12[:,128:]) M=4096 N=128 K=1024, 512 blk
    mm<32, 32, 1, true, false><<<dim3(4 * 128), 256, 0, stream>>>(
        lifted, DDIM, Wf1bT, 1024, 128, bf1, tmp12 + 128, 256, tmp2, HDIM, 1024, 4);
    // 5. mm_pairs: fused [x_tr|delta] GEMM + BC + final epilogue -> out, last_h
    mm_pairs<<<dim3(32 * 32), 256, 0, stream>>>(tmp2, WpairT, bias_pair,
                                                Amat, h0, h0mask, out, last_h);
}

// Round 13
// 54.105 us; speedup vs baseline: 3.2705x; 1.0426x over previous
//
#include <hip/hip_runtime.h>
#include <cmath>

#define B_SZ 2
#define LSEQ 2048
#define DDIM 1024
#define NDIM 16
#define HDIM 128
#define MROWS (B_SZ * LSEQ)    // 4096
#define NBIG (DDIM + 2 * NDIM) // 1056
#define NPAD 1088              // NBIG padded to 64

typedef __bf16 bf16x8 __attribute__((ext_vector_type(8)));
typedef __bf16 bf16x4 __attribute__((ext_vector_type(4)));
typedef float f32x4 __attribute__((ext_vector_type(4)));

// async global->LDS, 16B/lane; LDS dest = wave-uniform base + lane*16
__device__ __forceinline__ void glds16(const __bf16* g, __bf16* l) {
    __builtin_amdgcn_global_load_lds(
        (const __attribute__((address_space(1))) unsigned int*)g,
        (__attribute__((address_space(3))) unsigned int*)l, 16, 0, 0);
}

// pair-layout row slots
__device__ __forceinline__ int slot_xt(int d) { return (d >> 4) * 32 + (d & 15); }
__device__ __forceinline__ int slot_de(int d) { return (d >> 4) * 32 + 16 + (d & 15); }

// ---------------------------------------------------------------------------
// Preprocessing (flat 1-D grid, 1797 blocks).
// ---------------------------------------------------------------------------
__device__ __forceinline__ void tcast_tile(const float* __restrict__ in,
                                           __bf16* __restrict__ out, int K, int N,
                                           int bx, int by, float (*t)[33]) {
    int tx = threadIdx.x & 31, ty = threadIdx.x >> 5;
    int n0 = bx * 32, k0 = by * 32;
    #pragma unroll
    for (int i = 0; i < 4; ++i) {
        int k = k0 + ty + i * 8, n = n0 + tx;
        t[ty + i * 8][tx] = (k < K && n < N) ? in[(size_t)k * N + n] : 0.f;
    }
    __syncthreads();
    #pragma unroll
    for (int i = 0; i < 4; ++i) {
        int n = n0 + ty + i * 8, k = k0 + tx;
        if (n < N && k < K) out[(size_t)n * K + k] = (__bf16)t[tx][ty + i * 8];
    }
}

// Wf2 [128][1024] -> WpairT xt slots (row slot_xt(n), ld 128)
__device__ __forceinline__ void tcast_pair_tile(const float* __restrict__ in,
                                                __bf16* __restrict__ out,
                                                int bx, int by, float (*t)[33]) {
    int tx = threadIdx.x & 31, ty = threadIdx.x >> 5;
    int n0 = bx * 32, k0 = by * 32;
    #pragma unroll
    for (int i = 0; i < 4; ++i) {
        int k = k0 + ty + i * 8, n = n0 + tx;
        t[ty + i * 8][tx] = in[(size_t)k * 1024 + n];
    }
    __syncthreads();
    #pragma unroll
    for (int i = 0; i < 4; ++i) {
        int n = n0 + ty + i * 8, k = k0 + tx;
        out[(size_t)slot_xt(n) * 128 + k] = (__bf16)t[tx][ty + i * 8];
    }
}

__global__ __launch_bounds__(256) void pack_all(
    const float* W1, const float* W2, const float* W3, const float* Wl1,
    const float* Wl2, const float* Wf1, const float* Wf2,
    const float* bf2, const float* h0,
    __bf16* WbigT, __bf16* WaT, __bf16* Wf1bT, __bf16* Wl2T, __bf16* WpairT,
    __bf16* Wf2c, float* bias_pair, unsigned* h0mask) {
    __shared__ float t[32][33];
    const int b = blockIdx.x;
    const int tid = threadIdx.x;
    if (b < 1024) {                       // W1 -> WbigT
        tcast_tile(W1, WbigT, 1024, 1024, b & 31, b >> 5, t);
    } else if (b < 1152) {                // Wl1 -> WaT
        int i = b - 1024; tcast_tile(Wl1, WaT, 1024, 128, i & 3, i >> 2, t);
    } else if (b < 1280) {                // Wf1 top -> WaT[128k..]
        int i = b - 1152; tcast_tile(Wf1, WaT + 128 * 1024, 1024, 128, i & 3, i >> 2, t);
    } else if (b < 1408) {                // Wf1 bottom -> Wf1bT
        int i = b - 1280;
        tcast_tile(Wf1 + (size_t)1024 * 128, Wf1bT, 1024, 128, i & 3, i >> 2, t);
    } else if (b < 1536) {                // Wl2 -> Wl2T
        int i = b - 1408; tcast_tile(Wl2, Wl2T, 128, 1024, i & 31, i >> 5, t);
    } else if (b < 1664) {                // Wf2 -> WpairT xt slots
        int i = b - 1536; tcast_pair_tile(Wf2, WpairT, i & 31, i >> 5, t);
    } else if (b < 1696) {                // W2 -> WbigT[1024..]
        int i = b - 1664; tcast_tile(W2, WbigT + (size_t)1024 * 1024, 1024, 16, 0, i, t);
    } else if (b < 1728) {                // W3 -> WbigT[1040..]
        int i = b - 1696; tcast_tile(W3, WbigT + (size_t)1040 * 1024, 1024, 16, 0, i, t);
    } else if (b < 1732) {                // xt bias scatter
        int i = (b - 1728) * 256 + tid;
        bias_pair[slot_xt(i)] = bf2[i];
    } else if (b < 1764) {                // zero WbigT pad rows
        int i = (b - 1732) * 256 + tid;
        #pragma unroll
        for (int r = 0; r < 4; ++r) {
            int e = i + r * 8192;
            if (e < 32 * 1024) WbigT[(size_t)1056 * 1024 + e] = (__bf16)0.f;
        }
    } else if (b < 1796) {                // Wf2 -> Wf2c row-major bf16
        int id = (b - 1764) * 256 + tid;
        #pragma unroll
        for (int j = 0; j < 4; ++j) {
            int e = id + j * 8192;
            float4 v = ((const float4*)Wf2)[e];
            bf16x4 o2 = {(__bf16)v.x, (__bf16)v.y, (__bf16)v.z, (__bf16)v.w};
            ((bf16x4*)Wf2c)[e] = o2;
        }
    } else {                              // h0 nonzero bitmask
        __shared__ unsigned sm[32];
        if (tid < 32) sm[tid] = 0u;
        __syncthreads();
        unsigned nib = 0;
        #pragma unroll
        for (int j = 0; j < 4; ++j) {
            int d = tid * 4 + j;
            const uint4* hu = (const uint4*)(h0 + d * NDIM);
            uint4 a0 = hu[0], a1 = hu[1], a2 = hu[2], a3 = hu[3];
            unsigned nz = a0.x | a0.y | a0.z | a0.w | a1.x | a1.y | a1.z | a1.w |
                          a2.x | a2.y | a2.z | a2.w | a3.x | a3.y | a3.z | a3.w;
            if (nz) nib |= (1u << j);
        }
        if (nib) atomicOr(&sm[(tid * 4) >> 5], nib << ((tid * 4) & 31));
        __syncthreads();
        if (tid < 32) h0mask[tid] = sm[tid];
    }
}

// ---------------------------------------------------------------------------
// Core BMxBN MFMA GEMM, templated BK (64/128/256) and NBUF (1=single-stage,
// 2=double-buffered). 8-slot XOR swizzle c = pos ^ (row&7) on both sides
// (involution, rule #21) — bank behavior identical across BK choices.
// ACT: 1 relu(+prev), 2 fast-tanh, 4 split128-relu, 7 pair-scatter raw (Gpre)
// ---------------------------------------------------------------------------
template <int BM, int BN, int BK, int NBUF, int ACT, bool ADD_PREV, bool GUARDN, bool AF32>
__device__ __forceinline__ void gemm_core(
    const void* Av, int lda, const __bf16* __restrict__ Bt, int ldb, int Ntot,
    const float* __restrict__ bias, const __bf16* __restrict__ prev, int ldp,
    __bf16* __restrict__ C, int ldc, int K, int bm, int bn,
    __bf16* As, __bf16* Bs) {
    constexpr int WM = BM / 2, WN = BN / 2, FM = WM / 16, FN = WN / 16;
    constexpr int ASZ = BM * BK, BSZ = BN * BK;
    constexpr int CPR = BK / 8;   // 16B chunks per row
    constexpr int NH = BK / 32;   // k-slices of 32 per tile
    const int tid = threadIdx.x;
    const int lane = tid & 63, w = tid >> 6;
    const int wr = w >> 1, wc = w & 1;
    const int g = lane >> 4, lr = lane & 15;
    const __bf16* A16 = (const __bf16*)Av;
    const float* A32 = (const float*)Av;

    auto stage = [&](int buf, int k0) {
        #pragma unroll
        for (int i = 0; i < BM * BK / 2048; ++i) {
            int D = i * 256 + tid;
            int row = D / CPR, pos = D % CPR, c = pos ^ (row & 7);
            if constexpr (AF32) {
                const float* s = &A32[(size_t)(bm + row) * lda + k0 + c * 8];
                float4 v0 = *(const float4*)s;
                float4 v1 = *(const float4*)(s + 4);
                bf16x8 pk = {(__bf16)v0.x, (__bf16)v0.y, (__bf16)v0.z, (__bf16)v0.w,
                             (__bf16)v1.x, (__bf16)v1.y, (__bf16)v1.z, (__bf16)v1.w};
                *(bf16x8*)&As[buf * ASZ + row * BK + pos * 8] = pk;
            } else {
                glds16(&A16[(size_t)(bm + row) * lda + k0 + c * 8],
                       &As[buf * ASZ + (i * 256 + w * 64) * 8]);
            }
        }
        #pragma unroll
        for (int i = 0; i < BN * BK / 2048; ++i) {
            int D = i * 256 + tid;
            int row = D / CPR, pos = D % CPR, c = pos ^ (row & 7);
            glds16(&Bt[(size_t)(bn + row) * ldb + k0 + c * 8],
                   &Bs[buf * BSZ + (i * 256 + w * 64) * 8]);
        }
    };

    f32x4 acc[FM][FN] = {};
    const int x7 = lr & 7;
    int ca[NH];
    #pragma unroll
    for (int h = 0; h < NH; ++h) ca[h] = ((h * 4 + g) ^ x7) * 8;
    const int arow0 = wr * WM + lr;
    const int brow0 = wc * WN + lr;

    const int nt = K / BK;
    stage(0, 0);
    __syncthreads();
    for (int t = 0; t < nt; ++t) {
        if (NBUF == 2 && t + 1 < nt) stage((t + 1) & 1, (t + 1) * BK);
        const __bf16* Ab = &As[(NBUF == 2 ? (t & 1) : 0) * ASZ];
        const __bf16* Bb = &Bs[(NBUF == 2 ? (t & 1) : 0) * BSZ];
        bf16x8 af[FM][NH], bfr[FN][NH];
        #pragma unroll
        for (int m = 0; m < FM; ++m)
            #pragma unroll
            for (int h = 0; h < NH; ++h)
                af[m][h] = *(const bf16x8*)&Ab[(arow0 + m * 16) * BK + ca[h]];
        #pragma unroll
        for (int n = 0; n < FN; ++n)
            #pragma unroll
            for (int h = 0; h < NH; ++h)
                bfr[n][h] = *(const bf16x8*)&Bb[(brow0 + n * 16) * BK + ca[h]];
        #pragma unroll
        for (int h = 0; h < NH; ++h)
            #pragma unroll
            for (int m = 0; m < FM; ++m)
                #pragma unroll
                for (int n = 0; n < FN; ++n)
                    acc[m][n] = __builtin_amdgcn_mfma_f32_16x16x32_bf16(
                        af[m][h], bfr[n][h], acc[m][n], 0, 0, 0);
        __syncthreads();
    }

    // epilogue: C/D layout col=lane&15, row=(lane>>4)*4+reg
    #pragma unroll
    for (int m = 0; m < FM; ++m) {
        #pragma unroll
        for (int n = 0; n < FN; ++n) {
            #pragma unroll
            for (int r = 0; r < 4; ++r) {
                int grow = bm + wr * WM + m * 16 + g * 4 + r;
                int gcol = bn + wc * WN + n * 16 + lr;
                if (!GUARDN || gcol < Ntot) {
                    float v = acc[m][n][r];
                    int orow = grow;
                    if (ACT == 1) {
                        v += bias[gcol];
                        if (ADD_PREV) v += (float)prev[(size_t)grow * ldp + gcol];
                        v = fmaxf(v, 0.f);
                    } else if (ACT == 2) { // fast tanh: 1 - 2/(1+e^2v)
                        v += bias[gcol];
                        float e = __expf(2.f * v);
                        v = 1.f - 2.f * __builtin_amdgcn_rcpf(e + 1.f);
                    } else if (ACT == 4) {
                        if (gcol < HDIM) v = fmaxf(v + bias[gcol], 0.f);
                    } else if (ACT == 7) { // Gpre pair-scatter, raw
                        orow = (grow < 1024) ? slot_de(grow) : 2048 + (grow - 1024);
                    }
                    C[(size_t)orow * ldc + gcol] = (__bf16)v;
                }
            }
        }
    }
}

// thin global wrapper (1-D grid, bijective XCD swizzle when NB%8==0)
template <int BM, int BN, int BK, int NBUF, int ACT, bool ADD_PREV, bool GUARDN>
__global__ __launch_bounds__(256) void mm(const __bf16* __restrict__ A, int lda,
                                          const __bf16* __restrict__ Bt, int ldb, int Ntot,
                                          const float* __restrict__ bias,
                                          const __bf16* __restrict__ prev, int ldp,
                                          __bf16* __restrict__ C, int ldc, int K, int nbx) {
    __shared__ __bf16 As[NBUF * BM * BK];
    __shared__ __bf16 Bs[NBUF * BN * BK];
    const int NB = gridDim.x;
    const int aid = ((NB & 7) == 0)
                        ? (blockIdx.x & 7) * (NB >> 3) + (blockIdx.x >> 3)
                        : blockIdx.x;
    const int bn = (aid % nbx) * BN, bm = (aid / nbx) * BM;
    gemm_core<BM, BN, BK, NBUF, ACT, ADD_PREV, GUARDN, false>(
        A, lda, Bt, ldb, Ntot, bias, prev, ldp, C, ldc, K, bm, bn, As, Bs);
}

// ---------------------------------------------------------------------------
// Merged stage-2: [0,512) G1 (x fp32 reg-staged, BK=128); [512,546) Gpre
// (BK=64) -> WpairT; [546,810) bias fold -> bias_pair.
// Shared buffers sized for the max user: As 8192, Bs 16384 elems (48 KB).
// ---------------------------------------------------------------------------
__global__ __launch_bounds__(256) void stage2_k(
    const float* __restrict__ x, const __bf16* __restrict__ WaT,
    const __bf16* __restrict__ WbigT, const __bf16* __restrict__ Wf2c,
    const float* __restrict__ bf2, const float* __restrict__ b1,
    const float* __restrict__ b2, const float* __restrict__ b3,
    const float* __restrict__ bl1,
    __bf16* __restrict__ tmp12, __bf16* __restrict__ WpairT,
    float* __restrict__ bias_pair) {
    __shared__ __bf16 As[8192];
    __shared__ __bf16 Bs[16384];
    const int b = blockIdx.x;
    if (b < 512) {
        // G1: tmp12 = [relu(x@Wl1+bl1) | x@Wf1_top]  M=4096 N=256 K=1024
        const int aid = (b & 7) * 64 + (b >> 3);
        const int bn = (aid & 3) * 64, bm = (aid >> 2) * 32;
        gemm_core<32, 64, 128, 2, 4, false, false, true>(
            x, DDIM, WaT, 1024, 256, bl1, nullptr, 0, tmp12, 256, 1024, bm, bn, As, Bs);
    } else if (b < 546) {
        // Gpre: Wcomb cols scattered into WpairT delta/BC slots  M=1088 N=128 K=1024
        const int aid = b - 512;
        const int bn = (aid & 1) * 64, bm = (aid >> 1) * 64;
        gemm_core<64, 64, 64, 2, 7, false, false, false>(
            WbigT, 1024, Wf2c, 1024, 128, nullptr, nullptr, 0,
            WpairT, 128, 1024, bm, bn, As, Bs);
    } else {
        // bias fold: fold(n) = ball[n] + sum_d bf2[d]*Wall[d][n] -> pair/BC slots
        const int n = (b - 546) * 4 + (threadIdx.x >> 6);
        const int lane = threadIdx.x & 63;
        const __bf16* wr = WbigT + (size_t)n * 1024 + lane * 16;
        float s = 0.f;
        #pragma unroll
        for (int i = 0; i < 2; ++i) {
            bf16x8 wv = *(const bf16x8*)&wr[i * 8];
            float4 f0 = *(const float4*)&bf2[lane * 16 + i * 8];
            float4 f1 = *(const float4*)&bf2[lane * 16 + i * 8 + 4];
            s += (float)wv[0] * f0.x + (float)wv[1] * f0.y + (float)wv[2] * f0.z +
                 (float)wv[3] * f0.w + (float)wv[4] * f1.x + (float)wv[5] * f1.y +
                 (float)wv[6] * f1.z + (float)wv[7] * f1.w;
        }
        #pragma unroll
        for (int off = 32; off; off >>= 1) s += __shfl_down(s, off);
        if (lane == 0) {
            float base = (n < DDIM) ? b1[n]
                       : (n < DDIM + NDIM) ? b2[n - DDIM] : b3[n - DDIM - NDIM];
            int sl = (n < DDIM) ? slot_de(n) : 2048 + (n - DDIM);
            bias_pair[sl] = base + s;
        }
    }
}

// ---------------------------------------------------------------------------
// mm_pairs: [xt|de] pair GEMM + in-kernel BC (Bm/Cm/cb) + final epilogue.
// M=4096 N=2048 K=128. BM=128 BN=64, 1024 blocks, LDS 48 KB. (unchanged R12)
// ---------------------------------------------------------------------------
__global__ __launch_bounds__(256) void mm_pairs(
    const __bf16* __restrict__ tmp2, const __bf16* __restrict__ WpairT,
    const float* __restrict__ bias_pair,
    const float* __restrict__ Amat, const float* __restrict__ h0,
    const unsigned* __restrict__ h0mask,
    float* __restrict__ out, float* __restrict__ last_h) {
    constexpr int ASZ = 128 * 64, BSZ = 64 * 64;
    __shared__ __bf16 As[2 * ASZ];
    __shared__ __bf16 Bs[2 * BSZ];
    const int NB = gridDim.x; // 1024
    const int aid = (blockIdx.x & 7) * (NB >> 3) + (blockIdx.x >> 3);
    const int bn = (aid & 31) * 64, bm = (aid >> 5) * 128;
    const int tid = threadIdx.x;
    const int lane = tid & 63, w = tid >> 6;
    const int wr = w >> 1, wc = w & 1;
    const int g = lane >> 4, lr = lane & 15;

    auto stage = [&](int buf, int k0) {
        #pragma unroll
        for (int i = 0; i < 4; ++i) {
            int D = i * 256 + tid;
            int row = D >> 3, pos = D & 7, c = pos ^ (row & 7);
            glds16(&tmp2[(size_t)(bm + row) * 128 + k0 + c * 8],
                   &As[buf * ASZ + (i * 256 + w * 64) * 8]);
        }
        #pragma unroll
        for (int i = 0; i < 2; ++i) {
            int D = i * 256 + tid;
            int row = D >> 3, pos = D & 7, c = pos ^ (row & 7);
            glds16(&WpairT[(size_t)(bn + row) * 128 + k0 + c * 8],
                   &Bs[buf * BSZ + (i * 256 + w * 64) * 8]);
        }
    };

    f32x4 acc[4][2] = {};
    const int x7 = lr & 7;
    const int ca[2] = {(g ^ x7) * 8, ((4 + g) ^ x7) * 8};
    const int arow0 = wr * 64 + lr, brow0 = wc * 32 + lr;
    stage(0, 0);
    __syncthreads();
    #pragma unroll
    for (int t = 0; t < 2; ++t) {
        if (t == 0) stage(1, 64);
        const __bf16* Ab = &As[t * ASZ];
        const __bf16* Bb = &Bs[t * BSZ];
        bf16x8 af[4][2], bfr[2][2];
        #pragma unroll
        for (int m = 0; m < 4; ++m)
            #pragma unroll
            for (int h = 0; h < 2; ++h)
                af[m][h] = *(const bf16x8*)&Ab[(arow0 + m * 16) * 64 + ca[h]];
        #pragma unroll
        for (int n = 0; n < 2; ++n)
            #pragma unroll
            for (int h = 0; h < 2; ++h)
                bfr[n][h] = *(const bf16x8*)&Bb[(brow0 + n * 16) * 64 + ca[h]];
        #pragma unroll
        for (int h = 0; h < 2; ++h)
            #pragma unroll
            for (int m = 0; m < 4; ++m)
                #pragma unroll
                for (int n = 0; n < 2; ++n)
                    acc[m][n] = __builtin_amdgcn_mfma_f32_16x16x32_bf16(
                        af[m][h], bfr[n][h], acc[m][n], 0, 0, 0);
        __syncthreads();
    }

    // --- in-kernel BC: stage Bbc (WpairT rows 2048..2079) into Bs buf0 ---
    {
        int row = tid >> 3, pos = tid & 7, c = pos ^ (row & 7);
        #pragma unroll
        for (int t2 = 0; t2 < 2; ++t2)
            glds16(&WpairT[(size_t)(2048 + row) * 128 + t2 * 64 + c * 8],
                   &Bs[t2 * 2048 + w * 512]);
    }
    __syncthreads();
    f32x4 accB[2] = {}, accC[2] = {};
    #pragma unroll
    for (int t2 = 0; t2 < 2; ++t2) {
        const __bf16* Ab = &As[t2 * ASZ];
        #pragma unroll
        for (int h = 0; h < 2; ++h) {
            bf16x8 bB = *(const bf16x8*)&Bs[t2 * 2048 + lr * 64 + ca[h]];
            bf16x8 bC = *(const bf16x8*)&Bs[t2 * 2048 + (16 + lr) * 64 + ca[h]];
            #pragma unroll
            for (int m2 = 0; m2 < 2; ++m2) {
                bf16x8 a2 = *(const bf16x8*)&Ab[(w * 32 + m2 * 16 + lr) * 64 + ca[h]];
                accB[m2] = __builtin_amdgcn_mfma_f32_16x16x32_bf16(a2, bB, accB[m2], 0, 0, 0);
                accC[m2] = __builtin_amdgcn_mfma_f32_16x16x32_bf16(a2, bC, accC[m2], 0, 0, 0);
            }
        }
    }
    __syncthreads();
    float* sCB = (float*)As;
    __bf16* sBC = &Bs[BSZ];
    const float bB_ = bias_pair[2048 + lr], bC_ = bias_pair[2064 + lr];
    #pragma unroll
    for (int m2 = 0; m2 < 2; ++m2) {
        #pragma unroll
        for (int r = 0; r < 4; ++r) {
            int lrow = w * 32 + m2 * 16 + g * 4 + r;
            float vB = accB[m2][r] + bB_;
            float vC = accC[m2][r] + bC_;
            sBC[lrow * 32 + lr] = (__bf16)vB;
            sBC[lrow * 32 + 16 + lr] = (__bf16)vC;
            float p = vB * vC;
            #pragma unroll
            for (int m3 = 1; m3 < 16; m3 <<= 1) p += __shfl_xor(p, m3);
            if (lr == 0) sCB[lrow] = p;
        }
    }
    __syncthreads();

    const int d = ((bn + wc * 32) >> 1) + lr;
    const float bx_ = bias_pair[bn + wc * 32 + lr];
    const float bd_ = bias_pair[bn + wc * 32 + 16 + lr];
    const bool msk = (h0mask[d >> 5] >> (d & 31)) & 1u;
    #pragma unroll
    for (int m = 0; m < 4; ++m) {
        #pragma unroll
        for (int r = 0; r < 4; ++r) {
            const int lrow = wr * 64 + m * 16 + g * 4 + r;
            const int row = bm + lrow;
            const float xt = acc[m][0][r] + bx_;
            const float dr = acc[m][1][r] + bd_;
            const float e = __expf(-fabsf(dr));
            const float de = fmaxf(dr, 0.f) + __logf(1.f + e);
            const float xd = xt * de;
            float res = xd * sCB[lrow];
            const bool is_last = (row & (LSEQ - 1)) == (LSEQ - 1);
            if (msk) {
                float s = 0.f;
                #pragma unroll
                for (int n = 0; n < NDIM; ++n) {
                    float z = de * Amat[d * NDIM + n];
                    float c2 = (z > 0.f) ? z : __expf(z) - 1.f;
                    float da = __expf(-c2);
                    float h0v = h0[d * NDIM + n];
                    s += (float)sBC[lrow * 32 + 16 + n] * da * h0v;
                    if (is_last)
                        last_h[(((size_t)(row >> 11)) * DDIM + d) * NDIM + n] =
                            da * h0v + xd * (float)sBC[lrow * 32 + n];
                }
                res += s;
            } else if (is_last) {
                #pragma unroll
                for (int n = 0; n < NDIM; ++n)
                    last_h[(((size_t)(row >> 11)) * DDIM + d) * NDIM + n] =
                        xd * (float)sBC[lrow * 32 + n];
            }
            out[(size_t)row * DDIM + d] = res;
        }
    }
}

extern "C" void kernel_launch(void* const* d_in, const int* in_sizes, int n_in,
                              void* d_out, int out_size, void* d_ws, size_t ws_size,
                              hipStream_t stream) {
    const float* x   = (const float*)d_in[0];
    const float* W1  = (const float*)d_in[1];
    const float* b1  = (const float*)d_in[2];
    const float* W2  = (const float*)d_in[3];
    const float* b2  = (const float*)d_in[4];
    const float* W3  = (const float*)d_in[5];
    const float* b3  = (const float*)d_in[6];
    const float* Wl1 = (const float*)d_in[7];
    const float* bl1 = (const float*)d_in[8];
    const float* Wl2 = (const float*)d_in[9];
    const float* bl2 = (const float*)d_in[10];
    const float* Wf1 = (const float*)d_in[11];
    const float* bf1 = (const float*)d_in[12];
    const float* Wf2 = (const float*)d_in[13];
    const float* bf2 = (const float*)d_in[14];
    const float* h0  = (const float*)d_in[15];
    const float* Amat= (const float*)d_in[16];

    float* out    = (float*)d_out;
    float* last_h = (float*)d_out + (size_t)MROWS * DDIM;

    __bf16* wsb = (__bf16*)d_ws;
    size_t o = 0;
    auto alloc = [&](size_t n) { __bf16* p = wsb + o; o += n; return p; };
    __bf16* WaT    = alloc(256 * 1024);             // [Wl1 | Wf1_top]^T
    __bf16* Wf1bT  = alloc(128 * 1024);
    __bf16* Wl2T   = alloc(1024 * 128);
    __bf16* WbigT  = alloc((size_t)NPAD * 1024);    // [W1 | W2 | W3 | pad]^T
    __bf16* WpairT = alloc(2112 * 128);             // pairs 0..2047, BC 2048..2079
    __bf16* Wf2c   = alloc(128 * 1024);             // Wf2 bf16 row-major
    __bf16* tmp12  = alloc((size_t)MROWS * 256);    // [relu(x@Wl1+bl1) | x@Wf1_top]
    __bf16* lifted = alloc((size_t)MROWS * DDIM);
    __bf16* tmp2   = alloc((size_t)MROWS * HDIM);
    float*  bias_pair = (float*)(wsb + o); o += 2 * 2112;
    unsigned* h0mask = (unsigned*)(wsb + o);

    // 1. pack (flat 1797 blocks)
    pack_all<<<dim3(1797), 256, 0, stream>>>(W1, W2, W3, Wl1, Wl2, Wf1, Wf2,
                                             bf2, h0,
                                             WbigT, WaT, Wf1bT, Wl2T, WpairT,
                                             Wf2c, bias_pair, h0mask);
    // 2. merged: G1 (512, BK=128) + Gpre (34, BK=64) + bias fold (264)
    stage2_k<<<dim3(810), 256, 0, stream>>>(x, WaT, WbigT, Wf2c, bf2, b1, b2, b3,
                                            bl1, tmp12, WpairT, bias_pair);
    // 3. G2: lifted = tanh(tmp12[:,:128] @ Wl2 + bl2)  M=4096 N=1024 K=128
    //    BK=128 single-stage (1 barrier), 1024 blk, LDS 32 KB
    mm<64, 64, 128, 1, 2, false, false><<<dim3(16 * 64), 256, 0, stream>>>(
        tmp12, 256, Wl2T, 128, 1024, bl2, nullptr, 0, lifted, DDIM, 128, 16);
    // 4. G3: tmp2 = relu(lifted@Wf1_bot + bf1 + tmp12[:,128:]) M=4096 N=128 K=1024
    //    BK=256 (nt=4), 512 blk, LDS 64 KB
    mm<32, 32, 256, 2, 1, true, false><<<dim3(4 * 128), 256, 0, stream>>>(
        lifted, DDIM, Wf1bT, 1024, 128, bf1, tmp12 + 128, 256, tmp2, HDIM, 1024, 4);
    // 5. mm_pairs: fused [x_tr|delta] GEMM + BC + final epilogue -> out, last_h
    mm_pairs<<<dim3(32 * 32), 256, 0, stream>>>(tmp2, WpairT, bias_pair,
                                                Amat, h0, h0mask, out, last_h);
}

// Round 14
// 53.237 us; speedup vs baseline: 3.3238x; 1.0163x over previous
//
#include <hip/hip_runtime.h>
#include <cmath>

#define B_SZ 2
#define LSEQ 2048
#define DDIM 1024
#define NDIM 16
#define HDIM 128
#define MROWS (B_SZ * LSEQ)    // 4096
#define NBIG (DDIM + 2 * NDIM) // 1056
#define NPAD 1088              // NBIG padded to 64

typedef __bf16 bf16x8 __attribute__((ext_vector_type(8)));
typedef __bf16 bf16x4 __attribute__((ext_vector_type(4)));
typedef float f32x4 __attribute__((ext_vector_type(4)));

// async global->LDS, 16B/lane; LDS dest = wave-uniform base + lane*16
__device__ __forceinline__ void glds16(const __bf16* g, __bf16* l) {
    __builtin_amdgcn_global_load_lds(
        (const __attribute__((address_space(1))) unsigned int*)g,
        (__attribute__((address_space(3))) unsigned int*)l, 16, 0, 0);
}

// pair-layout row slots
__device__ __forceinline__ int slot_xt(int d) { return (d >> 4) * 32 + (d & 15); }
__device__ __forceinline__ int slot_de(int d) { return (d >> 4) * 32 + 16 + (d & 15); }

// ---------------------------------------------------------------------------
// Preprocessing (flat 1-D grid, 1797 blocks).
// ---------------------------------------------------------------------------
__device__ __forceinline__ void tcast_tile(const float* __restrict__ in,
                                           __bf16* __restrict__ out, int K, int N,
                                           int bx, int by, float (*t)[33]) {
    int tx = threadIdx.x & 31, ty = threadIdx.x >> 5;
    int n0 = bx * 32, k0 = by * 32;
    #pragma unroll
    for (int i = 0; i < 4; ++i) {
        int k = k0 + ty + i * 8, n = n0 + tx;
        t[ty + i * 8][tx] = (k < K && n < N) ? in[(size_t)k * N + n] : 0.f;
    }
    __syncthreads();
    #pragma unroll
    for (int i = 0; i < 4; ++i) {
        int n = n0 + ty + i * 8, k = k0 + tx;
        if (n < N && k < K) out[(size_t)n * K + k] = (__bf16)t[tx][ty + i * 8];
    }
}

// Wf2 [128][1024] -> WpairT xt slots (row slot_xt(n), ld 128)
__device__ __forceinline__ void tcast_pair_tile(const float* __restrict__ in,
                                                __bf16* __restrict__ out,
                                                int bx, int by, float (*t)[33]) {
    int tx = threadIdx.x & 31, ty = threadIdx.x >> 5;
    int n0 = bx * 32, k0 = by * 32;
    #pragma unroll
    for (int i = 0; i < 4; ++i) {
        int k = k0 + ty + i * 8, n = n0 + tx;
        t[ty + i * 8][tx] = in[(size_t)k * 1024 + n];
    }
    __syncthreads();
    #pragma unroll
    for (int i = 0; i < 4; ++i) {
        int n = n0 + ty + i * 8, k = k0 + tx;
        out[(size_t)slot_xt(n) * 128 + k] = (__bf16)t[tx][ty + i * 8];
    }
}

__global__ __launch_bounds__(256) void pack_all(
    const float* W1, const float* W2, const float* W3, const float* Wl1,
    const float* Wl2, const float* Wf1, const float* Wf2,
    const float* bf2, const float* h0,
    __bf16* WbigT, __bf16* WaT, __bf16* Wf1bT, __bf16* Wl2T, __bf16* WpairT,
    __bf16* Wf2c, float* bias_pair, unsigned* h0mask) {
    __shared__ float t[32][33];
    const int b = blockIdx.x;
    const int tid = threadIdx.x;
    if (b < 1024) {                       // W1 -> WbigT
        tcast_tile(W1, WbigT, 1024, 1024, b & 31, b >> 5, t);
    } else if (b < 1152) {                // Wl1 -> WaT
        int i = b - 1024; tcast_tile(Wl1, WaT, 1024, 128, i & 3, i >> 2, t);
    } else if (b < 1280) {                // Wf1 top -> WaT[128k..]
        int i = b - 1152; tcast_tile(Wf1, WaT + 128 * 1024, 1024, 128, i & 3, i >> 2, t);
    } else if (b < 1408) {                // Wf1 bottom -> Wf1bT
        int i = b - 1280;
        tcast_tile(Wf1 + (size_t)1024 * 128, Wf1bT, 1024, 128, i & 3, i >> 2, t);
    } else if (b < 1536) {                // Wl2 -> Wl2T
        int i = b - 1408; tcast_tile(Wl2, Wl2T, 128, 1024, i & 31, i >> 5, t);
    } else if (b < 1664) {                // Wf2 -> WpairT xt slots
        int i = b - 1536; tcast_pair_tile(Wf2, WpairT, i & 31, i >> 5, t);
    } else if (b < 1696) {                // W2 -> WbigT[1024..]
        int i = b - 1664; tcast_tile(W2, WbigT + (size_t)1024 * 1024, 1024, 16, 0, i, t);
    } else if (b < 1728) {                // W3 -> WbigT[1040..]
        int i = b - 1696; tcast_tile(W3, WbigT + (size_t)1040 * 1024, 1024, 16, 0, i, t);
    } else if (b < 1732) {                // xt bias scatter
        int i = (b - 1728) * 256 + tid;
        bias_pair[slot_xt(i)] = bf2[i];
    } else if (b < 1764) {                // zero WbigT pad rows
        int i = (b - 1732) * 256 + tid;
        #pragma unroll
        for (int r = 0; r < 4; ++r) {
            int e = i + r * 8192;
            if (e < 32 * 1024) WbigT[(size_t)1056 * 1024 + e] = (__bf16)0.f;
        }
    } else if (b < 1796) {                // Wf2 -> Wf2c row-major bf16
        int id = (b - 1764) * 256 + tid;
        #pragma unroll
        for (int j = 0; j < 4; ++j) {
            int e = id + j * 8192;
            float4 v = ((const float4*)Wf2)[e];
            bf16x4 o2 = {(__bf16)v.x, (__bf16)v.y, (__bf16)v.z, (__bf16)v.w};
            ((bf16x4*)Wf2c)[e] = o2;
        }
    } else {                              // h0 nonzero bitmask
        __shared__ unsigned sm[32];
        if (tid < 32) sm[tid] = 0u;
        __syncthreads();
        unsigned nib = 0;
        #pragma unroll
        for (int j = 0; j < 4; ++j) {
            int d = tid * 4 + j;
            const uint4* hu = (const uint4*)(h0 + d * NDIM);
            uint4 a0 = hu[0], a1 = hu[1], a2 = hu[2], a3 = hu[3];
            unsigned nz = a0.x | a0.y | a0.z | a0.w | a1.x | a1.y | a1.z | a1.w |
                          a2.x | a2.y | a2.z | a2.w | a3.x | a3.y | a3.z | a3.w;
            if (nz) nib |= (1u << j);
        }
        if (nib) atomicOr(&sm[(tid * 4) >> 5], nib << ((tid * 4) & 31));
        __syncthreads();
        if (tid < 32) h0mask[tid] = sm[tid];
    }
}

// ---------------------------------------------------------------------------
// Core BMxBN MFMA GEMM, templated BK (64/128/256) and NBUF (1=single-stage,
// 2=double-buffered). 8-slot XOR swizzle c = pos ^ (row&7) on both sides.
// ACT: 1 relu(+prev), 2 fast-tanh, 4 split128-relu, 7 pair-scatter raw (Gpre)
// ---------------------------------------------------------------------------
template <int BM, int BN, int BK, int NBUF, int ACT, bool ADD_PREV, bool GUARDN, bool AF32>
__device__ __forceinline__ void gemm_core(
    const void* Av, int lda, const __bf16* __restrict__ Bt, int ldb, int Ntot,
    const float* __restrict__ bias, const __bf16* __restrict__ prev, int ldp,
    __bf16* __restrict__ C, int ldc, int K, int bm, int bn,
    __bf16* As, __bf16* Bs) {
    constexpr int WM = BM / 2, WN = BN / 2, FM = WM / 16, FN = WN / 16;
    constexpr int ASZ = BM * BK, BSZ = BN * BK;
    constexpr int CPR = BK / 8;   // 16B chunks per row
    constexpr int NH = BK / 32;   // k-slices of 32 per tile
    const int tid = threadIdx.x;
    const int lane = tid & 63, w = tid >> 6;
    const int wr = w >> 1, wc = w & 1;
    const int g = lane >> 4, lr = lane & 15;
    const __bf16* A16 = (const __bf16*)Av;
    const float* A32 = (const float*)Av;

    auto stage = [&](int buf, int k0) {
        #pragma unroll
        for (int i = 0; i < BM * BK / 2048; ++i) {
            int D = i * 256 + tid;
            int row = D / CPR, pos = D % CPR, c = pos ^ (row & 7);
            if constexpr (AF32) {
                const float* s = &A32[(size_t)(bm + row) * lda + k0 + c * 8];
                float4 v0 = *(const float4*)s;
                float4 v1 = *(const float4*)(s + 4);
                bf16x8 pk = {(__bf16)v0.x, (__bf16)v0.y, (__bf16)v0.z, (__bf16)v0.w,
                             (__bf16)v1.x, (__bf16)v1.y, (__bf16)v1.z, (__bf16)v1.w};
                *(bf16x8*)&As[buf * ASZ + row * BK + pos * 8] = pk;
            } else {
                glds16(&A16[(size_t)(bm + row) * lda + k0 + c * 8],
                       &As[buf * ASZ + (i * 256 + w * 64) * 8]);
            }
        }
        #pragma unroll
        for (int i = 0; i < BN * BK / 2048; ++i) {
            int D = i * 256 + tid;
            int row = D / CPR, pos = D % CPR, c = pos ^ (row & 7);
            glds16(&Bt[(size_t)(bn + row) * ldb + k0 + c * 8],
                   &Bs[buf * BSZ + (i * 256 + w * 64) * 8]);
        }
    };

    f32x4 acc[FM][FN] = {};
    const int x7 = lr & 7;
    int ca[NH];
    #pragma unroll
    for (int h = 0; h < NH; ++h) ca[h] = ((h * 4 + g) ^ x7) * 8;
    const int arow0 = wr * WM + lr;
    const int brow0 = wc * WN + lr;

    const int nt = K / BK;
    stage(0, 0);
    __syncthreads();
    for (int t = 0; t < nt; ++t) {
        if (NBUF == 2 && t + 1 < nt) stage((t + 1) & 1, (t + 1) * BK);
        const __bf16* Ab = &As[(NBUF == 2 ? (t & 1) : 0) * ASZ];
        const __bf16* Bb = &Bs[(NBUF == 2 ? (t & 1) : 0) * BSZ];
        bf16x8 af[FM][NH], bfr[FN][NH];
        #pragma unroll
        for (int m = 0; m < FM; ++m)
            #pragma unroll
            for (int h = 0; h < NH; ++h)
                af[m][h] = *(const bf16x8*)&Ab[(arow0 + m * 16) * BK + ca[h]];
        #pragma unroll
        for (int n = 0; n < FN; ++n)
            #pragma unroll
            for (int h = 0; h < NH; ++h)
                bfr[n][h] = *(const bf16x8*)&Bb[(brow0 + n * 16) * BK + ca[h]];
        #pragma unroll
        for (int h = 0; h < NH; ++h)
            #pragma unroll
            for (int m = 0; m < FM; ++m)
                #pragma unroll
                for (int n = 0; n < FN; ++n)
                    acc[m][n] = __builtin_amdgcn_mfma_f32_16x16x32_bf16(
                        af[m][h], bfr[n][h], acc[m][n], 0, 0, 0);
        __syncthreads();
    }

    // epilogue: C/D layout col=lane&15, row=(lane>>4)*4+reg
    #pragma unroll
    for (int m = 0; m < FM; ++m) {
        #pragma unroll
        for (int n = 0; n < FN; ++n) {
            #pragma unroll
            for (int r = 0; r < 4; ++r) {
                int grow = bm + wr * WM + m * 16 + g * 4 + r;
                int gcol = bn + wc * WN + n * 16 + lr;
                if (!GUARDN || gcol < Ntot) {
                    float v = acc[m][n][r];
                    int orow = grow;
                    if (ACT == 1) {
                        v += bias[gcol];
                        if (ADD_PREV) v += (float)prev[(size_t)grow * ldp + gcol];
                        v = fmaxf(v, 0.f);
                    } else if (ACT == 2) { // fast tanh: 1 - 2/(1+e^2v)
                        v += bias[gcol];
                        float e = __expf(2.f * v);
                        v = 1.f - 2.f * __builtin_amdgcn_rcpf(e + 1.f);
                    } else if (ACT == 4) {
                        if (gcol < HDIM) v = fmaxf(v + bias[gcol], 0.f);
                    } else if (ACT == 7) { // Gpre pair-scatter, raw
                        orow = (grow < 1024) ? slot_de(grow) : 2048 + (grow - 1024);
                    }
                    C[(size_t)orow * ldc + gcol] = (__bf16)v;
                }
            }
        }
    }
}

// thin global wrapper (1-D grid, bijective XCD swizzle when NB%8==0)
template <int BM, int BN, int BK, int NBUF, int ACT, bool ADD_PREV, bool GUARDN>
__global__ __launch_bounds__(256) void mm(const __bf16* __restrict__ A, int lda,
                                          const __bf16* __restrict__ Bt, int ldb, int Ntot,
                                          const float* __restrict__ bias,
                                          const __bf16* __restrict__ prev, int ldp,
                                          __bf16* __restrict__ C, int ldc, int K, int nbx) {
    __shared__ __bf16 As[NBUF * BM * BK];
    __shared__ __bf16 Bs[NBUF * BN * BK];
    const int NB = gridDim.x;
    const int aid = ((NB & 7) == 0)
                        ? (blockIdx.x & 7) * (NB >> 3) + (blockIdx.x >> 3)
                        : blockIdx.x;
    const int bn = (aid % nbx) * BN, bm = (aid / nbx) * BM;
    gemm_core<BM, BN, BK, NBUF, ACT, ADD_PREV, GUARDN, false>(
        A, lda, Bt, ldb, Ntot, bias, prev, ldp, C, ldc, K, bm, bn, As, Bs);
}

// ---------------------------------------------------------------------------
// stage2: [0,512) G1 (x fp32 reg-staged, BK=128); [512,776) bias fold.
// (Gpre moved to stage3 — it only depends on pack, not on G1.)
// ---------------------------------------------------------------------------
__global__ __launch_bounds__(256) void stage2_k(
    const float* __restrict__ x, const __bf16* __restrict__ WaT,
    const __bf16* __restrict__ WbigT,
    const float* __restrict__ bf2, const float* __restrict__ b1,
    const float* __restrict__ b2, const float* __restrict__ b3,
    const float* __restrict__ bl1,
    __bf16* __restrict__ tmp12, float* __restrict__ bias_pair) {
    __shared__ __bf16 As[8192];
    __shared__ __bf16 Bs[16384];
    const int b = blockIdx.x;
    if (b < 512) {
        // G1: tmp12 = [relu(x@Wl1+bl1) | x@Wf1_top]  M=4096 N=256 K=1024
        const int aid = (b & 7) * 64 + (b >> 3);
        const int bn = (aid & 3) * 64, bm = (aid >> 2) * 32;
        gemm_core<32, 64, 128, 2, 4, false, false, true>(
            x, DDIM, WaT, 1024, 256, bl1, nullptr, 0, tmp12, 256, 1024, bm, bn, As, Bs);
    } else {
        // bias fold: fold(n) = ball[n] + sum_d bf2[d]*Wall[d][n] -> pair/BC slots
        const int n = (b - 512) * 4 + (threadIdx.x >> 6);
        const int lane = threadIdx.x & 63;
        const __bf16* wr = WbigT + (size_t)n * 1024 + lane * 16;
        float s = 0.f;
        #pragma unroll
        for (int i = 0; i < 2; ++i) {
            bf16x8 wv = *(const bf16x8*)&wr[i * 8];
            float4 f0 = *(const float4*)&bf2[lane * 16 + i * 8];
            float4 f1 = *(const float4*)&bf2[lane * 16 + i * 8 + 4];
            s += (float)wv[0] * f0.x + (float)wv[1] * f0.y + (float)wv[2] * f0.z +
                 (float)wv[3] * f0.w + (float)wv[4] * f1.x + (float)wv[5] * f1.y +
                 (float)wv[6] * f1.z + (float)wv[7] * f1.w;
        }
        #pragma unroll
        for (int off = 32; off; off >>= 1) s += __shfl_down(s, off);
        if (lane == 0) {
            float base = (n < DDIM) ? b1[n]
                       : (n < DDIM + NDIM) ? b2[n - DDIM] : b3[n - DDIM - NDIM];
            int sl = (n < DDIM) ? slot_de(n) : 2048 + (n - DDIM);
            bias_pair[sl] = base + s;
        }
    }
}

// ---------------------------------------------------------------------------
// stage3: [0,68) Gpre (32x64, BK=128, dbuf) -> WpairT; [68,1092) G2
// (64x64, BK=128, single-stage, fast-tanh). Gpre runs concurrent with G2.
// Shared: As 8192 (16 KB), Bs 16384 (32 KB) -> 48 KB, 3 blocks/CU.
// ---------------------------------------------------------------------------
__global__ __launch_bounds__(256) void stage3_k(
    const __bf16* __restrict__ tmp12, const __bf16* __restrict__ Wl2T,
    const __bf16* __restrict__ WbigT, const __bf16* __restrict__ Wf2c,
    const float* __restrict__ bl2,
    __bf16* __restrict__ lifted, __bf16* __restrict__ WpairT) {
    __shared__ __bf16 As[8192];
    __shared__ __bf16 Bs[16384];
    const int b = blockIdx.x;
    if (b < 68) {
        // Gpre: Wcomb cols scattered into WpairT delta/BC slots  M=1088 N=128 K=1024
        const int bm = (b >> 1) * 32, bn = (b & 1) * 64;
        gemm_core<32, 64, 128, 2, 7, false, false, false>(
            WbigT, 1024, Wf2c, 1024, 128, nullptr, nullptr, 0,
            WpairT, 128, 1024, bm, bn, As, Bs);
    } else {
        // G2: lifted = tanh(tmp12[:,:128] @ Wl2 + bl2)  M=4096 N=1024 K=128
        const int local = b - 68; // 1024 blocks, %8==0 -> bijective swizzle
        const int aid = (local & 7) * 128 + (local >> 3);
        const int bn = (aid & 15) * 64, bm = (aid >> 4) * 64;
        gemm_core<64, 64, 128, 1, 2, false, false, false>(
            tmp12, 256, Wl2T, 128, 1024, bl2, nullptr, 0, lifted, DDIM, 128, bm, bn, As, Bs);
    }
}

// ---------------------------------------------------------------------------
// mm_pairs: [xt|de] pair GEMM + in-kernel BC (Bm/Cm/cb) + final epilogue.
// M=4096 N=2048 K=128. BM=128 BN=64, 1024 blocks, LDS 48 KB. (unchanged)
// ---------------------------------------------------------------------------
__global__ __launch_bounds__(256) void mm_pairs(
    const __bf16* __restrict__ tmp2, const __bf16* __restrict__ WpairT,
    const float* __restrict__ bias_pair,
    const float* __restrict__ Amat, const float* __restrict__ h0,
    const unsigned* __restrict__ h0mask,
    float* __restrict__ out, float* __restrict__ last_h) {
    constexpr int ASZ = 128 * 64, BSZ = 64 * 64;
    __shared__ __bf16 As[2 * ASZ];
    __shared__ __bf16 Bs[2 * BSZ];
    const int NB = gridDim.x; // 1024
    const int aid = (blockIdx.x & 7) * (NB >> 3) + (blockIdx.x >> 3);
    const int bn = (aid & 31) * 64, bm = (aid >> 5) * 128;
    const int tid = threadIdx.x;
    const int lane = tid & 63, w = tid >> 6;
    const int wr = w >> 1, wc = w & 1;
    const int g = lane >> 4, lr = lane & 15;

    auto stage = [&](int buf, int k0) {
        #pragma unroll
        for (int i = 0; i < 4; ++i) {
            int D = i * 256 + tid;
            int row = D >> 3, pos = D & 7, c = pos ^ (row & 7);
            glds16(&tmp2[(size_t)(bm + row) * 128 + k0 + c * 8],
                   &As[buf * ASZ + (i * 256 + w * 64) * 8]);
        }
        #pragma unroll
        for (int i = 0; i < 2; ++i) {
            int D = i * 256 + tid;
            int row = D >> 3, pos = D & 7, c = pos ^ (row & 7);
            glds16(&WpairT[(size_t)(bn + row) * 128 + k0 + c * 8],
                   &Bs[buf * BSZ + (i * 256 + w * 64) * 8]);
        }
    };

    f32x4 acc[4][2] = {};
    const int x7 = lr & 7;
    const int ca[2] = {(g ^ x7) * 8, ((4 + g) ^ x7) * 8};
    const int arow0 = wr * 64 + lr, brow0 = wc * 32 + lr;
    stage(0, 0);
    __syncthreads();
    #pragma unroll
    for (int t = 0; t < 2; ++t) {
        if (t == 0) stage(1, 64);
        const __bf16* Ab = &As[t * ASZ];
        const __bf16* Bb = &Bs[t * BSZ];
        bf16x8 af[4][2], bfr[2][2];
        #pragma unroll
        for (int m = 0; m < 4; ++m)
            #pragma unroll
            for (int h = 0; h < 2; ++h)
                af[m][h] = *(const bf16x8*)&Ab[(arow0 + m * 16) * 64 + ca[h]];
        #pragma unroll
        for (int n = 0; n < 2; ++n)
            #pragma unroll
            for (int h = 0; h < 2; ++h)
                bfr[n][h] = *(const bf16x8*)&Bb[(brow0 + n * 16) * 64 + ca[h]];
        #pragma unroll
        for (int h = 0; h < 2; ++h)
            #pragma unroll
            for (int m = 0; m < 4; ++m)
                #pragma unroll
                for (int n = 0; n < 2; ++n)
                    acc[m][n] = __builtin_amdgcn_mfma_f32_16x16x32_bf16(
                        af[m][h], bfr[n][h], acc[m][n], 0, 0, 0);
        __syncthreads();
    }

    // --- in-kernel BC: stage Bbc (WpairT rows 2048..2079) into Bs buf0 ---
    {
        int row = tid >> 3, pos = tid & 7, c = pos ^ (row & 7);
        #pragma unroll
        for (int t2 = 0; t2 < 2; ++t2)
            glds16(&WpairT[(size_t)(2048 + row) * 128 + t2 * 64 + c * 8],
                   &Bs[t2 * 2048 + w * 512]);
    }
    __syncthreads();
    f32x4 accB[2] = {}, accC[2] = {};
    #pragma unroll
    for (int t2 = 0; t2 < 2; ++t2) {
        const __bf16* Ab = &As[t2 * ASZ];
        #pragma unroll
        for (int h = 0; h < 2; ++h) {
            bf16x8 bB = *(const bf16x8*)&Bs[t2 * 2048 + lr * 64 + ca[h]];
            bf16x8 bC = *(const bf16x8*)&Bs[t2 * 2048 + (16 + lr) * 64 + ca[h]];
            #pragma unroll
            for (int m2 = 0; m2 < 2; ++m2) {
                bf16x8 a2 = *(const bf16x8*)&Ab[(w * 32 + m2 * 16 + lr) * 64 + ca[h]];
                accB[m2] = __builtin_amdgcn_mfma_f32_16x16x32_bf16(a2, bB, accB[m2], 0, 0, 0);
                accC[m2] = __builtin_amdgcn_mfma_f32_16x16x32_bf16(a2, bC, accC[m2], 0, 0, 0);
            }
        }
    }
    __syncthreads();
    float* sCB = (float*)As;
    __bf16* sBC = &Bs[BSZ];
    const float bB_ = bias_pair[2048 + lr], bC_ = bias_pair[2064 + lr];
    #pragma unroll
    for (int m2 = 0; m2 < 2; ++m2) {
        #pragma unroll
        for (int r = 0; r < 4; ++r) {
            int lrow = w * 32 + m2 * 16 + g * 4 + r;
            float vB = accB[m2][r] + bB_;
            float vC = accC[m2][r] + bC_;
            sBC[lrow * 32 + lr] = (__bf16)vB;
            sBC[lrow * 32 + 16 + lr] = (__bf16)vC;
            float p = vB * vC;
            #pragma unroll
            for (int m3 = 1; m3 < 16; m3 <<= 1) p += __shfl_xor(p, m3);
            if (lr == 0) sCB[lrow] = p;
        }
    }
    __syncthreads();

    const int d = ((bn + wc * 32) >> 1) + lr;
    const float bx_ = bias_pair[bn + wc * 32 + lr];
    const float bd_ = bias_pair[bn + wc * 32 + 16 + lr];
    const bool msk = (h0mask[d >> 5] >> (d & 31)) & 1u;
    #pragma unroll
    for (int m = 0; m < 4; ++m) {
        #pragma unroll
        for (int r = 0; r < 4; ++r) {
            const int lrow = wr * 64 + m * 16 + g * 4 + r;
            const int row = bm + lrow;
            const float xt = acc[m][0][r] + bx_;
            const float dr = acc[m][1][r] + bd_;
            const float e = __expf(-fabsf(dr));
            const float de = fmaxf(dr, 0.f) + __logf(1.f + e);
            const float xd = xt * de;
            float res = xd * sCB[lrow];
            const bool is_last = (row & (LSEQ - 1)) == (LSEQ - 1);
            if (msk) {
                float s = 0.f;
                #pragma unroll
                for (int n = 0; n < NDIM; ++n) {
                    float z = de * Amat[d * NDIM + n];
                    float c2 = (z > 0.f) ? z : __expf(z) - 1.f;
                    float da = __expf(-c2);
                    float h0v = h0[d * NDIM + n];
                    s += (float)sBC[lrow * 32 + 16 + n] * da * h0v;
                    if (is_last)
                        last_h[(((size_t)(row >> 11)) * DDIM + d) * NDIM + n] =
                            da * h0v + xd * (float)sBC[lrow * 32 + n];
                }
                res += s;
            } else if (is_last) {
                #pragma unroll
                for (int n = 0; n < NDIM; ++n)
                    last_h[(((size_t)(row >> 11)) * DDIM + d) * NDIM + n] =
                        xd * (float)sBC[lrow * 32 + n];
            }
            out[(size_t)row * DDIM + d] = res;
        }
    }
}

extern "C" void kernel_launch(void* const* d_in, const int* in_sizes, int n_in,
                              void* d_out, int out_size, void* d_ws, size_t ws_size,
                              hipStream_t stream) {
    const float* x   = (const float*)d_in[0];
    const float* W1  = (const float*)d_in[1];
    const float* b1  = (const float*)d_in[2];
    const float* W2  = (const float*)d_in[3];
    const float* b2  = (const float*)d_in[4];
    const float* W3  = (const float*)d_in[5];
    const float* b3  = (const float*)d_in[6];
    const float* Wl1 = (const float*)d_in[7];
    const float* bl1 = (const float*)d_in[8];
    const float* Wl2 = (const float*)d_in[9];
    const float* bl2 = (const float*)d_in[10];
    const float* Wf1 = (const float*)d_in[11];
    const float* bf1 = (const float*)d_in[12];
    const float* Wf2 = (const float*)d_in[13];
    const float* bf2 = (const float*)d_in[14];
    const float* h0  = (const float*)d_in[15];
    const float* Amat= (const float*)d_in[16];

    float* out    = (float*)d_out;
    float* last_h = (float*)d_out + (size_t)MROWS * DDIM;

    __bf16* wsb = (__bf16*)d_ws;
    size_t o = 0;
    auto alloc = [&](size_t n) { __bf16* p = wsb + o; o += n; return p; };
    __bf16* WaT    = alloc(256 * 1024);             // [Wl1 | Wf1_top]^T
    __bf16* Wf1bT  = alloc(128 * 1024);
    __bf16* Wl2T   = alloc(1024 * 128);
    __bf16* WbigT  = alloc((size_t)NPAD * 1024);    // [W1 | W2 | W3 | pad]^T
    __bf16* WpairT = alloc(2112 * 128);             // pairs 0..2047, BC 2048..2079
    __bf16* Wf2c   = alloc(128 * 1024);             // Wf2 bf16 row-major
    __bf16* tmp12  = alloc((size_t)MROWS * 256);    // [relu(x@Wl1+bl1) | x@Wf1_top]
    __bf16* lifted = alloc((size_t)MROWS * DDIM);
    __bf16* tmp2   = alloc((size_t)MROWS * HDIM);
    float*  bias_pair = (float*)(wsb + o); o += 2 * 2112;
    unsigned* h0mask = (unsigned*)(wsb + o);

    // 1. pack (flat 1797 blocks)
    pack_all<<<dim3(1797), 256, 0, stream>>>(W1, W2, W3, Wl1, Wl2, Wf1, Wf2,
                                             bf2, h0,
                                             WbigT, WaT, Wf1bT, Wl2T, WpairT,
                                             Wf2c, bias_pair, h0mask);
    // 2. stage2: G1 (512, BK=128) + bias fold (264)
    stage2_k<<<dim3(776), 256, 0, stream>>>(x, WaT, WbigT, bf2, b1, b2, b3,
                                            bl1, tmp12, bias_pair);
    // 3. stage3: Gpre (68, BK=128) || G2 (1024, BK=128 single-stage)
    stage3_k<<<dim3(1092), 256, 0, stream>>>(tmp12, Wl2T, WbigT, Wf2c, bl2,
                                             lifted, WpairT);
    // 4. G3: tmp2 = relu(lifted@Wf1_bot + bf1 + tmp12[:,128:]) M=4096 N=128 K=1024
    //    BK=256 (nt=4), 512 blk, LDS 64 KB
    mm<32, 32, 256, 2, 1, true, false><<<dim3(4 * 128), 256, 0, stream>>>(
        lifted, DDIM, Wf1bT, 1024, 128, bf1, tmp12 + 128, 256, tmp2, HDIM, 1024, 4);
    // 5. mm_pairs: fused [x_tr|delta] GEMM + BC + final epilogue -> out, last_h
    mm_pairs<<<dim3(32 * 32), 256, 0, stream>>>(tmp2, WpairT, bias_pair,
                                                Amat, h0, h0mask, out, last_h);
}

// Round 15
// 51.280 us; speedup vs baseline: 3.4507x; 1.0382x over previous
//
#include <hip/hip_runtime.h>
#include <cmath>

#define B_SZ 2
#define LSEQ 2048
#define DDIM 1024
#define NDIM 16
#define HDIM 128
#define MROWS (B_SZ * LSEQ)    // 4096
#define NBIG (DDIM + 2 * NDIM) // 1056
#define NPAD 1088              // NBIG padded to 64

typedef __bf16 bf16x8 __attribute__((ext_vector_type(8)));
typedef __bf16 bf16x4 __attribute__((ext_vector_type(4)));
typedef float f32x4 __attribute__((ext_vector_type(4)));

// async global->LDS, 16B/lane; LDS dest = wave-uniform base + lane*16
__device__ __forceinline__ void glds16(const __bf16* g, __bf16* l) {
    __builtin_amdgcn_global_load_lds(
        (const __attribute__((address_space(1))) unsigned int*)g,
        (__attribute__((address_space(3))) unsigned int*)l, 16, 0, 0);
}

// pair-layout row slots
__device__ __forceinline__ int slot_xt(int d) { return (d >> 4) * 32 + (d & 15); }
__device__ __forceinline__ int slot_de(int d) { return (d >> 4) * 32 + 16 + (d & 15); }

// ---------------------------------------------------------------------------
// Preprocessing (flat 1-D grid, 1797 blocks).
// ---------------------------------------------------------------------------
__device__ __forceinline__ void tcast_tile(const float* __restrict__ in,
                                           __bf16* __restrict__ out, int K, int N,
                                           int bx, int by, float (*t)[33]) {
    int tx = threadIdx.x & 31, ty = threadIdx.x >> 5;
    int n0 = bx * 32, k0 = by * 32;
    #pragma unroll
    for (int i = 0; i < 4; ++i) {
        int k = k0 + ty + i * 8, n = n0 + tx;
        t[ty + i * 8][tx] = (k < K && n < N) ? in[(size_t)k * N + n] : 0.f;
    }
    __syncthreads();
    #pragma unroll
    for (int i = 0; i < 4; ++i) {
        int n = n0 + ty + i * 8, k = k0 + tx;
        if (n < N && k < K) out[(size_t)n * K + k] = (__bf16)t[tx][ty + i * 8];
    }
}

// Wf2 [128][1024] -> WpairT xt slots (row slot_xt(n), ld 128)
__device__ __forceinline__ void tcast_pair_tile(const float* __restrict__ in,
                                                __bf16* __restrict__ out,
                                                int bx, int by, float (*t)[33]) {
    int tx = threadIdx.x & 31, ty = threadIdx.x >> 5;
    int n0 = bx * 32, k0 = by * 32;
    #pragma unroll
    for (int i = 0; i < 4; ++i) {
        int k = k0 + ty + i * 8, n = n0 + tx;
        t[ty + i * 8][tx] = in[(size_t)k * 1024 + n];
    }
    __syncthreads();
    #pragma unroll
    for (int i = 0; i < 4; ++i) {
        int n = n0 + ty + i * 8, k = k0 + tx;
        out[(size_t)slot_xt(n) * 128 + k] = (__bf16)t[tx][ty + i * 8];
    }
}

__global__ __launch_bounds__(256) void pack_all(
    const float* W1, const float* W2, const float* W3, const float* Wl1,
    const float* Wl2, const float* Wf1, const float* Wf2,
    const float* bf2, const float* h0,
    __bf16* WbigT, __bf16* WaT, __bf16* Wf1bT, __bf16* Wl2T, __bf16* WpairT,
    __bf16* Wf2c, float* bias_pair, unsigned* h0mask) {
    __shared__ float t[32][33];
    const int b = blockIdx.x;
    const int tid = threadIdx.x;
    if (b < 1024) {                       // W1 -> WbigT
        tcast_tile(W1, WbigT, 1024, 1024, b & 31, b >> 5, t);
    } else if (b < 1152) {                // Wl1 -> WaT
        int i = b - 1024; tcast_tile(Wl1, WaT, 1024, 128, i & 3, i >> 2, t);
    } else if (b < 1280) {                // Wf1 top -> WaT[128k..]
        int i = b - 1152; tcast_tile(Wf1, WaT + 128 * 1024, 1024, 128, i & 3, i >> 2, t);
    } else if (b < 1408) {                // Wf1 bottom -> Wf1bT
        int i = b - 1280;
        tcast_tile(Wf1 + (size_t)1024 * 128, Wf1bT, 1024, 128, i & 3, i >> 2, t);
    } else if (b < 1536) {                // Wl2 -> Wl2T
        int i = b - 1408; tcast_tile(Wl2, Wl2T, 128, 1024, i & 31, i >> 5, t);
    } else if (b < 1664) {                // Wf2 -> WpairT xt slots
        int i = b - 1536; tcast_pair_tile(Wf2, WpairT, i & 31, i >> 5, t);
    } else if (b < 1696) {                // W2 -> WbigT[1024..]
        int i = b - 1664; tcast_tile(W2, WbigT + (size_t)1024 * 1024, 1024, 16, 0, i, t);
    } else if (b < 1728) {                // W3 -> WbigT[1040..]
        int i = b - 1696; tcast_tile(W3, WbigT + (size_t)1040 * 1024, 1024, 16, 0, i, t);
    } else if (b < 1732) {                // xt bias scatter
        int i = (b - 1728) * 256 + tid;
        bias_pair[slot_xt(i)] = bf2[i];
    } else if (b < 1764) {                // zero WbigT pad rows
        int i = (b - 1732) * 256 + tid;
        #pragma unroll
        for (int r = 0; r < 4; ++r) {
            int e = i + r * 8192;
            if (e < 32 * 1024) WbigT[(size_t)1056 * 1024 + e] = (__bf16)0.f;
        }
    } else if (b < 1796) {                // Wf2 -> Wf2c row-major bf16
        int id = (b - 1764) * 256 + tid;
        #pragma unroll
        for (int j = 0; j < 4; ++j) {
            int e = id + j * 8192;
            float4 v = ((const float4*)Wf2)[e];
            bf16x4 o2 = {(__bf16)v.x, (__bf16)v.y, (__bf16)v.z, (__bf16)v.w};
            ((bf16x4*)Wf2c)[e] = o2;
        }
    } else {                              // h0 nonzero bitmask
        __shared__ unsigned sm[32];
        if (tid < 32) sm[tid] = 0u;
        __syncthreads();
        unsigned nib = 0;
        #pragma unroll
        for (int j = 0; j < 4; ++j) {
            int d = tid * 4 + j;
            const uint4* hu = (const uint4*)(h0 + d * NDIM);
            uint4 a0 = hu[0], a1 = hu[1], a2 = hu[2], a3 = hu[3];
            unsigned nz = a0.x | a0.y | a0.z | a0.w | a1.x | a1.y | a1.z | a1.w |
                          a2.x | a2.y | a2.z | a2.w | a3.x | a3.y | a3.z | a3.w;
            if (nz) nib |= (1u << j);
        }
        if (nib) atomicOr(&sm[(tid * 4) >> 5], nib << ((tid * 4) & 31));
        __syncthreads();
        if (tid < 32) h0mask[tid] = sm[tid];
    }
}

// ---------------------------------------------------------------------------
// Core BMxBN MFMA GEMM, templated BK/NBUF. XOR swizzle both sides.
// ACT: 1 relu(+prev), 2 fast-tanh, 4 split128-relu, 7 pair-scatter raw (Gpre)
// ---------------------------------------------------------------------------
template <int BM, int BN, int BK, int NBUF, int ACT, bool ADD_PREV, bool GUARDN, bool AF32>
__device__ __forceinline__ void gemm_core(
    const void* Av, int lda, const __bf16* __restrict__ Bt, int ldb, int Ntot,
    const float* __restrict__ bias, const __bf16* __restrict__ prev, int ldp,
    __bf16* __restrict__ C, int ldc, int K, int bm, int bn,
    __bf16* As, __bf16* Bs) {
    constexpr int WM = BM / 2, WN = BN / 2, FM = WM / 16, FN = WN / 16;
    constexpr int ASZ = BM * BK, BSZ = BN * BK;
    constexpr int CPR = BK / 8;
    constexpr int NH = BK / 32;
    const int tid = threadIdx.x;
    const int lane = tid & 63, w = tid >> 6;
    const int wr = w >> 1, wc = w & 1;
    const int g = lane >> 4, lr = lane & 15;
    const __bf16* A16 = (const __bf16*)Av;
    const float* A32 = (const float*)Av;

    auto stage = [&](int buf, int k0) {
        #pragma unroll
        for (int i = 0; i < BM * BK / 2048; ++i) {
            int D = i * 256 + tid;
            int row = D / CPR, pos = D % CPR, c = pos ^ (row & 7);
            if constexpr (AF32) {
                const float* s = &A32[(size_t)(bm + row) * lda + k0 + c * 8];
                float4 v0 = *(const float4*)s;
                float4 v1 = *(const float4*)(s + 4);
                bf16x8 pk = {(__bf16)v0.x, (__bf16)v0.y, (__bf16)v0.z, (__bf16)v0.w,
                             (__bf16)v1.x, (__bf16)v1.y, (__bf16)v1.z, (__bf16)v1.w};
                *(bf16x8*)&As[buf * ASZ + row * BK + pos * 8] = pk;
            } else {
                glds16(&A16[(size_t)(bm + row) * lda + k0 + c * 8],
                       &As[buf * ASZ + (i * 256 + w * 64) * 8]);
            }
        }
        #pragma unroll
        for (int i = 0; i < BN * BK / 2048; ++i) {
            int D = i * 256 + tid;
            int row = D / CPR, pos = D % CPR, c = pos ^ (row & 7);
            glds16(&Bt[(size_t)(bn + row) * ldb + k0 + c * 8],
                   &Bs[buf * BSZ + (i * 256 + w * 64) * 8]);
        }
    };

    f32x4 acc[FM][FN] = {};
    const int x7 = lr & 7;
    int ca[NH];
    #pragma unroll
    for (int h = 0; h < NH; ++h) ca[h] = ((h * 4 + g) ^ x7) * 8;
    const int arow0 = wr * WM + lr;
    const int brow0 = wc * WN + lr;

    const int nt = K / BK;
    stage(0, 0);
    __syncthreads();
    for (int t = 0; t < nt; ++t) {
        if (NBUF == 2 && t + 1 < nt) stage((t + 1) & 1, (t + 1) * BK);
        const __bf16* Ab = &As[(NBUF == 2 ? (t & 1) : 0) * ASZ];
        const __bf16* Bb = &Bs[(NBUF == 2 ? (t & 1) : 0) * BSZ];
        bf16x8 af[FM][NH], bfr[FN][NH];
        #pragma unroll
        for (int m = 0; m < FM; ++m)
            #pragma unroll
            for (int h = 0; h < NH; ++h)
                af[m][h] = *(const bf16x8*)&Ab[(arow0 + m * 16) * BK + ca[h]];
        #pragma unroll
        for (int n = 0; n < FN; ++n)
            #pragma unroll
            for (int h = 0; h < NH; ++h)
                bfr[n][h] = *(const bf16x8*)&Bb[(brow0 + n * 16) * BK + ca[h]];
        #pragma unroll
        for (int h = 0; h < NH; ++h)
            #pragma unroll
            for (int m = 0; m < FM; ++m)
                #pragma unroll
                for (int n = 0; n < FN; ++n)
                    acc[m][n] = __builtin_amdgcn_mfma_f32_16x16x32_bf16(
                        af[m][h], bfr[n][h], acc[m][n], 0, 0, 0);
        __syncthreads();
    }

    #pragma unroll
    for (int m = 0; m < FM; ++m) {
        #pragma unroll
        for (int n = 0; n < FN; ++n) {
            #pragma unroll
            for (int r = 0; r < 4; ++r) {
                int grow = bm + wr * WM + m * 16 + g * 4 + r;
                int gcol = bn + wc * WN + n * 16 + lr;
                if (!GUARDN || gcol < Ntot) {
                    float v = acc[m][n][r];
                    int orow = grow;
                    if (ACT == 1) {
                        v += bias[gcol];
                        if (ADD_PREV) v += (float)prev[(size_t)grow * ldp + gcol];
                        v = fmaxf(v, 0.f);
                    } else if (ACT == 2) {
                        v += bias[gcol];
                        float e = __expf(2.f * v);
                        v = 1.f - 2.f * __builtin_amdgcn_rcpf(e + 1.f);
                    } else if (ACT == 4) {
                        if (gcol < HDIM) v = fmaxf(v + bias[gcol], 0.f);
                    } else if (ACT == 7) { // Gpre pair-scatter, raw
                        orow = (grow < 1024) ? slot_de(grow) : 2048 + (grow - 1024);
                    }
                    C[(size_t)orow * ldc + gcol] = (__bf16)v;
                }
            }
        }
    }
}

// ---------------------------------------------------------------------------
// stage2: [0,512) G1 (x fp32 reg-staged, BK=128); [512,580) Gpre (BK=128);
// [580,844) bias fold -> bias_pair. All depend only on pack_all.
// ---------------------------------------------------------------------------
__global__ __launch_bounds__(256) void stage2_k(
    const float* __restrict__ x, const __bf16* __restrict__ WaT,
    const __bf16* __restrict__ WbigT, const __bf16* __restrict__ Wf2c,
    const float* __restrict__ bf2, const float* __restrict__ b1,
    const float* __restrict__ b2, const float* __restrict__ b3,
    const float* __restrict__ bl1,
    __bf16* __restrict__ tmp12, __bf16* __restrict__ WpairT,
    float* __restrict__ bias_pair) {
    __shared__ __bf16 As[8192];
    __shared__ __bf16 Bs[16384];
    const int b = blockIdx.x;
    if (b < 512) {
        // G1: tmp12 = [relu(x@Wl1+bl1) | x@Wf1_top]  M=4096 N=256 K=1024
        const int aid = (b & 7) * 64 + (b >> 3);
        const int bn = (aid & 3) * 64, bm = (aid >> 2) * 32;
        gemm_core<32, 64, 128, 2, 4, false, false, true>(
            x, DDIM, WaT, 1024, 256, bl1, nullptr, 0, tmp12, 256, 1024, bm, bn, As, Bs);
    } else if (b < 580) {
        // Gpre: Wcomb cols scattered into WpairT delta/BC slots  M=1088 N=128 K=1024
        const int aid = b - 512;
        const int bm = (aid >> 1) * 32, bn = (aid & 1) * 64;
        gemm_core<32, 64, 128, 2, 7, false, false, false>(
            WbigT, 1024, Wf2c, 1024, 128, nullptr, nullptr, 0,
            WpairT, 128, 1024, bm, bn, As, Bs);
    } else {
        // bias fold: fold(n) = ball[n] + sum_d bf2[d]*Wall[d][n] -> pair/BC slots
        const int n = (b - 580) * 4 + (threadIdx.x >> 6);
        const int lane = threadIdx.x & 63;
        const __bf16* wr = WbigT + (size_t)n * 1024 + lane * 16;
        float s = 0.f;
        #pragma unroll
        for (int i = 0; i < 2; ++i) {
            bf16x8 wv = *(const bf16x8*)&wr[i * 8];
            float4 f0 = *(const float4*)&bf2[lane * 16 + i * 8];
            float4 f1 = *(const float4*)&bf2[lane * 16 + i * 8 + 4];
            s += (float)wv[0] * f0.x + (float)wv[1] * f0.y + (float)wv[2] * f0.z +
                 (float)wv[3] * f0.w + (float)wv[4] * f1.x + (float)wv[5] * f1.y +
                 (float)wv[6] * f1.z + (float)wv[7] * f1.w;
        }
        #pragma unroll
        for (int off = 32; off; off >>= 1) s += __shfl_down(s, off);
        if (lane == 0) {
            float base = (n < DDIM) ? b1[n]
                       : (n < DDIM + NDIM) ? b2[n - DDIM] : b3[n - DDIM - NDIM];
            int sl = (n < DDIM) ? slot_de(n) : 2048 + (n - DDIM);
            bias_pair[sl] = base + s;
        }
    }
}

// ---------------------------------------------------------------------------
// g23_k: fused G2+G3. Per block: 16 tmp2 rows; loop kc over 1024 in 128s:
//   lifted_c = tanh(t1 @ Wl2[:,kc:kc+128])   (per wave: 16x16 slice, 4 MFMA)
//   -> LDS (XOR-swizzled) ->
//   acc2 += lifted_c @ Wf1b[kc:kc+128, :]    (4 MFMA)
// Epilogue: relu(acc2 + bf1 + tmp12[:,128:]) -> tmp2. `lifted` never hits HBM.
// 256 blocks x 512 thr (8 waves, col-slice 16 each). LDS 139 KB, 1 blk/CU.
// ---------------------------------------------------------------------------
__global__ __launch_bounds__(512) void g23_k(
    const __bf16* __restrict__ tmp12, const __bf16* __restrict__ Wl2T,
    const __bf16* __restrict__ Wf1bT, const float* __restrict__ bl2,
    const float* __restrict__ bf1, __bf16* __restrict__ tmp2) {
    __shared__ __bf16 T1[2048];       // t1 16x128 (swizzled chunks)
    __shared__ __bf16 LS[2048];       // lifted chunk 16x128 (swizzled)
    __shared__ __bf16 B1[2][16384];   // Wl2T rows [kc..kc+128) x 128
    __shared__ __bf16 B2[2][16384];   // Wf1bT rows [0,128) x cols [kc..kc+128)
    const int tid = threadIdx.x;
    const int lane = tid & 63, w = tid >> 6;   // 8 waves
    const int g = lane >> 4, lr = lane & 15;
    const int x7 = lr & 7;
    const int bm = blockIdx.x * 16;            // 256 blocks

    // stage t1 (once): 256 chunks, threads 0..255
    if (tid < 256) {
        int row = tid >> 4, pos = tid & 15, c = pos ^ (row & 7);
        glds16(&tmp12[(size_t)(bm + row) * 256 + c * 8], &T1[w * 512]);
    }
    auto stageB = [&](int buf, int kc) {
        #pragma unroll
        for (int i = 0; i < 4; ++i) {
            int D = i * 512 + tid;
            int row = D >> 4, pos = D & 15, c = pos ^ (row & 7);
            glds16(&Wl2T[(size_t)(kc + row) * 128 + c * 8],
                   &B1[buf][(i * 512 + w * 64) * 8]);
            glds16(&Wf1bT[(size_t)row * 1024 + kc + c * 8],
                   &B2[buf][(i * 512 + w * 64) * 8]);
        }
    };

    int ca[4];
    #pragma unroll
    for (int h = 0; h < 4; ++h) ca[h] = ((h * 4 + g) ^ x7) * 8;
    const int col = w * 16 + lr;      // this thread's output column (0..127)
    const int brow = col * 128;       // B-fragment row base (col&7 == lr&7)

    stageB(0, 0);
    __syncthreads();
    bf16x8 a1[4];
    #pragma unroll
    for (int h = 0; h < 4; ++h) a1[h] = *(const bf16x8*)&T1[lr * 128 + ca[h]];

    f32x4 acc2 = {};
    for (int t = 0; t < 8; ++t) {
        if (t + 1 < 8) stageB((t + 1) & 1, (t + 1) * 128);
        const __bf16* b1b = B1[t & 1];
        const __bf16* b2b = B2[t & 1];
        // phase1: lifted_c[:, col] (16 rows)
        f32x4 acc1 = {};
        #pragma unroll
        for (int h = 0; h < 4; ++h) {
            bf16x8 bf = *(const bf16x8*)&b1b[brow + ca[h]];
            acc1 = __builtin_amdgcn_mfma_f32_16x16x32_bf16(a1[h], bf, acc1, 0, 0, 0);
        }
        const float bl = bl2[t * 128 + col];
        const int chunk = col >> 3, cin = col & 7;
        #pragma unroll
        for (int r = 0; r < 4; ++r) {
            float v = acc1[r] + bl;
            float e = __expf(2.f * v);
            v = 1.f - 2.f * __builtin_amdgcn_rcpf(e + 1.f);  // tanh
            int row = g * 4 + r;
            LS[row * 128 + ((chunk ^ (row & 7)) << 3) + cin] = (__bf16)v;
        }
        __syncthreads();  // LS visible; all reads of B[t&1] done
        // phase2: acc2 += lifted_c @ Wf1b-chunk (A rows = lr)
        #pragma unroll
        for (int h = 0; h < 4; ++h) {
            bf16x8 a2 = *(const bf16x8*)&LS[lr * 128 + ca[h]];
            bf16x8 bf = *(const bf16x8*)&b2b[brow + ca[h]];
            acc2 = __builtin_amdgcn_mfma_f32_16x16x32_bf16(a2, bf, acc2, 0, 0, 0);
        }
        __syncthreads();  // LS + B[t&1] free for reuse
    }

    // epilogue: relu(acc2 + bf1 + t1b) -> tmp2
    const float bfv = bf1[col];
    #pragma unroll
    for (int r = 0; r < 4; ++r) {
        const int row = g * 4 + r;
        float v = acc2[r] + bfv + (float)tmp12[(size_t)(bm + row) * 256 + 128 + col];
        v = fmaxf(v, 0.f);
        tmp2[(size_t)(bm + row) * 128 + col] = (__bf16)v;
    }
}

// ---------------------------------------------------------------------------
// mm_pairs: [xt|de] pair GEMM + in-kernel BC (Bm/Cm/cb) + final epilogue.
// M=4096 N=2048 K=128. BM=128 BN=64, 1024 blocks, LDS 48 KB. (unchanged)
// ---------------------------------------------------------------------------
__global__ __launch_bounds__(256) void mm_pairs(
    const __bf16* __restrict__ tmp2, const __bf16* __restrict__ WpairT,
    const float* __restrict__ bias_pair,
    const float* __restrict__ Amat, const float* __restrict__ h0,
    const unsigned* __restrict__ h0mask,
    float* __restrict__ out, float* __restrict__ last_h) {
    constexpr int ASZ = 128 * 64, BSZ = 64 * 64;
    __shared__ __bf16 As[2 * ASZ];
    __shared__ __bf16 Bs[2 * BSZ];
    const int NB = gridDim.x; // 1024
    const int aid = (blockIdx.x & 7) * (NB >> 3) + (blockIdx.x >> 3);
    const int bn = (aid & 31) * 64, bm = (aid >> 5) * 128;
    const int tid = threadIdx.x;
    const int lane = tid & 63, w = tid >> 6;
    const int wr = w >> 1, wc = w & 1;
    const int g = lane >> 4, lr = lane & 15;

    auto stage = [&](int buf, int k0) {
        #pragma unroll
        for (int i = 0; i < 4; ++i) {
            int D = i * 256 + tid;
            int row = D >> 3, pos = D & 7, c = pos ^ (row & 7);
            glds16(&tmp2[(size_t)(bm + row) * 128 + k0 + c * 8],
                   &As[buf * ASZ + (i * 256 + w * 64) * 8]);
        }
        #pragma unroll
        for (int i = 0; i < 2; ++i) {
            int D = i * 256 + tid;
            int row = D >> 3, pos = D & 7, c = pos ^ (row & 7);
            glds16(&WpairT[(size_t)(bn + row) * 128 + k0 + c * 8],
                   &Bs[buf * BSZ + (i * 256 + w * 64) * 8]);
        }
    };

    f32x4 acc[4][2] = {};
    const int x7 = lr & 7;
    const int ca[2] = {(g ^ x7) * 8, ((4 + g) ^ x7) * 8};
    const int arow0 = wr * 64 + lr, brow0 = wc * 32 + lr;
    stage(0, 0);
    __syncthreads();
    #pragma unroll
    for (int t = 0; t < 2; ++t) {
        if (t == 0) stage(1, 64);
        const __bf16* Ab = &As[t * ASZ];
        const __bf16* Bb = &Bs[t * BSZ];
        bf16x8 af[4][2], bfr[2][2];
        #pragma unroll
        for (int m = 0; m < 4; ++m)
            #pragma unroll
            for (int h = 0; h < 2; ++h)
                af[m][h] = *(const bf16x8*)&Ab[(arow0 + m * 16) * 64 + ca[h]];
        #pragma unroll
        for (int n = 0; n < 2; ++n)
            #pragma unroll
            for (int h = 0; h < 2; ++h)
                bfr[n][h] = *(const bf16x8*)&Bb[(brow0 + n * 16) * 64 + ca[h]];
        #pragma unroll
        for (int h = 0; h < 2; ++h)
            #pragma unroll
            for (int m = 0; m < 4; ++m)
                #pragma unroll
                for (int n = 0; n < 2; ++n)
                    acc[m][n] = __builtin_amdgcn_mfma_f32_16x16x32_bf16(
                        af[m][h], bfr[n][h], acc[m][n], 0, 0, 0);
        __syncthreads();
    }

    // in-kernel BC
    {
        int row = tid >> 3, pos = tid & 7, c = pos ^ (row & 7);
        #pragma unroll
        for (int t2 = 0; t2 < 2; ++t2)
            glds16(&WpairT[(size_t)(2048 + row) * 128 + t2 * 64 + c * 8],
                   &Bs[t2 * 2048 + w * 512]);
    }
    __syncthreads();
    f32x4 accB[2] = {}, accC[2] = {};
    #pragma unroll
    for (int t2 = 0; t2 < 2; ++t2) {
        const __bf16* Ab = &As[t2 * ASZ];
        #pragma unroll
        for (int h = 0; h < 2; ++h) {
            bf16x8 bB = *(const bf16x8*)&Bs[t2 * 2048 + lr * 64 + ca[h]];
            bf16x8 bC = *(const bf16x8*)&Bs[t2 * 2048 + (16 + lr) * 64 + ca[h]];
            #pragma unroll
            for (int m2 = 0; m2 < 2; ++m2) {
                bf16x8 a2 = *(const bf16x8*)&Ab[(w * 32 + m2 * 16 + lr) * 64 + ca[h]];
                accB[m2] = __builtin_amdgcn_mfma_f32_16x16x32_bf16(a2, bB, accB[m2], 0, 0, 0);
                accC[m2] = __builtin_amdgcn_mfma_f32_16x16x32_bf16(a2, bC, accC[m2], 0, 0, 0);
            }
        }
    }
    __syncthreads();
    float* sCB = (float*)As;
    __bf16* sBC = &Bs[BSZ];
    const float bB_ = bias_pair[2048 + lr], bC_ = bias_pair[2064 + lr];
    #pragma unroll
    for (int m2 = 0; m2 < 2; ++m2) {
        #pragma unroll
        for (int r = 0; r < 4; ++r) {
            int lrow = w * 32 + m2 * 16 + g * 4 + r;
            float vB = accB[m2][r] + bB_;
            float vC = accC[m2][r] + bC_;
            sBC[lrow * 32 + lr] = (__bf16)vB;
            sBC[lrow * 32 + 16 + lr] = (__bf16)vC;
            float p = vB * vC;
            #pragma unroll
            for (int m3 = 1; m3 < 16; m3 <<= 1) p += __shfl_xor(p, m3);
            if (lr == 0) sCB[lrow] = p;
        }
    }
    __syncthreads();

    const int d = ((bn + wc * 32) >> 1) + lr;
    const float bx_ = bias_pair[bn + wc * 32 + lr];
    const float bd_ = bias_pair[bn + wc * 32 + 16 + lr];
    const bool msk = (h0mask[d >> 5] >> (d & 31)) & 1u;
    #pragma unroll
    for (int m = 0; m < 4; ++m) {
        #pragma unroll
        for (int r = 0; r < 4; ++r) {
            const int lrow = wr * 64 + m * 16 + g * 4 + r;
            const int row = bm + lrow;
            const float xt = acc[m][0][r] + bx_;
            const float dr = acc[m][1][r] + bd_;
            const float e = __expf(-fabsf(dr));
            const float de = fmaxf(dr, 0.f) + __logf(1.f + e);
            const float xd = xt * de;
            float res = xd * sCB[lrow];
            const bool is_last = (row & (LSEQ - 1)) == (LSEQ - 1);
            if (msk) {
                float s = 0.f;
                #pragma unroll
                for (int n = 0; n < NDIM; ++n) {
                    float z = de * Amat[d * NDIM + n];
                    float c2 = (z > 0.f) ? z : __expf(z) - 1.f;
                    float da = __expf(-c2);
                    float h0v = h0[d * NDIM + n];
                    s += (float)sBC[lrow * 32 + 16 + n] * da * h0v;
                    if (is_last)
                        last_h[(((size_t)(row >> 11)) * DDIM + d) * NDIM + n] =
                            da * h0v + xd * (float)sBC[lrow * 32 + n];
                }
                res += s;
            } else if (is_last) {
                #pragma unroll
                for (int n = 0; n < NDIM; ++n)
                    last_h[(((size_t)(row >> 11)) * DDIM + d) * NDIM + n] =
                        xd * (float)sBC[lrow * 32 + n];
            }
            out[(size_t)row * DDIM + d] = res;
        }
    }
}

extern "C" void kernel_launch(void* const* d_in, const int* in_sizes, int n_in,
                              void* d_out, int out_size, void* d_ws, size_t ws_size,
                              hipStream_t stream) {
    const float* x   = (const float*)d_in[0];
    const float* W1  = (const float*)d_in[1];
    const float* b1  = (const float*)d_in[2];
    const float* W2  = (const float*)d_in[3];
    const float* b2  = (const float*)d_in[4];
    const float* W3  = (const float*)d_in[5];
    const float* b3  = (const float*)d_in[6];
    const float* Wl1 = (const float*)d_in[7];
    const float* bl1 = (const float*)d_in[8];
    const float* Wl2 = (const float*)d_in[9];
    const float* bl2 = (const float*)d_in[10];
    const float* Wf1 = (const float*)d_in[11];
    const float* bf1 = (const float*)d_in[12];
    const float* Wf2 = (const float*)d_in[13];
    const float* bf2 = (const float*)d_in[14];
    const float* h0  = (const float*)d_in[15];
    const float* Amat= (const float*)d_in[16];

    float* out    = (float*)d_out;
    float* last_h = (float*)d_out + (size_t)MROWS * DDIM;

    __bf16* wsb = (__bf16*)d_ws;
    size_t o = 0;
    auto alloc = [&](size_t n) { __bf16* p = wsb + o; o += n; return p; };
    __bf16* WaT    = alloc(256 * 1024);             // [Wl1 | Wf1_top]^T
    __bf16* Wf1bT  = alloc(128 * 1024);
    __bf16* Wl2T   = alloc(1024 * 128);
    __bf16* WbigT  = alloc((size_t)NPAD * 1024);    // [W1 | W2 | W3 | pad]^T
    __bf16* WpairT = alloc(2112 * 128);             // pairs 0..2047, BC 2048..2079
    __bf16* Wf2c   = alloc(128 * 1024);             // Wf2 bf16 row-major
    __bf16* tmp12  = alloc((size_t)MROWS * 256);    // [relu(x@Wl1+bl1) | x@Wf1_top]
    __bf16* tmp2   = alloc((size_t)MROWS * HDIM);
    float*  bias_pair = (float*)(wsb + o); o += 2 * 2112;
    unsigned* h0mask = (unsigned*)(wsb + o);

    // 1. pack (flat 1797 blocks)
    pack_all<<<dim3(1797), 256, 0, stream>>>(W1, W2, W3, Wl1, Wl2, Wf1, Wf2,
                                             bf2, h0,
                                             WbigT, WaT, Wf1bT, Wl2T, WpairT,
                                             Wf2c, bias_pair, h0mask);
    // 2. stage2: G1 (512) + Gpre (68) + bias fold (264)
    stage2_k<<<dim3(844), 256, 0, stream>>>(x, WaT, WbigT, Wf2c, bf2, b1, b2, b3,
                                            bl1, tmp12, WpairT, bias_pair);
    // 3. g23: fused G2+G3 -> tmp2 (lifted never materialized)
    g23_k<<<dim3(256), 512, 0, stream>>>(tmp12, Wl2T, Wf1bT, bl2, bf1, tmp2);
    // 4. mm_pairs: fused [x_tr|delta] GEMM + BC + final epilogue -> out, last_h
    mm_pairs<<<dim3(32 * 32), 256, 0, stream>>>(tmp2, WpairT, bias_pair,
                                                Amat, h0, h0mask, out, last_h);
}